// Round 2
// baseline (950.214 us; speedup 1.0000x reference)
//
#include <hip/hip_runtime.h>
#include <hip/hip_bf16.h>

#define DEVFN static __device__ __forceinline__

constexpr int NN = 16384;
constexpr int EE = 65536;
constexpr int GG = 512;
constexpr float AVG_LOG_F = 1.0227308671603782f; // (sum d*log d, d=1..4, hist 1,2,3,4)/10

typedef __attribute__((ext_vector_type(8))) short bfrag;          // 8 bf16 = 4 VGPR
typedef __attribute__((ext_vector_type(8))) unsigned short us8;   // 8 bf16 store
typedef __attribute__((ext_vector_type(4))) float f4;             // MFMA C/D

// fp32 -> bf16 (RNE) bit helpers
DEVFN unsigned short f2bf(float f) {
  unsigned int u = __float_as_uint(f);
  unsigned int r = (u + 0x7fffu + ((u >> 16) & 1u)) >> 16;
  return (unsigned short)r;
}
DEVFN float bf2f(unsigned short s) { return __uint_as_float(((unsigned int)s) << 16); }

// XOR swizzle for packed bf16 [R][K] operand arrays staged with global_load_lds:
// element (row,k) lives at row*K + swk(row,k). Within each 32-wide K window the
// four 8-element slots are permuted by (row>>1)&3 so a wave's ds_read_b128
// fragment reads become a permutation of a contiguous 1 KB region ->
// bank-conflict-free. global_load_lds copies LINEARLY, so the swizzle is baked
// into the packed global layout (both-sides rule, #21).
DEVFN int swk(int row, int k) {
  return (k & ~31) + ((((k >> 3) & 3) ^ ((row >> 1) & 3)) << 3) + (k & 7);
}

// async global->LDS, 16 B per lane; LDS dest = wave-uniform base + lane*16
DEVFN void gll16(const unsigned short* g, unsigned short* l) {
  __builtin_amdgcn_global_load_lds(
      (__attribute__((address_space(1))) void*)g,
      (__attribute__((address_space(3))) void*)l, 16, 0, 0);
}

#define WAITCNT_VM(N) asm volatile("s_waitcnt vmcnt(" #N ")" ::: "memory")
#define SCHED0() __builtin_amdgcn_sched_barrier(0)

// aux pointer bundle for fused A-staging modes
struct AuxP {
  const float* p0;
  const float* p1;
  const float* p2;
  const float* p3;
  const float* p4;
};

// ---------------------------------------------------------------------------
// Split-bf16 MFMA GEMM: C[M,Nc] = A[M,K] @ W[K,Nc](fp32, pre-split hi/lo)
// A-staging modes (ASRC):
//   0: plain fp32, split on the fly (3 MFMA ~= fp32 GEMM)
//   1: bf16 ushort input (pre-swizzled), global_load_lds copy (2 MFMA)
//   3: PNA post-combine fused: A = Px + P_id + s*P_amp + invs*P_att + bpost
//   4: fp32 / rowcount (p0=cntf) -- global mean pool divide
//   5: pre-split hi/lo ushort arrays (Av=hi, p0=lo, pre-swizzled), 3 MFMA
// B (WThi/WTlo) pre-swizzled packed, staged via global_load_lds.
//
// 2-deep software pipeline (T3+T4): gll-staged tiles are TRIPLE-buffered; at
// step k we issue tile k+2's loads, run MFMA on tile k, then wait a COUNTED
// s_waitcnt vmcnt(G) (G = glls just issued) + lgkmcnt(0) + raw s_barrier.
// vmcnt retires in issue order, so <=G outstanding guarantees tile k+1's glls
// (older) have landed while tile k+2's remain in flight across the barrier.
// Compute-mode A goes global->VGPR(va, double-buffered)->ds_write (write-late,
// T14); the ds-A LDS is double-buffered (writes to buf (k+1)&1 at step k are
// barrier-separated from reads of that buf at steps k-1/k+1).
// Block 256 = 4 waves; tile M=128, N=64, BK=32. M%128==0, K%32==0 (nk even),
// col<Nc guarded.
// ---------------------------------------------------------------------------
template <int ASRC, bool BIAS, bool RELU>
__global__ __launch_bounds__(256) void mgemm(
    const void* __restrict__ Av, const unsigned short* __restrict__ WThi,
    const unsigned short* __restrict__ WTlo, const float* __restrict__ bias,
    float* __restrict__ C, AuxP aux,
    int Nc, int K, int lda, int ldc,
    long long bsA, long long bsW, long long bsC, int bsBias)
{
  constexpr bool SPLITA = (ASRC != 1);
  constexpr bool COPYA = (ASRC == 1 || ASRC == 5);
  constexpr int ABUF = COPYA ? 3 : 2;                       // gll-A needs 3; ds-A needs 2
  constexpr int GLL = (ASRC == 5) ? 6 : (ASRC == 1 ? 4 : 2); // glls per wave per tile

  const int z = blockIdx.z;
  WThi += (long long)z * bsW;
  WTlo += (long long)z * bsW;
  C += (long long)z * bsC;
  if (BIAS) bias += (long long)z * bsBias;

  __shared__ __align__(16) unsigned short AhS[ABUF * 128 * 32];
  __shared__ __align__(16) unsigned short AlS[SPLITA ? ABUF * 128 * 32 : 8];
  __shared__ __align__(16) unsigned short BhS[3 * 64 * 32];
  __shared__ __align__(16) unsigned short BlS[3 * 64 * 32];

  const int tid = threadIdx.x;
  const long long bm = (long long)blockIdx.x * 128;
  const int bn = blockIdx.y * 64;
  const int w = tid >> 6;
  const int lane = tid & 63;
  const int quad = lane >> 4;
  const int c16 = lane & 15;
  const int srow = lane >> 2;        // staging row within 16-row chunk
  const int sslot = (lane & 3) << 3; // staging slot (ushort offset)

  // compute-mode indices: each thread produces 16 A elements of one row-half
  const int arow = tid >> 1;
  const int sel = tid & 1;
  const long long rowsrc = bm + arow;

  f4 acc[2][4];
#pragma unroll
  for (int mt = 0; mt < 2; ++mt)
#pragma unroll
    for (int nt = 0; nt < 4; ++nt) acc[mt][nt] = (f4){0.f, 0.f, 0.f, 0.f};

  // lane-invariant staging bases
  const unsigned short* wh_lane = WThi + (long long)(bn + w * 16 + srow) * K + sslot;
  const unsigned short* wl_lane = WTlo + (long long)(bn + w * 16 + srow) * K + sslot;
  unsigned short* bh_dst = BhS + w * 512;
  unsigned short* bl_dst = BlS + w * 512;

  const unsigned short* a_lane[2] = {nullptr, nullptr};
  const unsigned short* alo_lane[2] = {nullptr, nullptr};
  if (COPYA) {
    const unsigned short* Ab = (const unsigned short*)Av + (long long)z * bsA;
#pragma unroll
    for (int j = 0; j < 2; ++j)
      a_lane[j] = Ab + (bm + j * 64 + w * 16 + srow) * (long long)lda + sslot;
    if (ASRC == 5) {
      const unsigned short* Al2 = (const unsigned short*)aux.p0 + (long long)z * bsA;
#pragma unroll
      for (int j = 0; j < 2; ++j)
        alo_lane[j] = Al2 + (bm + j * 64 + w * 16 + srow) * (long long)lda + sslot;
    }
  }

  // compute-mode A state
  float invdc = 1.f;
  float sv = 0.f, iv = 0.f;
  const float* apA = nullptr;
  const float* Prow_base = nullptr;
  const float* pxp_base = nullptr;
  if (!COPYA) {
    if (ASRC == 3) {
      Prow_base = aux.p0 + rowsrc * 384;
      pxp_base = aux.p1 + rowsrc * 128;
      sv = aux.p2[rowsrc];
      iv = aux.p3[rowsrc];
    } else {
      apA = (const float*)Av + (long long)z * bsA + rowsrc * lda;
      if (ASRC == 4) invdc = 1.f / fmaxf(aux.p0[rowsrc], 1.f);
    }
  }
  // swizzled LDS write offsets for compute-mode A (ds_write path)
  const int swa = (arow >> 1) & 3;
  const int s0us = arow * 32 + (((2 * sel) ^ swa) << 3);
  const int s1us = arow * 32 + (((2 * sel + 1) ^ swa) << 3);

  // fragment-read swizzle: slot quad ^ ((row>>1)&3); row bits 1..2 == c16 bits
  const int swr8 = ((quad ^ ((c16 >> 1) & 3)) << 3);

  auto stageB = [&](int bi, int k0) {
    gll16(wh_lane + k0, bh_dst + bi * 2048);
    gll16(wl_lane + k0, bl_dst + bi * 2048);
  };
  auto stageA = [&](int bi, int k0) {
#pragma unroll
    for (int j = 0; j < 2; ++j)
      gll16(a_lane[j] + k0, AhS + bi * 4096 + j * 2048 + w * 512);
    if (ASRC == 5) {
#pragma unroll
      for (int j = 0; j < 2; ++j)
        gll16(alo_lane[j] + k0, AlS + bi * 4096 + j * 2048 + w * 512);
    }
  };
  // issue-early raw loads (T14 split); consumed by stageWrite one step later
  auto stageLoad = [&](int k0, float* va) {
    const int ck0 = k0 + sel * 16;
    if (ASRC == 3) {
      const float* Prow = Prow_base + ((ck0 >> 5) * 96) + (ck0 & 31);
      const float* pxp = pxp_base + ck0;
#pragma unroll
      for (int i = 0; i < 16; ++i)
        va[i] = pxp[i] + Prow[i] + sv * Prow[32 + i] + iv * Prow[64 + i] +
                aux.p4[ck0 + i];
    } else {
      *(float4*)&va[0] = *(const float4*)(apA + ck0);
      *(float4*)&va[4] = *(const float4*)(apA + ck0 + 4);
      *(float4*)&va[8] = *(const float4*)(apA + ck0 + 8);
      *(float4*)&va[12] = *(const float4*)(apA + ck0 + 12);
    }
  };
  // write-late: split + swizzled ds_write (after the MFMA block)
  auto stageWrite = [&](int bi, const float* va) {
    us8 hv0, hv1, lv0, lv1;
#pragma unroll
    for (int i = 0; i < 16; ++i) {
      float x = va[i];
      if (ASRC == 4) x *= invdc;
      unsigned short h = f2bf(x);
      unsigned short lo = f2bf(x - bf2f(h));
      if (i < 8) { hv0[i] = h; lv0[i] = lo; }
      else       { hv1[i - 8] = h; lv1[i - 8] = lo; }
    }
    *(us8*)&AhS[bi * 4096 + s0us] = hv0;
    *(us8*)&AhS[bi * 4096 + s1us] = hv1;
    *(us8*)&AlS[bi * 4096 + s0us] = lv0;
    *(us8*)&AlS[bi * 4096 + s1us] = lv1;
  };
  auto fragmfma = [&](int biA, int biB) {
    bfrag ah[2], al[2];
#pragma unroll
    for (int mt = 0; mt < 2; ++mt) {
      const int r = w * 32 + mt * 16 + c16;
      ah[mt] = *(const bfrag*)&AhS[biA * 4096 + r * 32 + swr8];
      if (SPLITA) al[mt] = *(const bfrag*)&AlS[biA * 4096 + r * 32 + swr8];
    }
#pragma unroll
    for (int nt = 0; nt < 4; ++nt) {
      const int r = nt * 16 + c16;
      bfrag bh = *(const bfrag*)&BhS[biB * 2048 + r * 32 + swr8];
      bfrag bl = *(const bfrag*)&BlS[biB * 2048 + r * 32 + swr8];
#pragma unroll
      for (int mt = 0; mt < 2; ++mt) {
        acc[mt][nt] = __builtin_amdgcn_mfma_f32_16x16x32_bf16(ah[mt], bh, acc[mt][nt], 0, 0, 0);
        if (SPLITA)
          acc[mt][nt] = __builtin_amdgcn_mfma_f32_16x16x32_bf16(al[mt], bh, acc[mt][nt], 0, 0, 0);
        acc[mt][nt] = __builtin_amdgcn_mfma_f32_16x16x32_bf16(ah[mt], bl, acc[mt][nt], 0, 0, 0);
      }
    }
  };
  // counted-vmcnt sync: deep=true leaves the just-issued tile's glls in flight
  auto pipe_sync = [&](bool deep) {
    if (deep) {
      if constexpr (GLL == 6) WAITCNT_VM(6);
      else if constexpr (GLL == 4) WAITCNT_VM(4);
      else WAITCNT_VM(2);
    } else {
      WAITCNT_VM(0);
    }
    SCHED0();
    asm volatile("s_waitcnt lgkmcnt(0)" ::: "memory");
    SCHED0();
    __builtin_amdgcn_s_barrier();
    asm volatile("" ::: "memory");
    SCHED0();
  };

  float va0[16], va1[16];
  const int nk = K >> 5; // 4 or 16 (always even)

  // ---- prologue: stage tiles 0 and 1; write tile 0 (compute modes) ----
  if (COPYA) {
    stageA(0, 0);
    stageB(0, 0);
    stageA(1, 32);
    stageB(1, 32);
  } else {
    stageLoad(0, va0);
    stageLoad(32, va1);
    stageB(0, 0);
    stageB(1, 32);
    stageWrite(0, va0);
  }
  pipe_sync(true); // tile 0 glls landed; tile 1's may remain in flight

  // ---- main loop, unrolled by 2 for static va / ds-buf parity ----
  for (int kt = 0; kt < nk; kt += 2) {
    { // even step k = kt: va tile k lives in va0, tile k+1 in va1
      const int k = kt;
      const bool pf = (k + 2 < nk);
      if (pf) {
        if (COPYA) stageA((k + 2) % 3, (k + 2) << 5);
        else stageLoad((k + 2) << 5, va0);       // tile k+2 -> va[(k+2)&1] = va0
        stageB((k + 2) % 3, (k + 2) << 5);
      }
      fragmfma(COPYA ? (k % 3) : 0, k % 3);
      if (!COPYA && (k + 1 < nk)) stageWrite(1, va1); // tile k+1 -> ds buf 1
      if (k + 1 < nk) pipe_sync(pf);
    }
    { // odd step k = kt+1
      const int k = kt + 1;
      const bool pf = (k + 2 < nk);
      if (pf) {
        if (COPYA) stageA((k + 2) % 3, (k + 2) << 5);
        else stageLoad((k + 2) << 5, va1);       // tile k+2 -> va1
        stageB((k + 2) % 3, (k + 2) << 5);
      }
      fragmfma(COPYA ? (k % 3) : 1, k % 3);
      if (!COPYA && (k + 1 < nk)) stageWrite(0, va0); // tile k+1 -> ds buf 0
      if (k + 1 < nk) pipe_sync(pf);
    }
  }

  // epilogue: C/D layout col=lane&15, row=quad*4+reg
#pragma unroll
  for (int nt = 0; nt < 4; ++nt) {
    int col = bn + nt * 16 + c16;
    if (col >= Nc) continue;
    float bv = BIAS ? bias[col] : 0.f;
#pragma unroll
    for (int mt = 0; mt < 2; ++mt) {
#pragma unroll
      for (int r = 0; r < 4; ++r) {
        long long row = bm + w * 32 + mt * 16 + quad * 4 + r;
        float v = acc[mt][nt][r] + bv;
        if (RELU) v = fmaxf(v, 0.f);
        C[row * ldc + col] = v;
      }
    }
  }
}

// ---------------------------------------------------------------------------
// Encoders
// ---------------------------------------------------------------------------
__global__ void node_enc(const float* __restrict__ x, const float* __restrict__ Wa,
                         const float* __restrict__ ba, float* __restrict__ h)
{
  int n = blockIdx.x, c = threadIdx.x; // 128
  float acc = ba[c];
#pragma unroll
  for (int k = 0; k < 11; ++k) acc += x[n * 11 + k] * Wa[k * 128 + c];
  h[(long long)n * 128 + c] = fmaxf(acc, 0.f);
}

// writes split hi/lo DIRECTLY in CSR slot order, PRE-SWIZZLED for gll staging
__global__ void edge_enc(const float* __restrict__ eat, const float* __restrict__ We,
                         const float* __restrict__ be, const int* __restrict__ slot_of,
                         unsigned short* __restrict__ eh, unsigned short* __restrict__ el)
{
  int e = blockIdx.x, c = threadIdx.x; // 128
  float acc = be[c];
#pragma unroll
  for (int k = 0; k < 4; ++k) acc += eat[e * 4 + k] * We[k * 128 + c];
  float v = fmaxf(acc, 0.f);
  unsigned short h = f2bf(v);
  long long slot = slot_of[e];
  int sc = swk((int)slot, c);
  eh[slot * 128 + sc] = h;
  el[slot * 128 + sc] = f2bf(v - bf2f(h));
}

// ---------------------------------------------------------------------------
// CSR build: count -> scan (also inits cursor + s/invs) -> scatter
// ---------------------------------------------------------------------------
__global__ void count_deg(const int* __restrict__ dst, int* __restrict__ degi)
{
  int e = blockIdx.x * 256 + threadIdx.x;
  if (e < EE) atomicAdd(&degi[dst[e]], 1);
}

__global__ __launch_bounds__(1024) void scan_k(const int* __restrict__ degi,
                                               int* __restrict__ row_off,
                                               int* __restrict__ cursor,
                                               float* __restrict__ s_arr,
                                               float* __restrict__ invs)
{
  __shared__ int tsum[1024];
  int t = threadIdx.x;
  int local[16];
  int base = t * 16;
  int s = 0;
#pragma unroll
  for (int i = 0; i < 16; ++i) { local[i] = s; s += degi[base + i]; }
  tsum[t] = s;
  __syncthreads();
  for (int off = 1; off < 1024; off <<= 1) {
    int v = (t >= off) ? tsum[t - off] : 0;
    __syncthreads();
    tsum[t] += v;
    __syncthreads();
  }
  int prev = (t == 0) ? 0 : tsum[t - 1];
#pragma unroll
  for (int i = 0; i < 16; ++i) {
    int start = prev + local[i];
    row_off[base + i] = start;
    cursor[base + i] = start;
    int cnt = degi[base + i];
    float degc = fmaxf((float)cnt, 1.f);
    float sv = logf(degc + 1.f) / AVG_LOG_F;
    s_arr[base + i] = sv;
    invs[base + i] = 1.f / sv;
  }
  if (t == 1023) row_off[NN] = tsum[1023];
}

__global__ void scatter_k(const int* __restrict__ src, const int* __restrict__ dst,
                          int* __restrict__ cursor,
                          int* __restrict__ slot_of, int* __restrict__ esrc)
{
  int e = blockIdx.x * 256 + threadIdx.x;
  if (e >= EE) return;
  int d = dst[e];
  int slot = atomicAdd(&cursor[d], 1);
  slot_of[e] = slot;
  esrc[slot] = src[e];
}

// ---------------------------------------------------------------------------
// Weight folds (fp32) + transpose-split packers (fp32 -> bf16 hi/lo, [N][K])
// All packed operand arrays are PRE-SWIZZLED (swk) for global_load_lds staging.
// ---------------------------------------------------------------------------
__global__ __launch_bounds__(512) void fold_w(const float* __restrict__ We_conv,
                                              const float* __restrict__ Wpre,
                                              float* __restrict__ Wfold)
{
  int k = blockIdx.x & 127, l = blockIdx.x >> 7;
  int t = threadIdx.x >> 7, f = threadIdx.x & 127;
  const float* wc = We_conv + (long long)(l * 128 + k) * 128;
  const float* wp = Wpre + ((long long)((l * 4 + t) * 384 + 256)) * 128 + f;
  float acc = 0.f;
  for (int j = 0; j < 128; ++j) acc += wc[j] * wp[(long long)j * 128];
  Wfold[((long long)(l * 128 + k)) * 512 + threadIdx.x] = acc;
}

__global__ __launch_bounds__(512) void fold_b(const float* __restrict__ be_conv,
                                              const float* __restrict__ Wpre,
                                              const float* __restrict__ bpre,
                                              float* __restrict__ bfold)
{
  int l = blockIdx.x;
  int t = threadIdx.x >> 7, f = threadIdx.x & 127;
  const float* bc = be_conv + l * 128;
  const float* wp = Wpre + ((long long)((l * 4 + t) * 384 + 256)) * 128 + f;
  float acc = bpre[(l * 4 + t) * 128 + f];
  for (int j = 0; j < 128; ++j) acc += bc[j] * wp[(long long)j * 128];
  bfold[l * 512 + threadIdx.x] = acc;
}

DEVFN void wsplit(float v, unsigned short* hi, unsigned short* lo, long long o)
{
  unsigned short h = f2bf(v);
  hi[o] = h;
  lo[o] = f2bf(v - bf2f(h));
}

// preABT[lt][n(256)][k(128)] (swizzled)
__global__ void tsplit_preAB(const float* __restrict__ Wpre,
                             unsigned short* __restrict__ hi, unsigned short* __restrict__ lo)
{
  int b = blockIdx.x; // 12*256
  int lt = b >> 8, n = b & 255, k = threadIdx.x; // 128
  int row = (n < 128) ? k : (128 + k);
  int f = n & 127;
  float v = Wpre[((long long)(lt * 384 + row)) * 128 + f];
  wsplit(v, hi, lo, ((long long)(lt * 256 + n)) * 128 + swk(n, k));
}

// WfoldT[lt][n(128)][k(128)] from Wfold[l][k][t*128+n] (swizzled)
__global__ void tsplit_fold(const float* __restrict__ Wfold,
                            unsigned short* __restrict__ hi, unsigned short* __restrict__ lo)
{
  int b = blockIdx.x; // 12*128
  int lt = b >> 7, n = b & 127, k = threadIdx.x; // 128
  int l = lt >> 2, t = lt & 3;
  float v = Wfold[((long long)(l * 128 + k)) * 512 + t * 128 + n];
  wsplit(v, hi, lo, ((long long)(lt * 128 + n)) * 128 + swk(n, k));
}

// post3T[lt][c(128, pad>=96 zero)][r(512)] (swizzled)
__global__ __launch_bounds__(512) void tsplit_post3(const float* __restrict__ Wpost,
                                                    unsigned short* __restrict__ hi,
                                                    unsigned short* __restrict__ lo)
{
  int b = blockIdx.x; // 12*128
  int lt = b >> 7, c = b & 127;
  int r = threadIdx.x; // 512
  float v = 0.f;
  if (c < 96)
    v = Wpost[((long long)(lt * 1664 + 128 + (c >> 5) * 512 + r)) * 32 + (c & 31)];
  wsplit(v, hi, lo, ((long long)(lt * 128 + c)) * 512 + swk(c, r));
}

// WxT[l][c(128)][k(128)] (swizzled)
__global__ void tsplit_wx(const float* __restrict__ Wpost,
                          unsigned short* __restrict__ hi, unsigned short* __restrict__ lo)
{
  int b = blockIdx.x; // 3*128
  int l = b >> 7, c = b & 127, k = threadIdx.x;
  float v = Wpost[((long long)((l * 4 + (c >> 5)) * 1664 + k)) * 32 + (c & 31)];
  wsplit(v, hi, lo, ((long long)(l * 128 + c)) * 128 + swk(c, k));
}

// WlinT[l][n][k] (swizzled)
__global__ void tsplit_lin(const float* __restrict__ Wlin,
                           unsigned short* __restrict__ hi, unsigned short* __restrict__ lo)
{
  int b = blockIdx.x; // 3*128
  int l = b >> 7, n = b & 127, k = threadIdx.x;
  float v = Wlin[((long long)(l * 128 + k)) * 128 + n];
  wsplit(v, hi, lo, ((long long)(l * 128 + n)) * 128 + swk(n, k));
}

// W1T[n(64)][k(128)] (swizzled)
__global__ void tsplit_w1(const float* __restrict__ W1,
                          unsigned short* __restrict__ hi, unsigned short* __restrict__ lo)
{
  int n = blockIdx.x; // 64
  int k = threadIdx.x; // 128
  wsplit(W1[k * 64 + n], hi, lo, (long long)n * 128 + swk(n, k));
}

// ---------------------------------------------------------------------------
// Per-tower aggregation, both towers of the pair folded into one block.
// Block 128 = 2 nodes x 2 towers x 32 lanes(x4 ch float4). Edges processed in
// chunks of 4: esrc batch-loaded first, then 8 independent float4 loads in
// flight (breaks the esrc->ABs dependent-latency chain). Accumulation order
// per channel is IDENTICAL to the scalar version (bit-identical numerics).
// Output aggs bf16 [N][512], PRE-SWIZZLED (swk) for gll staging by P gemm.
// ---------------------------------------------------------------------------
__global__ __launch_bounds__(128) void aggregate_ct(
    const float* __restrict__ ABb, const float* __restrict__ Mb,
    const int* __restrict__ row_off, const int* __restrict__ esrc,
    unsigned short* __restrict__ aggs, int pair)
{
  const int tid = threadIdx.x;
  const int c4 = (tid & 31) << 2;
  const int z = (tid >> 5) & 1;
  const int n = blockIdx.x * 2 + (tid >> 6);
  const float* M = Mb + (long long)z * EE * 128;
  const float* ABs = ABb + (long long)(pair * 2 + z) * NN * 256;
  unsigned short* ag = aggs + (long long)(pair * 2 + z) * NN * 512;
  const int beg = row_off[n], end = row_off[n + 1];
  const int cnt = end - beg;
  const float degc = fmaxf((float)cnt, 1.0f);
  const float4 aval = *(const float4*)&ABs[(long long)n * 256 + c4];

  float sum[4] = {0.f, 0.f, 0.f, 0.f}, sq[4] = {0.f, 0.f, 0.f, 0.f};
  float mn[4] = {INFINITY, INFINITY, INFINITY, INFINITY};
  float mx[4] = {-INFINITY, -INFINITY, -INFINITY, -INFINITY};

  auto upd = [&](const float4& mv, const float4& bv) {
    float m0 = aval.x + bv.x + mv.x;
    float m1 = aval.y + bv.y + mv.y;
    float m2 = aval.z + bv.z + mv.z;
    float m3 = aval.w + bv.w + mv.w;
    sum[0] += m0; sq[0] += m0 * m0; mn[0] = fminf(mn[0], m0); mx[0] = fmaxf(mx[0], m0);
    sum[1] += m1; sq[1] += m1 * m1; mn[1] = fminf(mn[1], m1); mx[1] = fmaxf(mx[1], m1);
    sum[2] += m2; sq[2] += m2 * m2; mn[2] = fminf(mn[2], m2); mx[2] = fmaxf(mx[2], m2);
    sum[3] += m3; sq[3] += m3 * m3; mn[3] = fminf(mn[3], m3); mx[3] = fmaxf(mx[3], m3);
  };

  for (int s0 = beg; s0 < end; s0 += 4) {
    const int e1 = min(s0 + 1, end - 1);
    const int e2 = min(s0 + 2, end - 1);
    const int e3 = min(s0 + 3, end - 1);
    const int sA = esrc[s0], sB = esrc[e1], sC = esrc[e2], sD = esrc[e3];
    const float4 mA = *(const float4*)&M[(long long)s0 * 128 + c4];
    const float4 mB = *(const float4*)&M[(long long)e1 * 128 + c4];
    const float4 mC = *(const float4*)&M[(long long)e2 * 128 + c4];
    const float4 mD = *(const float4*)&M[(long long)e3 * 128 + c4];
    const float4 bA = *(const float4*)&ABs[(long long)sA * 256 + 128 + c4];
    const float4 bB = *(const float4*)&ABs[(long long)sB * 256 + 128 + c4];
    const float4 bC = *(const float4*)&ABs[(long long)sC * 256 + 128 + c4];
    const float4 bD = *(const float4*)&ABs[(long long)sD * 256 + 128 + c4];
    upd(mA, bA);
    if (s0 + 1 < end) upd(mB, bB);
    if (s0 + 2 < end) upd(mC, bC);
    if (s0 + 3 < end) upd(mD, bD);
  }

  const float inv = 1.0f / degc;
  float mean[4], stdv[4];
#pragma unroll
  for (int j = 0; j < 4; ++j) {
    mean[j] = sum[j] * inv;
    float var = sq[j] * inv - mean[j] * mean[j];
    stdv[j] = sqrtf(fmaxf(var, 0.f) + 1e-5f);
    if (cnt == 0) { mn[j] = 0.f; mx[j] = 0.f; }
  }
  const int sc = swk(n, c4);
  const long long base = (long long)n * 512 + sc;
  ushort4 o;
  o.x = f2bf(mean[0]); o.y = f2bf(mean[1]); o.z = f2bf(mean[2]); o.w = f2bf(mean[3]);
  *(ushort4*)&ag[base] = o;
  o.x = f2bf(mn[0]); o.y = f2bf(mn[1]); o.z = f2bf(mn[2]); o.w = f2bf(mn[3]);
  *(ushort4*)&ag[base + 128] = o;
  o.x = f2bf(mx[0]); o.y = f2bf(mx[1]); o.z = f2bf(mx[2]); o.w = f2bf(mx[3]);
  *(ushort4*)&ag[base + 256] = o;
  o.x = f2bf(stdv[0]); o.y = f2bf(stdv[1]); o.z = f2bf(stdv[2]); o.w = f2bf(stdv[3]);
  *(ushort4*)&ag[base + 384] = o;
}

// ---------------------------------------------------------------------------
// BatchNorm stats over N rows, 128 cols + coefficient precompute + apply
// ---------------------------------------------------------------------------
__global__ __launch_bounds__(256) void bn_partial(const float* __restrict__ y,
                                                  float* __restrict__ colsum,
                                                  float* __restrict__ colsq)
{
  int c = threadIdx.x & 127;
  int rh = threadIdx.x >> 7;
  int r0 = blockIdx.x * 128;
  float s = 0.f, q = 0.f;
  for (int r = r0 + rh; r < r0 + 128; r += 2) {
    float v = y[(long long)r * 128 + c];
    s += v;
    q += v * v;
  }
  __shared__ float ps[256], pq[256];
  ps[threadIdx.x] = s;
  pq[threadIdx.x] = q;
  __syncthreads();
  if (threadIdx.x < 128) {
    atomicAdd(&colsum[c], ps[c] + ps[c + 128]);
    atomicAdd(&colsq[c], pq[c] + pq[c + 128]);
  }
}

// coef[c] = g*rsqrt(var+eps); coef[128+c] = b - mean*scale  (BN as FMA)
__global__ void bn_coef(const float* __restrict__ colsum, const float* __restrict__ colsq,
                        const float* __restrict__ g, const float* __restrict__ b,
                        float* __restrict__ coef)
{
  int c = threadIdx.x; // 128
  float mean = colsum[c] * (1.f / 16384.f);
  float var = colsq[c] * (1.f / 16384.f) - mean * mean;
  float sc = g[c] * rsqrtf(var + 1e-5f);
  coef[c] = sc;
  coef[128 + c] = b[c] - mean * sc;
}

// o = relu(y*scale + shift), float4 grid-stride-free (grid exactly covers)
__global__ __launch_bounds__(256) void bn_apply(const float* __restrict__ y,
                                                const float* __restrict__ coef,
                                                float* __restrict__ o)
{
  int idx = (blockIdx.x * 256 + threadIdx.x) * 4; // < NN*128
  int c = idx & 127;
  float4 v = *(const float4*)&y[idx];
  float4 r;
  r.x = fmaxf(v.x * coef[c + 0] + coef[128 + c + 0], 0.f);
  r.y = fmaxf(v.y * coef[c + 1] + coef[128 + c + 1], 0.f);
  r.z = fmaxf(v.z * coef[c + 2] + coef[128 + c + 2], 0.f);
  r.w = fmaxf(v.w * coef[c + 3] + coef[128 + c + 3], 0.f);
  *(float4*)&o[idx] = r;
}

// ---------------------------------------------------------------------------
// Global mean pool (BN+ReLU fused) + head
// ---------------------------------------------------------------------------
__global__ void pool_add(const float* __restrict__ y, const float* __restrict__ colsum,
                         const float* __restrict__ colsq, const float* __restrict__ g,
                         const float* __restrict__ b, const int* __restrict__ batch,
                         float* __restrict__ pooled, float* __restrict__ cntf)
{
  int n = blockIdx.x, c = threadIdx.x;
  float mean = colsum[c] * (1.f / 16384.f);
  float var = colsq[c] * (1.f / 16384.f) - mean * mean;
  float v = fmaxf((y[(long long)n * 128 + c] - mean) * rsqrtf(var + 1e-5f) * g[c] + b[c], 0.f);
  int bb = batch[n];
  atomicAdd(&pooled[(long long)bb * 128 + c], v);
  if (c == 0) atomicAdd(&cntf[bb], 1.f);
}

__global__ __launch_bounds__(256) void zstats(const float* __restrict__ z,
                                              float* __restrict__ zm, float* __restrict__ zv)
{
  int j = blockIdx.x; // 64 cols
  float s = 0.f, q = 0.f;
  for (int g = threadIdx.x; g < GG; g += 256) {
    float v = z[g * 64 + j];
    s += v;
    q += v * v;
  }
  __shared__ float ps[256], pq[256];
  ps[threadIdx.x] = s;
  pq[threadIdx.x] = q;
  __syncthreads();
  for (int st = 128; st > 0; st >>= 1) {
    if (threadIdx.x < st) {
      ps[threadIdx.x] += ps[threadIdx.x + st];
      pq[threadIdx.x] += pq[threadIdx.x + st];
    }
    __syncthreads();
  }
  if (threadIdx.x == 0) {
    float m = ps[0] / (float)GG;
    zm[j] = m;
    zv[j] = pq[0] / (float)GG - m * m;
  }
}

__global__ void final_out(const float* __restrict__ z, const float* __restrict__ zm,
                          const float* __restrict__ zv, const float* __restrict__ hg,
                          const float* __restrict__ hb, const float* __restrict__ W2,
                          const float* __restrict__ b2, float* __restrict__ out)
{
  int g = blockIdx.x;
  int j = threadIdx.x; // 64 = one wave
  float v = (z[g * 64 + j] - zm[j]) * rsqrtf(zv[j] + 1e-5f) * hg[j] + hb[j];
  float t = v * W2[j];
#pragma unroll
  for (int off = 32; off > 0; off >>= 1) t += __shfl_down(t, off);
  if (j == 0) out[g] = t + b2[0];
}

// ---------------------------------------------------------------------------
extern "C" void kernel_launch(void* const* d_in, const int* in_sizes, int n_in,
                              void* d_out, int out_size, void* d_ws, size_t ws_size,
                              hipStream_t stream)
{
  (void)in_sizes; (void)n_in; (void)out_size;
  const float* x = (const float*)d_in[0];
  const float* eat = (const float*)d_in[1];
  const int* ei = (const int*)d_in[2];
  const int* batch = (const int*)d_in[3];
  const float* Wa = (const float*)d_in[4];
  const float* ba = (const float*)d_in[5];
  const float* We = (const float*)d_in[6];
  const float* be = (const float*)d_in[7];
  const float* We_conv = (const float*)d_in[8];
  const float* be_conv = (const float*)d_in[9];
  const float* Wpre = (const float*)d_in[10];
  const float* bpre = (const float*)d_in[11];
  const float* Wpost = (const float*)d_in[12];
  const float* bpost = (const float*)d_in[13];
  const float* Wlin = (const float*)d_in[14];
  const float* blin = (const float*)d_in[15];
  const float* bng = (const float*)d_in[16];
  const float* bnb = (const float*)d_in[17];
  const float* W1 = (const float*)d_in[18];
  const float* b1 = (const float*)d_in[19];
  const float* hg = (const float*)d_in[20];
  const float* hb = (const float*)d_in[21];
  const float* W2 = (const float*)d_in[22];
  const float* b2 = (const float*)d_in[23];
  float* out = (float*)d_out;

  const int* srcI = ei;
  const int* dstI = ei + EE;

  char* ws = (char*)d_ws;
  size_t off = 0;
  auto alloc = [&](size_t bytes) -> char* {
    char* p = ws + off;
    off += (bytes + 255) & ~(size_t)255;
    return p;
  };

  // ~259 MB total (ws = 256 MiB = 268.4 MB)
  float* h0 = (float*)alloc((size_t)NN * 128 * 4);  // encoded; then BN-applied input
  float* hn = (float*)alloc((size_t)NN * 128 * 4);
  unsigned short* eah = (unsigned short*)alloc((size_t)EE * 128 * 2); // CSR slot order
  unsigned short* eal = (unsigned short*)alloc((size_t)EE * 128 * 2);
  float* AB = (float*)alloc((size_t)4 * NN * 256 * 4);       // [T][N][256] fp32
  char* Mregion = alloc((size_t)2 * EE * 128 * 4);           // C pair; later P|Px
  float* Mb = (float*)Mregion;
  float* P = (float*)Mregion;                                 // [N][384]
  float* Px = (float*)(Mregion + (size_t)NN * 384 * 4);       // [N][128]
  unsigned short* aggt = (unsigned short*)alloc((size_t)4 * NN * 512 * 2); // bf16 [T][N][512]
  float* s_arr = (float*)alloc((size_t)NN * 4);
  float* invs = (float*)alloc((size_t)NN * 4);
  int* degi = (int*)alloc((size_t)NN * 4);
  int* cursor = (int*)alloc((size_t)NN * 4);
  int* row_off = (int*)alloc((size_t)(NN + 1) * 4);
  int* slot_of = (int*)alloc((size_t)EE * 4);
  int* esrc = (int*)alloc((size_t)EE * 4);
  float* WfoldF = (float*)alloc((size_t)3 * 128 * 512 * 4);
  float* bfold = (float*)alloc((size_t)3 * 512 * 4);
  unsigned short* preABT_h = (unsigned short*)alloc((size_t)12 * 256 * 128 * 2);
  unsigned short* preABT_l = (unsigned short*)alloc((size_t)12 * 256 * 128 * 2);
  unsigned short* foldT_h = (unsigned short*)alloc((size_t)12 * 128 * 128 * 2);
  unsigned short* foldT_l = (unsigned short*)alloc((size_t)12 * 128 * 128 * 2);
  unsigned short* post3T_h = (unsigned short*)alloc((size_t)12 * 128 * 512 * 2);
  unsigned short* post3T_l = (unsigned short*)alloc((size_t)12 * 128 * 512 * 2);
  unsigned short* wxT_h = (unsigned short*)alloc((size_t)3 * 128 * 128 * 2);
  unsigned short* wxT_l = (unsigned short*)alloc((size_t)3 * 128 * 128 * 2);
  unsigned short* linT_h = (unsigned short*)alloc((size_t)3 * 128 * 128 * 2);
  unsigned short* linT_l = (unsigned short*)alloc((size_t)3 * 128 * 128 * 2);
  unsigned short* w1T_h = (unsigned short*)alloc((size_t)64 * 128 * 2);
  unsigned short* w1T_l = (unsigned short*)alloc((size_t)64 * 128 * 2);
  float* colstats = (float*)alloc(512 * 4); // two ping-pong buffers of 256
  float* bncoef = (float*)alloc(256 * 4);   // BN scale|shift for bn_apply
  float* pooled = (float*)alloc((size_t)GG * 128 * 4);
  float* cntf = (float*)alloc((size_t)GG * 4);
  float* zbuf = (float*)alloc((size_t)GG * 64 * 4);
  float* zm = (float*)alloc(64 * 4);
  float* zv = (float*)alloc(64 * 4);

  if (off > ws_size) return; // bail rather than corrupt

  float* cs[2] = {colstats, colstats + 256};

  // ---- graph structure ----
  hipMemsetAsync(degi, 0, (size_t)NN * 4, stream);
  count_deg<<<EE / 256, 256, 0, stream>>>(dstI, degi);
  scan_k<<<1, 1024, 0, stream>>>(degi, row_off, cursor, s_arr, invs);
  scatter_k<<<EE / 256, 256, 0, stream>>>(srcI, dstI, cursor, slot_of, esrc);

  // ---- encoders + weight folds/packing ----
  node_enc<<<NN, 128, 0, stream>>>(x, Wa, ba, h0);
  edge_enc<<<EE, 128, 0, stream>>>(eat, We, be, slot_of, eah, eal); // after scatter_k
  fold_w<<<384, 512, 0, stream>>>(We_conv, Wpre, WfoldF);
  fold_b<<<3, 512, 0, stream>>>(be_conv, Wpre, bpre, bfold);
  tsplit_preAB<<<12 * 256, 128, 0, stream>>>(Wpre, preABT_h, preABT_l);
  tsplit_fold<<<12 * 128, 128, 0, stream>>>(WfoldF, foldT_h, foldT_l);
  tsplit_post3<<<12 * 128, 512, 0, stream>>>(Wpost, post3T_h, post3T_l);
  tsplit_wx<<<3 * 128, 128, 0, stream>>>(Wpost, wxT_h, wxT_l);
  tsplit_lin<<<3 * 128, 128, 0, stream>>>(Wlin, linT_h, linT_l);
  tsplit_w1<<<64, 128, 0, stream>>>(W1, w1T_h, w1T_l);

  for (int l = 0; l < 3; ++l) {
    hipMemsetAsync(cs[l & 1], 0, 256 * 4, stream);
    // AB all towers: [N,128] @ [128,256] (z=4) -> fp32 [T][N][256]
    // h0 holds BN+ReLU-applied input for l>0 (bn_apply), encoded input for l=0
    mgemm<0, false, false><<<dim3(NN / 128, 4, 4), 256, 0, stream>>>(
        h0, preABT_h + (size_t)l * 4 * 256 * 128, preABT_l + (size_t)l * 4 * 256 * 128,
        nullptr, AB, AuxP{}, 256, 128, 128, 256,
        0, (long long)256 * 128, (long long)NN * 256, 0);
    for (int pair = 0; pair < 2; ++pair) {
      int lt0 = l * 4 + pair * 2;
      // C (pair of towers, streaming, CSR-ordered ea): [E,128]@[128,128]+bfold
      mgemm<5, true, false><<<dim3(EE / 128, 2, 2), 256, 0, stream>>>(
          eah, foldT_h + (size_t)lt0 * 128 * 128, foldT_l + (size_t)lt0 * 128 * 128,
          bfold + l * 512 + pair * 256, Mb,
          AuxP{(const float*)eal, nullptr, nullptr, nullptr, nullptr},
          128, 128, 128, 128, 0, (long long)128 * 128, (long long)EE * 128, 128);
      // stats over m = (A + B[src]) + C  (C streaming); both towers per block
      aggregate_ct<<<dim3(NN / 2, 1, 1), 128, 0, stream>>>(AB, Mb, row_off, esrc, aggt, pair);
    }
    // P all towers: bf16 [N,512] @ [512,96] (z=4) -> P[:, z*96..]
    mgemm<1, false, false><<<dim3(NN / 128, 2, 4), 256, 0, stream>>>(
        aggt, post3T_h + (size_t)l * 4 * 128 * 512, post3T_l + (size_t)l * 4 * 128 * 512,
        nullptr, P, AuxP{}, 96, 512, 512, 384,
        (long long)NN * 512, (long long)128 * 512, 96, 0);
    // Px: [N,128] @ [128,128]
    mgemm<0, false, false><<<dim3(NN / 128, 2, 1), 256, 0, stream>>>(
        h0, wxT_h + (size_t)l * 128 * 128, wxT_l + (size_t)l * 128 * 128,
        nullptr, Px, AuxP{}, 128, 128, 128, 128, 0, 0, 0, 0);
    // lin (post-combine fused in A-staging): [N,128] @ [128,128] + blin -> hn
    mgemm<3, true, false><<<dim3(NN / 128, 2, 1), 256, 0, stream>>>(
        nullptr, linT_h + (size_t)l * 128 * 128, linT_l + (size_t)l * 128 * 128,
        blin + l * 128, hn, AuxP{P, Px, s_arr, invs, bpost + l * 128},
        128, 128, 128, 128, 0, 0, 0, 0);
    bn_partial<<<128, 256, 0, stream>>>(hn, cs[l & 1], cs[l & 1] + 128);
    if (l < 2) {
      bn_coef<<<1, 128, 0, stream>>>(cs[l & 1], cs[l & 1] + 128,
                                     bng + l * 128, bnb + l * 128, bncoef);
      bn_apply<<<NN * 128 / 1024, 256, 0, stream>>>(hn, bncoef, h0);
    }
  }

  // ---- pooling (BN+ReLU fused) + head ----
  hipMemsetAsync(pooled, 0, (size_t)GG * 128 * 4, stream);
  hipMemsetAsync(cntf, 0, (size_t)GG * 4, stream);
  pool_add<<<NN, 128, 0, stream>>>(hn, cs[0], cs[0] + 128,
                                   bng + 2 * 128, bnb + 2 * 128, batch, pooled, cntf);
  mgemm<4, true, true><<<dim3(GG / 128, 1, 1), 256, 0, stream>>>(
      pooled, w1T_h, w1T_l, b1, zbuf,
      AuxP{cntf, nullptr, nullptr, nullptr, nullptr}, 64, 128, 128, 64, 0, 0, 0, 0);
  zstats<<<64, 256, 0, stream>>>(zbuf, zm, zv);
  final_out<<<GG, 64, 0, stream>>>(zbuf, zm, zv, hg, hb, W2, b2, out);
}

// Round 4
// 857.262 us; speedup vs baseline: 1.1084x; 1.1084x over previous
//
#include <hip/hip_runtime.h>
#include <hip/hip_bf16.h>

#define DEVFN static __device__ __forceinline__

constexpr int NN = 16384;
constexpr int EE = 65536;
constexpr int GG = 512;
constexpr float AVG_LOG_F = 1.0227308671603782f; // (sum d*log d, d=1..4, hist 1,2,3,4)/10

typedef __attribute__((ext_vector_type(8))) short bfrag;          // 8 bf16 = 4 VGPR
typedef __attribute__((ext_vector_type(8))) unsigned short us8;   // 8 bf16 store
typedef __attribute__((ext_vector_type(4))) float f4;             // MFMA C/D

// fp32 -> bf16 (RNE) bit helpers
DEVFN unsigned short f2bf(float f) {
  unsigned int u = __float_as_uint(f);
  unsigned int r = (u + 0x7fffu + ((u >> 16) & 1u)) >> 16;
  return (unsigned short)r;
}
DEVFN float bf2f(unsigned short s) { return __uint_as_float(((unsigned int)s) << 16); }

// XOR swizzle for packed bf16 [R][K] operand arrays staged with global_load_lds:
// element (row,k) lives at row*K + swk(row,k). Within each 32-wide K window the
// four 8-element slots are permuted by (row>>1)&3 so a wave's ds_read_b128
// fragment reads become a permutation of a contiguous 1 KB region ->
// bank-conflict-free. global_load_lds copies LINEARLY, so the swizzle is baked
// into the packed global layout (both-sides rule, #21).
DEVFN int swk(int row, int k) {
  return (k & ~31) + ((((k >> 3) & 3) ^ ((row >> 1) & 3)) << 3) + (k & 7);
}

// async global->LDS, 16 B per lane; LDS dest = wave-uniform base + lane*16
DEVFN void gll16(const unsigned short* g, unsigned short* l) {
  __builtin_amdgcn_global_load_lds(
      (__attribute__((address_space(1))) void*)g,
      (__attribute__((address_space(3))) void*)l, 16, 0, 0);
}

// aux pointer bundle for fused A-staging modes
struct AuxP {
  const float* p0;
  const float* p1;
  const float* p2;
  const float* p3;
  const float* p4;
};

// ---------------------------------------------------------------------------
// Split-bf16 MFMA GEMM: C[M,Nc] = A[M,K] @ W[K,Nc](fp32, pre-split hi/lo)
// A-staging modes (ASRC):
//   1: bf16 ushort input (pre-swizzled), gll copy, A hi only (2 MFMA)
//   3: PNA post-combine fused: A = Px + P_id + s*P_amp + invs*P_att + bpost
//   4: fp32 / rowcount (p0=cntf) -- global mean pool divide (ds-write path)
//   5: pre-split hi/lo ushort arrays (Av=hi, p0=lo, pre-swizzled), gll copy
// B (WThi/WTlo) pre-swizzled packed, staged via global_load_lds.
// NT = column fragments (tile N = NT*16). r1 sync structure (measured best):
// double-buffered LDS, stage tile k+1 via gll before MFMA on tile k, one
// __syncthreads per step (its vmcnt/lgkm drain completes the prefetch).
// Block 256 = 4 waves; tile M=128, BK=32. M%128==0, K%32==0, col<Nc guarded.
// ---------------------------------------------------------------------------
template <int ASRC, int NT, bool BIAS, bool RELU>
__global__ __launch_bounds__(256) void mgemm(
    const void* __restrict__ Av, const unsigned short* __restrict__ WThi,
    const unsigned short* __restrict__ WTlo, const float* __restrict__ bias,
    float* __restrict__ C, AuxP aux,
    int Nc, int K, int lda, int ldc,
    long long bsA, long long bsW, long long bsC, int bsBias)
{
  constexpr bool SPLITA = (ASRC != 1);
  constexpr bool COPYA = (ASRC == 1 || ASRC == 5);
  constexpr int BST = NT * 16 * 32; // ushorts per B buffer

  const int z = blockIdx.z;
  WThi += (long long)z * bsW;
  WTlo += (long long)z * bsW;
  C += (long long)z * bsC;
  if (BIAS) bias += (long long)z * bsBias;

  __shared__ __align__(16) unsigned short AhS[2 * 128 * 32];
  __shared__ __align__(16) unsigned short AlS[SPLITA ? 2 * 128 * 32 : 8];
  __shared__ __align__(16) unsigned short BhS[2 * BST];
  __shared__ __align__(16) unsigned short BlS[2 * BST];

  const int tid = threadIdx.x;
  const long long bm = (long long)blockIdx.x * 128;
  const int bn = blockIdx.y * (NT * 16);
  const int w = tid >> 6;
  const int lane = tid & 63;
  const int quad = lane >> 4;
  const int c16 = lane & 15;
  const int srow = lane >> 2;        // staging row within 16-row chunk
  const int sslot = (lane & 3) << 3; // staging slot (ushort offset)

  // ds-write-mode indices: each thread produces 16 A elements of one row-half
  const int arow = tid >> 1;
  const int sel = tid & 1;
  const long long rowsrc = bm + arow;

  f4 acc[2][NT];
#pragma unroll
  for (int mt = 0; mt < 2; ++mt)
#pragma unroll
    for (int nt = 0; nt < NT; ++nt) acc[mt][nt] = (f4){0.f, 0.f, 0.f, 0.f};

  // lane-invariant staging bases
  const unsigned short* whp = WThi + (long long)(bn + srow) * K + sslot;
  const unsigned short* wlp = WTlo + (long long)(bn + srow) * K + sslot;

  const unsigned short* ahp = nullptr;
  const unsigned short* alp = nullptr;
  if (COPYA) {
    ahp = (const unsigned short*)Av + (long long)z * bsA + (bm + srow) * (long long)lda + sslot;
    if (ASRC == 5)
      alp = (const unsigned short*)aux.p0 + (long long)z * bsA + (bm + srow) * (long long)lda + sslot;
  }

  // ds-write-mode A state (ASRC 3 / 4)
  float invdc = 1.f;
  float sv = 0.f, iv = 0.f;
  const float* apA = nullptr;
  const float* Prow_base = nullptr;
  const float* pxp_base = nullptr;
  if (!COPYA) {
    if (ASRC == 3) {
      Prow_base = aux.p0 + rowsrc * 384;
      pxp_base = aux.p1 + rowsrc * 128;
      sv = aux.p2[rowsrc];
      iv = aux.p3[rowsrc];
    } else {
      apA = (const float*)Av + (long long)z * bsA + rowsrc * lda;
      invdc = 1.f / fmaxf(aux.p0[rowsrc], 1.f);
    }
  }
  // swizzled LDS write offsets for ds-write-mode A
  const int swa = (arow >> 1) & 3;
  const int s0us = arow * 32 + (((2 * sel) ^ swa) << 3);
  const int s1us = arow * 32 + (((2 * sel + 1) ^ swa) << 3);

  // fragment-read swizzle: slot quad ^ ((row>>1)&3); row bits 1..2 == c16 bits
  const int swr8 = ((quad ^ ((c16 >> 1) & 3)) << 3);

  auto stageB = [&](int bi, int k0) {
#pragma unroll
    for (int ch = w; ch < NT; ch += 4) {
      gll16(whp + (long long)ch * 16 * K + k0, BhS + bi * BST + ch * 512);
      gll16(wlp + (long long)ch * 16 * K + k0, BlS + bi * BST + ch * 512);
    }
  };
  auto stageA = [&](int bi, int k0) {
#pragma unroll
    for (int ch = w; ch < 8; ch += 4) {
      gll16(ahp + (long long)ch * 16 * lda + k0, AhS + bi * 4096 + ch * 512);
      if (ASRC == 5)
        gll16(alp + (long long)ch * 16 * lda + k0, AlS + bi * 4096 + ch * 512);
    }
  };
  auto stageLoad = [&](int k0, float* va) {
    const int ck0 = k0 + sel * 16;
    if (ASRC == 3) {
      const float* Prow = Prow_base + ((ck0 >> 5) * 96) + (ck0 & 31);
      const float* pxp = pxp_base + ck0;
#pragma unroll
      for (int i = 0; i < 16; ++i)
        va[i] = pxp[i] + Prow[i] + sv * Prow[32 + i] + iv * Prow[64 + i] +
                aux.p4[ck0 + i];
    } else {
      *(float4*)&va[0] = *(const float4*)(apA + ck0);
      *(float4*)&va[4] = *(const float4*)(apA + ck0 + 4);
      *(float4*)&va[8] = *(const float4*)(apA + ck0 + 8);
      *(float4*)&va[12] = *(const float4*)(apA + ck0 + 12);
    }
  };
  auto stageWrite = [&](int bi, const float* va) {
    us8 hv0, hv1, lv0, lv1;
#pragma unroll
    for (int i = 0; i < 16; ++i) {
      float x = va[i];
      if (ASRC == 4) x *= invdc;
      unsigned short h = f2bf(x);
      unsigned short lo = f2bf(x - bf2f(h));
      if (i < 8) { hv0[i] = h; lv0[i] = lo; }
      else       { hv1[i - 8] = h; lv1[i - 8] = lo; }
    }
    *(us8*)&AhS[bi * 4096 + s0us] = hv0;
    *(us8*)&AhS[bi * 4096 + s1us] = hv1;
    *(us8*)&AlS[bi * 4096 + s0us] = lv0;
    *(us8*)&AlS[bi * 4096 + s1us] = lv1;
  };
  auto fragmfma = [&](int bi) {
    bfrag ah[2], al[2];
#pragma unroll
    for (int mt = 0; mt < 2; ++mt) {
      const int r = w * 32 + mt * 16 + c16;
      ah[mt] = *(const bfrag*)&AhS[bi * 4096 + r * 32 + swr8];
      if (SPLITA) al[mt] = *(const bfrag*)&AlS[bi * 4096 + r * 32 + swr8];
    }
#pragma unroll
    for (int nt = 0; nt < NT; ++nt) {
      const int r = nt * 16 + c16;
      bfrag bh = *(const bfrag*)&BhS[bi * BST + r * 32 + swr8];
      bfrag bl = *(const bfrag*)&BlS[bi * BST + r * 32 + swr8];
#pragma unroll
      for (int mt = 0; mt < 2; ++mt) {
        acc[mt][nt] = __builtin_amdgcn_mfma_f32_16x16x32_bf16(ah[mt], bh, acc[mt][nt], 0, 0, 0);
        if (SPLITA)
          acc[mt][nt] = __builtin_amdgcn_mfma_f32_16x16x32_bf16(al[mt], bh, acc[mt][nt], 0, 0, 0);
        acc[mt][nt] = __builtin_amdgcn_mfma_f32_16x16x32_bf16(ah[mt], bl, acc[mt][nt], 0, 0, 0);
      }
    }
  };

  float va[16];
  const int nk = K >> 5;

  // prologue: fill buffer 0
  if (COPYA) {
    stageA(0, 0);
    stageB(0, 0);
  } else {
    stageLoad(0, va);
    stageB(0, 0);
    stageWrite(0, va);
  }
  __syncthreads();

  for (int kt = 0; kt < nk; ++kt) {
    const int bi = kt & 1;
    const bool pf = (kt + 1 < nk);
    if (pf) {
      stageB(bi ^ 1, (kt + 1) << 5);
      if (COPYA) stageA(bi ^ 1, (kt + 1) << 5);
      else stageLoad((kt + 1) << 5, va);
    }
    fragmfma(bi);
    if (!COPYA && pf) stageWrite(bi ^ 1, va);
    __syncthreads();
  }

  // epilogue: C/D layout col=lane&15, row=quad*4+reg
#pragma unroll
  for (int nt = 0; nt < NT; ++nt) {
    int col = bn + nt * 16 + c16;
    if (col >= Nc) continue;
    float bv = BIAS ? bias[col] : 0.f;
#pragma unroll
    for (int mt = 0; mt < 2; ++mt) {
#pragma unroll
      for (int r = 0; r < 4; ++r) {
        long long row = bm + w * 32 + mt * 16 + quad * 4 + r;
        float v = acc[mt][nt][r] + bv;
        if (RELU) v = fmaxf(v, 0.f);
        C[row * ldc + col] = v;
      }
    }
  }
}

// ---------------------------------------------------------------------------
// Encoders -- h is produced directly as pre-split, pre-swizzled bf16 hi/lo
// (split-then-MFMA is math-identical to r1's on-the-fly split of fp32 h)
// ---------------------------------------------------------------------------
DEVFN void wsplit(float v, unsigned short* hi, unsigned short* lo, long long o)
{
  unsigned short h = f2bf(v);
  hi[o] = h;
  lo[o] = f2bf(v - bf2f(h));
}

__global__ void node_enc(const float* __restrict__ x, const float* __restrict__ Wa,
                         const float* __restrict__ ba,
                         unsigned short* __restrict__ hbh, unsigned short* __restrict__ hbl)
{
  int n = blockIdx.x, c = threadIdx.x; // 128
  float acc = ba[c];
#pragma unroll
  for (int k = 0; k < 11; ++k) acc += x[n * 11 + k] * Wa[k * 128 + c];
  wsplit(fmaxf(acc, 0.f), hbh, hbl, ((long long)n << 7) + swk(n, c));
}

// writes split hi/lo DIRECTLY in CSR slot order, PRE-SWIZZLED for gll staging
__global__ void edge_enc(const float* __restrict__ eat, const float* __restrict__ We,
                         const float* __restrict__ be, const int* __restrict__ slot_of,
                         unsigned short* __restrict__ eh, unsigned short* __restrict__ el)
{
  int e = blockIdx.x, c = threadIdx.x; // 128
  float acc = be[c];
#pragma unroll
  for (int k = 0; k < 4; ++k) acc += eat[e * 4 + k] * We[k * 128 + c];
  float v = fmaxf(acc, 0.f);
  long long slot = slot_of[e];
  wsplit(v, eh, el, slot * 128 + swk((int)slot, c));
}

// ---------------------------------------------------------------------------
// CSR build: count -> scan (also inits cursor + s/invs) -> scatter
// ---------------------------------------------------------------------------
__global__ void count_deg(const int* __restrict__ dst, int* __restrict__ degi)
{
  int e = blockIdx.x * 256 + threadIdx.x;
  if (e < EE) atomicAdd(&degi[dst[e]], 1);
}

__global__ __launch_bounds__(1024) void scan_k(const int* __restrict__ degi,
                                               int* __restrict__ row_off,
                                               int* __restrict__ cursor,
                                               float* __restrict__ s_arr,
                                               float* __restrict__ invs)
{
  __shared__ int tsum[1024];
  int t = threadIdx.x;
  int local[16];
  int base = t * 16;
  int s = 0;
#pragma unroll
  for (int i = 0; i < 16; ++i) { local[i] = s; s += degi[base + i]; }
  tsum[t] = s;
  __syncthreads();
  for (int off = 1; off < 1024; off <<= 1) {
    int v = (t >= off) ? tsum[t - off] : 0;
    __syncthreads();
    tsum[t] += v;
    __syncthreads();
  }
  int prev = (t == 0) ? 0 : tsum[t - 1];
#pragma unroll
  for (int i = 0; i < 16; ++i) {
    int start = prev + local[i];
    row_off[base + i] = start;
    cursor[base + i] = start;
    int cnt = degi[base + i];
    float degc = fmaxf((float)cnt, 1.f);
    float sv = logf(degc + 1.f) / AVG_LOG_F;
    s_arr[base + i] = sv;
    invs[base + i] = 1.f / sv;
  }
  if (t == 1023) row_off[NN] = tsum[1023];
}

__global__ void scatter_k(const int* __restrict__ src, const int* __restrict__ dst,
                          int* __restrict__ cursor,
                          int* __restrict__ slot_of, int* __restrict__ esrc)
{
  int e = blockIdx.x * 256 + threadIdx.x;
  if (e >= EE) return;
  int d = dst[e];
  int slot = atomicAdd(&cursor[d], 1);
  slot_of[e] = slot;
  esrc[slot] = src[e];
}

// ---------------------------------------------------------------------------
// Weight folds (fp32) + transpose-split packers (fp32 -> bf16 hi/lo, [N][K])
// All packed operand arrays are PRE-SWIZZLED (swk) for global_load_lds staging.
// ---------------------------------------------------------------------------
__global__ __launch_bounds__(512) void fold_w(const float* __restrict__ We_conv,
                                              const float* __restrict__ Wpre,
                                              float* __restrict__ Wfold)
{
  int k = blockIdx.x & 127, l = blockIdx.x >> 7;
  int t = threadIdx.x >> 7, f = threadIdx.x & 127;
  const float* wc = We_conv + (long long)(l * 128 + k) * 128;
  const float* wp = Wpre + ((long long)((l * 4 + t) * 384 + 256)) * 128 + f;
  float acc = 0.f;
  for (int j = 0; j < 128; ++j) acc += wc[j] * wp[(long long)j * 128];
  Wfold[((long long)(l * 128 + k)) * 512 + threadIdx.x] = acc;
}

__global__ __launch_bounds__(512) void fold_b(const float* __restrict__ be_conv,
                                              const float* __restrict__ Wpre,
                                              const float* __restrict__ bpre,
                                              float* __restrict__ bfold)
{
  int l = blockIdx.x;
  int t = threadIdx.x >> 7, f = threadIdx.x & 127;
  const float* bc = be_conv + l * 128;
  const float* wp = Wpre + ((long long)((l * 4 + t) * 384 + 256)) * 128 + f;
  float acc = bpre[(l * 4 + t) * 128 + f];
  for (int j = 0; j < 128; ++j) acc += bc[j] * wp[(long long)j * 128];
  bfold[l * 512 + threadIdx.x] = acc;
}

// preABT[lt][n(256)][k(128)] (swizzled)
__global__ void tsplit_preAB(const float* __restrict__ Wpre,
                             unsigned short* __restrict__ hi, unsigned short* __restrict__ lo)
{
  int b = blockIdx.x; // 12*256
  int lt = b >> 8, n = b & 255, k = threadIdx.x; // 128
  int row = (n < 128) ? k : (128 + k);
  int f = n & 127;
  float v = Wpre[((long long)(lt * 384 + row)) * 128 + f];
  wsplit(v, hi, lo, ((long long)(lt * 256 + n)) * 128 + swk(n, k));
}

// WfoldT[lt][n(128)][k(128)] from Wfold[l][k][t*128+n] (swizzled)
__global__ void tsplit_fold(const float* __restrict__ Wfold,
                            unsigned short* __restrict__ hi, unsigned short* __restrict__ lo)
{
  int b = blockIdx.x; // 12*128
  int lt = b >> 7, n = b & 127, k = threadIdx.x; // 128
  int l = lt >> 2, t = lt & 3;
  float v = Wfold[((long long)(l * 128 + k)) * 512 + t * 128 + n];
  wsplit(v, hi, lo, ((long long)(lt * 128 + n)) * 128 + swk(n, k));
}

// post3T[lt][c(128, pad>=96 zero)][r(512)] (swizzled)
__global__ __launch_bounds__(512) void tsplit_post3(const float* __restrict__ Wpost,
                                                    unsigned short* __restrict__ hi,
                                                    unsigned short* __restrict__ lo)
{
  int b = blockIdx.x; // 12*128
  int lt = b >> 7, c = b & 127;
  int r = threadIdx.x; // 512
  float v = 0.f;
  if (c < 96)
    v = Wpost[((long long)(lt * 1664 + 128 + (c >> 5) * 512 + r)) * 32 + (c & 31)];
  wsplit(v, hi, lo, ((long long)(lt * 128 + c)) * 512 + swk(c, r));
}

// WxT[l][c(128)][k(128)] (swizzled)
__global__ void tsplit_wx(const float* __restrict__ Wpost,
                          unsigned short* __restrict__ hi, unsigned short* __restrict__ lo)
{
  int b = blockIdx.x; // 3*128
  int l = b >> 7, c = b & 127, k = threadIdx.x;
  float v = Wpost[((long long)((l * 4 + (c >> 5)) * 1664 + k)) * 32 + (c & 31)];
  wsplit(v, hi, lo, ((long long)(l * 128 + c)) * 128 + swk(c, k));
}

// WlinT[l][n][k] (swizzled)
__global__ void tsplit_lin(const float* __restrict__ Wlin,
                           unsigned short* __restrict__ hi, unsigned short* __restrict__ lo)
{
  int b = blockIdx.x; // 3*128
  int l = b >> 7, n = b & 127, k = threadIdx.x;
  float v = Wlin[((long long)(l * 128 + k)) * 128 + n];
  wsplit(v, hi, lo, ((long long)(l * 128 + n)) * 128 + swk(n, k));
}

// W1T[n(64)][k(128)] (swizzled)
__global__ void tsplit_w1(const float* __restrict__ W1,
                          unsigned short* __restrict__ hi, unsigned short* __restrict__ lo)
{
  int n = blockIdx.x; // 64
  int k = threadIdx.x; // 128
  wsplit(W1[k * 64 + n], hi, lo, (long long)n * 128 + swk(n, k));
}

// ---------------------------------------------------------------------------
// Per-tower aggregation, both towers of the pair folded into one block.
// Block 128 = 2 nodes x 2 towers x 32 lanes(x4 ch float4). Edges processed in
// chunks of 4: esrc batch-loaded first, then 8 independent float4 loads in
// flight (breaks the esrc->ABs dependent-latency chain). Accumulation order
// per channel is IDENTICAL to the scalar version (bit-identical numerics).
// Output aggs bf16 [N][512], PRE-SWIZZLED (swk) for gll staging by the P gemm.
// ---------------------------------------------------------------------------
__global__ __launch_bounds__(128) void aggregate_ct(
    const float* __restrict__ ABb, const float* __restrict__ Mb,
    const int* __restrict__ row_off, const int* __restrict__ esrc,
    unsigned short* __restrict__ aggs, int pair)
{
  const int tid = threadIdx.x;
  const int c4 = (tid & 31) << 2;
  const int z = (tid >> 5) & 1;
  const int n = blockIdx.x * 2 + (tid >> 6);
  const float* M = Mb + (long long)z * EE * 128;
  const float* ABs = ABb + (long long)(pair * 2 + z) * NN * 256;
  unsigned short* ag = aggs + (long long)(pair * 2 + z) * NN * 512;
  const int beg = row_off[n], end = row_off[n + 1];
  const int cnt = end - beg;
  const float degc = fmaxf((float)cnt, 1.0f);
  const float4 aval = *(const float4*)&ABs[(long long)n * 256 + c4];

  float sum[4] = {0.f, 0.f, 0.f, 0.f}, sq[4] = {0.f, 0.f, 0.f, 0.f};
  float mn[4] = {INFINITY, INFINITY, INFINITY, INFINITY};
  float mx[4] = {-INFINITY, -INFINITY, -INFINITY, -INFINITY};

  auto upd = [&](const float4& mv, const float4& bv) {
    float m0 = aval.x + bv.x + mv.x;
    float m1 = aval.y + bv.y + mv.y;
    float m2 = aval.z + bv.z + mv.z;
    float m3 = aval.w + bv.w + mv.w;
    sum[0] += m0; sq[0] += m0 * m0; mn[0] = fminf(mn[0], m0); mx[0] = fmaxf(mx[0], m0);
    sum[1] += m1; sq[1] += m1 * m1; mn[1] = fminf(mn[1], m1); mx[1] = fmaxf(mx[1], m1);
    sum[2] += m2; sq[2] += m2 * m2; mn[2] = fminf(mn[2], m2); mx[2] = fmaxf(mx[2], m2);
    sum[3] += m3; sq[3] += m3 * m3; mn[3] = fminf(mn[3], m3); mx[3] = fmaxf(mx[3], m3);
  };

  for (int s0 = beg; s0 < end; s0 += 4) {
    const int e1 = min(s0 + 1, end - 1);
    const int e2 = min(s0 + 2, end - 1);
    const int e3 = min(s0 + 3, end - 1);
    const int sA = esrc[s0], sB = esrc[e1], sC = esrc[e2], sD = esrc[e3];
    const float4 mA = *(const float4*)&M[(long long)s0 * 128 + c4];
    const float4 mB = *(const float4*)&M[(long long)e1 * 128 + c4];
    const float4 mC = *(const float4*)&M[(long long)e2 * 128 + c4];
    const float4 mD = *(const float4*)&M[(long long)e3 * 128 + c4];
    const float4 bA = *(const float4*)&ABs[(long long)sA * 256 + 128 + c4];
    const float4 bB = *(const float4*)&ABs[(long long)sB * 256 + 128 + c4];
    const float4 bC = *(const float4*)&ABs[(long long)sC * 256 + 128 + c4];
    const float4 bD = *(const float4*)&ABs[(long long)sD * 256 + 128 + c4];
    upd(mA, bA);
    if (s0 + 1 < end) upd(mB, bB);
    if (s0 + 2 < end) upd(mC, bC);
    if (s0 + 3 < end) upd(mD, bD);
  }

  const float inv = 1.0f / degc;
  float mean[4], stdv[4];
#pragma unroll
  for (int j = 0; j < 4; ++j) {
    mean[j] = sum[j] * inv;
    float var = sq[j] * inv - mean[j] * mean[j];
    stdv[j] = sqrtf(fmaxf(var, 0.f) + 1e-5f);
    if (cnt == 0) { mn[j] = 0.f; mx[j] = 0.f; }
  }
  const int sc = swk(n, c4);
  const long long base = (long long)n * 512 + sc;
  ushort4 o;
  o.x = f2bf(mean[0]); o.y = f2bf(mean[1]); o.z = f2bf(mean[2]); o.w = f2bf(mean[3]);
  *(ushort4*)&ag[base] = o;
  o.x = f2bf(mn[0]); o.y = f2bf(mn[1]); o.z = f2bf(mn[2]); o.w = f2bf(mn[3]);
  *(ushort4*)&ag[base + 128] = o;
  o.x = f2bf(mx[0]); o.y = f2bf(mx[1]); o.z = f2bf(mx[2]); o.w = f2bf(mx[3]);
  *(ushort4*)&ag[base + 256] = o;
  o.x = f2bf(stdv[0]); o.y = f2bf(stdv[1]); o.z = f2bf(stdv[2]); o.w = f2bf(stdv[3]);
  *(ushort4*)&ag[base + 384] = o;
}

// ---------------------------------------------------------------------------
// BatchNorm stats over N rows, 128 cols + coefficient precompute + apply
// ---------------------------------------------------------------------------
__global__ __launch_bounds__(256) void bn_partial(const float* __restrict__ y,
                                                  float* __restrict__ colsum,
                                                  float* __restrict__ colsq)
{
  int c = threadIdx.x & 127;
  int rh = threadIdx.x >> 7;
  int r0 = blockIdx.x * 128;
  float s = 0.f, q = 0.f;
  for (int r = r0 + rh; r < r0 + 128; r += 2) {
    float v = y[(long long)r * 128 + c];
    s += v;
    q += v * v;
  }
  __shared__ float ps[256], pq[256];
  ps[threadIdx.x] = s;
  pq[threadIdx.x] = q;
  __syncthreads();
  if (threadIdx.x < 128) {
    atomicAdd(&colsum[c], ps[c] + ps[c + 128]);
    atomicAdd(&colsq[c], pq[c] + pq[c + 128]);
  }
}

// coef[c] = g*rsqrt(var+eps); coef[128+c] = b - mean*scale  (BN as FMA)
__global__ void bn_coef(const float* __restrict__ colsum, const float* __restrict__ colsq,
                        const float* __restrict__ g, const float* __restrict__ b,
                        float* __restrict__ coef)
{
  int c = threadIdx.x; // 128
  float mean = colsum[c] * (1.f / 16384.f);
  float var = colsq[c] * (1.f / 16384.f) - mean * mean;
  float sc = g[c] * rsqrtf(var + 1e-5f);
  coef[c] = sc;
  coef[128 + c] = b[c] - mean * sc;
}

// hbf = split(relu(y*scale + shift)) pre-swizzled
__global__ __launch_bounds__(256) void bn_apply(const float* __restrict__ y,
                                                const float* __restrict__ coef,
                                                unsigned short* __restrict__ hbh,
                                                unsigned short* __restrict__ hbl)
{
  int idx = blockIdx.x * 256 + threadIdx.x; // n*128+c
  int c = idx & 127, n = idx >> 7;
  float v = fmaxf(y[idx] * coef[c] + coef[128 + c], 0.f);
  wsplit(v, hbh, hbl, ((long long)n << 7) + swk(n, c));
}

// ---------------------------------------------------------------------------
// Global mean pool (BN+ReLU fused) + head
// ---------------------------------------------------------------------------
__global__ void pool_add(const float* __restrict__ y, const float* __restrict__ colsum,
                         const float* __restrict__ colsq, const float* __restrict__ g,
                         const float* __restrict__ b, const int* __restrict__ batch,
                         float* __restrict__ pooled, float* __restrict__ cntf)
{
  int n = blockIdx.x, c = threadIdx.x;
  float mean = colsum[c] * (1.f / 16384.f);
  float var = colsq[c] * (1.f / 16384.f) - mean * mean;
  float v = fmaxf((y[(long long)n * 128 + c] - mean) * rsqrtf(var + 1e-5f) * g[c] + b[c], 0.f);
  int bb = batch[n];
  atomicAdd(&pooled[(long long)bb * 128 + c], v);
  if (c == 0) atomicAdd(&cntf[bb], 1.f);
}

__global__ __launch_bounds__(256) void zstats(const float* __restrict__ z,
                                              float* __restrict__ zm, float* __restrict__ zv)
{
  int j = blockIdx.x; // 64 cols
  float s = 0.f, q = 0.f;
  for (int g = threadIdx.x; g < GG; g += 256) {
    float v = z[g * 64 + j];
    s += v;
    q += v * v;
  }
  __shared__ float ps[256], pq[256];
  ps[threadIdx.x] = s;
  pq[threadIdx.x] = q;
  __syncthreads();
  for (int st = 128; st > 0; st >>= 1) {
    if (threadIdx.x < st) {
      ps[threadIdx.x] += ps[threadIdx.x + st];
      pq[threadIdx.x] += pq[threadIdx.x + st];
    }
    __syncthreads();
  }
  if (threadIdx.x == 0) {
    float m = ps[0] / (float)GG;
    zm[j] = m;
    zv[j] = pq[0] / (float)GG - m * m;
  }
}

__global__ void final_out(const float* __restrict__ z, const float* __restrict__ zm,
                          const float* __restrict__ zv, const float* __restrict__ hg,
                          const float* __restrict__ hb, const float* __restrict__ W2,
                          const float* __restrict__ b2, float* __restrict__ out)
{
  int g = blockIdx.x;
  int j = threadIdx.x; // 64 = one wave
  float v = (z[g * 64 + j] - zm[j]) * rsqrtf(zv[j] + 1e-5f) * hg[j] + hb[j];
  float t = v * W2[j];
#pragma unroll
  for (int off = 32; off > 0; off >>= 1) t += __shfl_down(t, off);
  if (j == 0) out[g] = t + b2[0];
}

// ---------------------------------------------------------------------------
extern "C" void kernel_launch(void* const* d_in, const int* in_sizes, int n_in,
                              void* d_out, int out_size, void* d_ws, size_t ws_size,
                              hipStream_t stream)
{
  (void)in_sizes; (void)n_in; (void)out_size;
  const float* x = (const float*)d_in[0];
  const float* eat = (const float*)d_in[1];
  const int* ei = (const int*)d_in[2];
  const int* batch = (const int*)d_in[3];
  const float* Wa = (const float*)d_in[4];
  const float* ba = (const float*)d_in[5];
  const float* We = (const float*)d_in[6];
  const float* be = (const float*)d_in[7];
  const float* We_conv = (const float*)d_in[8];
  const float* be_conv = (const float*)d_in[9];
  const float* Wpre = (const float*)d_in[10];
  const float* bpre = (const float*)d_in[11];
  const float* Wpost = (const float*)d_in[12];
  const float* bpost = (const float*)d_in[13];
  const float* Wlin = (const float*)d_in[14];
  const float* blin = (const float*)d_in[15];
  const float* bng = (const float*)d_in[16];
  const float* bnb = (const float*)d_in[17];
  const float* W1 = (const float*)d_in[18];
  const float* b1 = (const float*)d_in[19];
  const float* hg = (const float*)d_in[20];
  const float* hb = (const float*)d_in[21];
  const float* W2 = (const float*)d_in[22];
  const float* b2 = (const float*)d_in[23];
  float* out = (float*)d_out;

  const int* srcI = ei;
  const int* dstI = ei + EE;

  char* ws = (char*)d_ws;
  size_t off = 0;
  auto alloc = [&](size_t bytes) -> char* {
    char* p = ws + off;
    off += (bytes + 255) & ~(size_t)255;
    return p;
  };

  unsigned short* hbf_h = (unsigned short*)alloc((size_t)NN * 128 * 2); // pre-split h
  unsigned short* hbf_l = (unsigned short*)alloc((size_t)NN * 128 * 2);
  float* hn = (float*)alloc((size_t)NN * 128 * 4);
  unsigned short* eah = (unsigned short*)alloc((size_t)EE * 128 * 2); // CSR slot order
  unsigned short* eal = (unsigned short*)alloc((size_t)EE * 128 * 2);
  float* AB = (float*)alloc((size_t)4 * NN * 256 * 4);       // [T][N][256] fp32
  char* Mregion = alloc((size_t)2 * EE * 128 * 4);           // C pair; later P|Px
  float* Mb = (float*)Mregion;
  float* P = (float*)Mregion;                                 // [N][384]
  float* Px = (float*)(Mregion + (size_t)NN * 384 * 4);       // [N][128]
  unsigned short* aggt = (unsigned short*)alloc((size_t)4 * NN * 512 * 2); // bf16 [T][N][512]
  float* s_arr = (float*)alloc((size_t)NN * 4);
  float* invs = (float*)alloc((size_t)NN * 4);
  int* degi = (int*)alloc((size_t)NN * 4);
  int* cursor = (int*)alloc((size_t)NN * 4);
  int* row_off = (int*)alloc((size_t)(NN + 1) * 4);
  int* slot_of = (int*)alloc((size_t)EE * 4);
  int* esrc = (int*)alloc((size_t)EE * 4);
  float* WfoldF = (float*)alloc((size_t)3 * 128 * 512 * 4);
  float* bfold = (float*)alloc((size_t)3 * 512 * 4);
  unsigned short* preABT_h = (unsigned short*)alloc((size_t)12 * 256 * 128 * 2);
  unsigned short* preABT_l = (unsigned short*)alloc((size_t)12 * 256 * 128 * 2);
  unsigned short* foldT_h = (unsigned short*)alloc((size_t)12 * 128 * 128 * 2);
  unsigned short* foldT_l = (unsigned short*)alloc((size_t)12 * 128 * 128 * 2);
  unsigned short* post3T_h = (unsigned short*)alloc((size_t)12 * 128 * 512 * 2);
  unsigned short* post3T_l = (unsigned short*)alloc((size_t)12 * 128 * 512 * 2);
  unsigned short* wxT_h = (unsigned short*)alloc((size_t)3 * 128 * 128 * 2);
  unsigned short* wxT_l = (unsigned short*)alloc((size_t)3 * 128 * 128 * 2);
  unsigned short* linT_h = (unsigned short*)alloc((size_t)3 * 128 * 128 * 2);
  unsigned short* linT_l = (unsigned short*)alloc((size_t)3 * 128 * 128 * 2);
  unsigned short* w1T_h = (unsigned short*)alloc((size_t)64 * 128 * 2);
  unsigned short* w1T_l = (unsigned short*)alloc((size_t)64 * 128 * 2);
  float* colstats = (float*)alloc(512 * 4); // two ping-pong buffers of 256
  float* bncoef = (float*)alloc(256 * 4);
  float* pooled = (float*)alloc((size_t)GG * 128 * 4);
  float* cntf = (float*)alloc((size_t)GG * 4);
  float* zbuf = (float*)alloc((size_t)GG * 64 * 4);
  float* zm = (float*)alloc(64 * 4);
  float* zv = (float*)alloc(64 * 4);

  if (off > ws_size) return; // bail rather than corrupt

  float* cs[2] = {colstats, colstats + 256};

  // ---- graph structure ----
  hipMemsetAsync(degi, 0, (size_t)NN * 4, stream);
  count_deg<<<EE / 256, 256, 0, stream>>>(dstI, degi);
  scan_k<<<1, 1024, 0, stream>>>(degi, row_off, cursor, s_arr, invs);
  scatter_k<<<EE / 256, 256, 0, stream>>>(srcI, dstI, cursor, slot_of, esrc);

  // ---- encoders + weight folds/packing ----
  node_enc<<<NN, 128, 0, stream>>>(x, Wa, ba, hbf_h, hbf_l);
  edge_enc<<<EE, 128, 0, stream>>>(eat, We, be, slot_of, eah, eal); // after scatter_k
  fold_w<<<384, 512, 0, stream>>>(We_conv, Wpre, WfoldF);
  fold_b<<<3, 512, 0, stream>>>(be_conv, Wpre, bpre, bfold);
  tsplit_preAB<<<12 * 256, 128, 0, stream>>>(Wpre, preABT_h, preABT_l);
  tsplit_fold<<<12 * 128, 128, 0, stream>>>(WfoldF, foldT_h, foldT_l);
  tsplit_post3<<<12 * 128, 512, 0, stream>>>(Wpost, post3T_h, post3T_l);
  tsplit_wx<<<3 * 128, 128, 0, stream>>>(Wpost, wxT_h, wxT_l);
  tsplit_lin<<<3 * 128, 128, 0, stream>>>(Wlin, linT_h, linT_l);
  tsplit_w1<<<64, 128, 0, stream>>>(W1, w1T_h, w1T_l);

  for (int l = 0; l < 3; ++l) {
    hipMemsetAsync(cs[l & 1], 0, 256 * 4, stream);
    // AB all towers: [N,128] @ [128,256] (z=4) -> fp32 [T][N][256]; A = hbf copy
    mgemm<5, 8, false, false><<<dim3(NN / 128, 2, 4), 256, 0, stream>>>(
        hbf_h, preABT_h + (size_t)l * 4 * 256 * 128, preABT_l + (size_t)l * 4 * 256 * 128,
        nullptr, AB, AuxP{(const float*)hbf_l, nullptr, nullptr, nullptr, nullptr},
        256, 128, 128, 256, 0, (long long)256 * 128, (long long)NN * 256, 0);
    for (int pair = 0; pair < 2; ++pair) {
      int lt0 = l * 4 + pair * 2;
      // C (pair of towers, streaming, CSR-ordered ea): [E,128]@[128,128]+bfold
      mgemm<5, 8, true, false><<<dim3(EE / 128, 1, 2), 256, 0, stream>>>(
          eah, foldT_h + (size_t)lt0 * 128 * 128, foldT_l + (size_t)lt0 * 128 * 128,
          bfold + l * 512 + pair * 256, Mb,
          AuxP{(const float*)eal, nullptr, nullptr, nullptr, nullptr},
          128, 128, 128, 128, 0, (long long)128 * 128, (long long)EE * 128, 128);
      // stats over m = (A + B[src]) + C  (C streaming); both towers per block
      aggregate_ct<<<dim3(NN / 2, 1, 1), 128, 0, stream>>>(AB, Mb, row_off, esrc, aggt, pair);
    }
    // P all towers: bf16 [N,512] @ [512,96] (z=4, exact 96-col tile) -> P[:, z*96..]
    mgemm<1, 6, false, false><<<dim3(NN / 128, 1, 4), 256, 0, stream>>>(
        aggt, post3T_h + (size_t)l * 4 * 128 * 512, post3T_l + (size_t)l * 4 * 128 * 512,
        nullptr, P, AuxP{}, 96, 512, 512, 384,
        (long long)NN * 512, (long long)128 * 512, 96, 0);
    // Px: [N,128] @ [128,128]; A = hbf copy
    mgemm<5, 8, false, false><<<dim3(NN / 128, 1, 1), 256, 0, stream>>>(
        hbf_h, wxT_h + (size_t)l * 128 * 128, wxT_l + (size_t)l * 128 * 128,
        nullptr, Px, AuxP{(const float*)hbf_l, nullptr, nullptr, nullptr, nullptr},
        128, 128, 128, 128, 0, 0, 0, 0);
    // lin (post-combine fused in A-staging): [N,128] @ [128,128] + blin -> hn
    mgemm<3, 8, true, false><<<dim3(NN / 128, 1, 1), 256, 0, stream>>>(
        nullptr, linT_h + (size_t)l * 128 * 128, linT_l + (size_t)l * 128 * 128,
        blin + l * 128, hn, AuxP{P, Px, s_arr, invs, bpost + l * 128},
        128, 128, 128, 128, 0, 0, 0, 0);
    bn_partial<<<128, 256, 0, stream>>>(hn, cs[l & 1], cs[l & 1] + 128);
    if (l < 2) {
      bn_coef<<<1, 128, 0, stream>>>(cs[l & 1], cs[l & 1] + 128,
                                     bng + l * 128, bnb + l * 128, bncoef);
      bn_apply<<<NN * 128 / 256, 256, 0, stream>>>(hn, bncoef, hbf_h, hbf_l);
    }
  }

  // ---- pooling (BN+ReLU fused) + head ----
  hipMemsetAsync(pooled, 0, (size_t)GG * 128 * 4, stream);
  hipMemsetAsync(cntf, 0, (size_t)GG * 4, stream);
  pool_add<<<NN, 128, 0, stream>>>(hn, cs[0], cs[0] + 128,
                                   bng + 2 * 128, bnb + 2 * 128, batch, pooled, cntf);
  mgemm<4, 4, true, true><<<dim3(GG / 128, 1, 1), 256, 0, stream>>>(
      pooled, w1T_h, w1T_l, b1, zbuf,
      AuxP{cntf, nullptr, nullptr, nullptr, nullptr}, 64, 128, 128, 64, 0, 0, 0, 0);
  zstats<<<64, 256, 0, stream>>>(zbuf, zm, zv);
  final_out<<<GG, 64, 0, stream>>>(zbuf, zm, zv, hg, hb, W2, b2, out);
}

// Round 7
// 763.121 us; speedup vs baseline: 1.2452x; 1.1234x over previous
//
#include <hip/hip_runtime.h>
#include <hip/hip_bf16.h>

#define DEVFN static __device__ __forceinline__

constexpr int NN = 16384;
constexpr int EE = 65536;
constexpr int GG = 512;
constexpr float AVG_LOG_F = 1.0227308671603782f; // (sum d*log d, d=1..4, hist 1,2,3,4)/10

typedef __attribute__((ext_vector_type(8))) short bfrag;          // 8 bf16 = 4 VGPR
typedef __attribute__((ext_vector_type(8))) unsigned short us8;   // 8 bf16 store
typedef __attribute__((ext_vector_type(4))) float f4;             // MFMA C/D

// fp32 -> bf16 (RNE) bit helpers
DEVFN unsigned short f2bf(float f) {
  unsigned int u = __float_as_uint(f);
  unsigned int r = (u + 0x7fffu + ((u >> 16) & 1u)) >> 16;
  return (unsigned short)r;
}
DEVFN float bf2f(unsigned short s) { return __uint_as_float(((unsigned int)s) << 16); }

// fp32 <-> fp16 (RNE, native v_cvt). fp16's 10 mantissa bits keep the slab
// rounding ~8x finer than bf16 at the same bandwidth (r5/r6 post-mortem:
// bf16 slabs cost +0.0097 absmax; fp16 predicted +0.0012).
DEVFN unsigned short f2h(float f) {
  _Float16 h = (_Float16)f;
  unsigned short r; __builtin_memcpy(&r, &h, 2); return r;
}
DEVFN float h2f(unsigned short s) {
  _Float16 h; __builtin_memcpy(&h, &s, 2); return (float)h;
}

// load 4 fp16 -> float4
DEVFN float4 ld4hf(const unsigned short* p) {
  ushort4 u = *(const ushort4*)p;
  float4 r;
  r.x = h2f(u.x); r.y = h2f(u.y); r.z = h2f(u.z); r.w = h2f(u.w);
  return r;
}

// XOR swizzle for packed bf16 [R][K] operand arrays staged with global_load_lds:
// element (row,k) lives at row*K + swk(row,k). Within each 32-wide K window the
// four 8-element slots are permuted by (row>>1)&3 so a wave's ds_read_b128
// fragment reads become a permutation of a contiguous 1 KB region ->
// bank-conflict-free. global_load_lds copies LINEARLY, so the swizzle is baked
// into the packed global layout (both-sides rule, #21).
DEVFN int swk(int row, int k) {
  return (k & ~31) + ((((k >> 3) & 3) ^ ((row >> 1) & 3)) << 3) + (k & 7);
}

// async global->LDS, 16 B per lane; LDS dest = wave-uniform base + lane*16
DEVFN void gll16(const unsigned short* g, unsigned short* l) {
  __builtin_amdgcn_global_load_lds(
      (__attribute__((address_space(1))) void*)g,
      (__attribute__((address_space(3))) void*)l, 16, 0, 0);
}

// aux pointer bundle for fused A-staging modes
struct AuxP {
  const float* p0;
  const float* p1;
  const float* p2;
  const float* p3;
  const float* p4;
};

// ---------------------------------------------------------------------------
// Split-bf16 MFMA GEMM: C[M,Nc] = A[M,K] @ W[K,Nc](fp32, pre-split hi/lo)
// A-staging modes (ASRC):
//   1: bf16 ushort input (pre-swizzled), gll copy, A hi only (2 MFMA)
//   3: PNA post-combine fused: A = Px + P_id + s*P_amp + invs*P_att + bpost
//   4: fp32 / rowcount (p0=cntf) -- global mean pool divide (ds-write path)
//   5: pre-split hi/lo ushort arrays (Av=hi, p0=lo, pre-swizzled), gll copy
// B (WThi/WTlo) pre-swizzled packed, staged via global_load_lds.
// OHALF: epilogue stores fp16 (slabs consumed by aggregate_ct only).
// NT = column fragments (tile N = NT*16). r1 sync structure (measured best):
// double-buffered LDS, stage tile k+1 via gll before MFMA on tile k, one
// __syncthreads per step (its vmcnt/lgkm drain completes the prefetch).
// Block 256 = 4 waves; tile M=128, BK=32. M%128==0, K%32==0, col<Nc guarded.
// ---------------------------------------------------------------------------
template <int ASRC, int NT, bool BIAS, bool RELU, bool OHALF>
__global__ __launch_bounds__(256) void mgemm(
    const void* __restrict__ Av, const unsigned short* __restrict__ WThi,
    const unsigned short* __restrict__ WTlo, const float* __restrict__ bias,
    float* __restrict__ C, AuxP aux,
    int Nc, int K, int lda, int ldc,
    long long bsA, long long bsW, long long bsC, int bsBias)
{
  constexpr bool SPLITA = (ASRC != 1);
  constexpr bool COPYA = (ASRC == 1 || ASRC == 5);
  constexpr int BST = NT * 16 * 32; // ushorts per B buffer

  const int z = blockIdx.z;
  WThi += (long long)z * bsW;
  WTlo += (long long)z * bsW;
  if (BIAS) bias += (long long)z * bsBias;
  float* Cf = C + (OHALF ? 0 : (long long)z * bsC);
  unsigned short* Cu = (unsigned short*)C + (OHALF ? (long long)z * bsC : 0);

  __shared__ __align__(16) unsigned short AhS[2 * 128 * 32];
  __shared__ __align__(16) unsigned short AlS[SPLITA ? 2 * 128 * 32 : 8];
  __shared__ __align__(16) unsigned short BhS[2 * BST];
  __shared__ __align__(16) unsigned short BlS[2 * BST];

  const int tid = threadIdx.x;
  const long long bm = (long long)blockIdx.x * 128;
  const int bn = blockIdx.y * (NT * 16);
  const int w = tid >> 6;
  const int lane = tid & 63;
  const int quad = lane >> 4;
  const int c16 = lane & 15;
  const int srow = lane >> 2;        // staging row within 16-row chunk
  const int sslot = (lane & 3) << 3; // staging slot (ushort offset)

  // ds-write-mode indices: each thread produces 16 A elements of one row-half
  const int arow = tid >> 1;
  const int sel = tid & 1;
  const long long rowsrc = bm + arow;

  f4 acc[2][NT];
#pragma unroll
  for (int mt = 0; mt < 2; ++mt)
#pragma unroll
    for (int nt = 0; nt < NT; ++nt) acc[mt][nt] = (f4){0.f, 0.f, 0.f, 0.f};

  // lane-invariant staging bases
  const unsigned short* whp = WThi + (long long)(bn + srow) * K + sslot;
  const unsigned short* wlp = WTlo + (long long)(bn + srow) * K + sslot;

  const unsigned short* ahp = nullptr;
  const unsigned short* alp = nullptr;
  if (COPYA) {
    ahp = (const unsigned short*)Av + (long long)z * bsA + (bm + srow) * (long long)lda + sslot;
    if (ASRC == 5)
      alp = (const unsigned short*)aux.p0 + (long long)z * bsA + (bm + srow) * (long long)lda + sslot;
  }

  // ds-write-mode A state (ASRC 3 / 4)
  float invdc = 1.f;
  float sv = 0.f, iv = 0.f;
  const float* apA = nullptr;
  const float* Prow_base = nullptr;
  const float* pxp_base = nullptr;
  if (!COPYA) {
    if (ASRC == 3) {
      Prow_base = aux.p0 + rowsrc * 384;
      pxp_base = aux.p1 + rowsrc * 128;
      sv = aux.p2[rowsrc];
      iv = aux.p3[rowsrc];
    } else {
      apA = (const float*)Av + (long long)z * bsA + rowsrc * lda;
      invdc = 1.f / fmaxf(aux.p0[rowsrc], 1.f);
    }
  }
  // swizzled LDS write offsets for ds-write-mode A
  const int swa = (arow >> 1) & 3;
  const int s0us = arow * 32 + (((2 * sel) ^ swa) << 3);
  const int s1us = arow * 32 + (((2 * sel + 1) ^ swa) << 3);

  // fragment-read swizzle: slot quad ^ ((row>>1)&3); row bits 1..2 == c16 bits
  const int swr8 = ((quad ^ ((c16 >> 1) & 3)) << 3);

  auto stageB = [&](int bi, int k0) {
#pragma unroll
    for (int ch = w; ch < NT; ch += 4) {
      gll16(whp + (long long)ch * 16 * K + k0, BhS + bi * BST + ch * 512);
      gll16(wlp + (long long)ch * 16 * K + k0, BlS + bi * BST + ch * 512);
    }
  };
  auto stageA = [&](int bi, int k0) {
#pragma unroll
    for (int ch = w; ch < 8; ch += 4) {
      gll16(ahp + (long long)ch * 16 * lda + k0, AhS + bi * 4096 + ch * 512);
      if (ASRC == 5)
        gll16(alp + (long long)ch * 16 * lda + k0, AlS + bi * 4096 + ch * 512);
    }
  };
  auto stageLoad = [&](int k0, float* va) {
    const int ck0 = k0 + sel * 16;
    if (ASRC == 3) {
      const float* Prow = Prow_base + ((ck0 >> 5) * 96) + (ck0 & 31);
      const float* pxp = pxp_base + ck0;
#pragma unroll
      for (int i = 0; i < 16; ++i)
        va[i] = pxp[i] + Prow[i] + sv * Prow[32 + i] + iv * Prow[64 + i] +
                aux.p4[ck0 + i];
    } else {
      *(float4*)&va[0] = *(const float4*)(apA + ck0);
      *(float4*)&va[4] = *(const float4*)(apA + ck0 + 4);
      *(float4*)&va[8] = *(const float4*)(apA + ck0 + 8);
      *(float4*)&va[12] = *(const float4*)(apA + ck0 + 12);
    }
  };
  auto stageWrite = [&](int bi, const float* va) {
    us8 hv0, hv1, lv0, lv1;
#pragma unroll
    for (int i = 0; i < 16; ++i) {
      float x = va[i];
      if (ASRC == 4) x *= invdc;
      unsigned short h = f2bf(x);
      unsigned short lo = f2bf(x - bf2f(h));
      if (i < 8) { hv0[i] = h; lv0[i] = lo; }
      else       { hv1[i - 8] = h; lv1[i - 8] = lo; }
    }
    *(us8*)&AhS[bi * 4096 + s0us] = hv0;
    *(us8*)&AhS[bi * 4096 + s1us] = hv1;
    *(us8*)&AlS[bi * 4096 + s0us] = lv0;
    *(us8*)&AlS[bi * 4096 + s1us] = lv1;
  };
  auto fragmfma = [&](int bi) {
    bfrag ah[2], al[2];
#pragma unroll
    for (int mt = 0; mt < 2; ++mt) {
      const int r = w * 32 + mt * 16 + c16;
      ah[mt] = *(const bfrag*)&AhS[bi * 4096 + r * 32 + swr8];
      if (SPLITA) al[mt] = *(const bfrag*)&AlS[bi * 4096 + r * 32 + swr8];
    }
#pragma unroll
    for (int nt = 0; nt < NT; ++nt) {
      const int r = nt * 16 + c16;
      bfrag bh = *(const bfrag*)&BhS[bi * BST + r * 32 + swr8];
      bfrag bl = *(const bfrag*)&BlS[bi * BST + r * 32 + swr8];
#pragma unroll
      for (int mt = 0; mt < 2; ++mt) {
        acc[mt][nt] = __builtin_amdgcn_mfma_f32_16x16x32_bf16(ah[mt], bh, acc[mt][nt], 0, 0, 0);
        if (SPLITA)
          acc[mt][nt] = __builtin_amdgcn_mfma_f32_16x16x32_bf16(al[mt], bh, acc[mt][nt], 0, 0, 0);
        acc[mt][nt] = __builtin_amdgcn_mfma_f32_16x16x32_bf16(ah[mt], bl, acc[mt][nt], 0, 0, 0);
      }
    }
  };

  float va[16];
  const int nk = K >> 5;

  // prologue: fill buffer 0
  if (COPYA) {
    stageA(0, 0);
    stageB(0, 0);
  } else {
    stageLoad(0, va);
    stageB(0, 0);
    stageWrite(0, va);
  }
  __syncthreads();

  for (int kt = 0; kt < nk; ++kt) {
    const int bi = kt & 1;
    const bool pf = (kt + 1 < nk);
    if (pf) {
      stageB(bi ^ 1, (kt + 1) << 5);
      if (COPYA) stageA(bi ^ 1, (kt + 1) << 5);
      else stageLoad((kt + 1) << 5, va);
    }
    fragmfma(bi);
    if (!COPYA && pf) stageWrite(bi ^ 1, va);
    __syncthreads();
  }

  // epilogue: C/D layout col=lane&15, row=quad*4+reg
#pragma unroll
  for (int nt = 0; nt < NT; ++nt) {
    int col = bn + nt * 16 + c16;
    if (col >= Nc) continue;
    float bv = BIAS ? bias[col] : 0.f;
#pragma unroll
    for (int mt = 0; mt < 2; ++mt) {
#pragma unroll
      for (int r = 0; r < 4; ++r) {
        long long row = bm + w * 32 + mt * 16 + quad * 4 + r;
        float v = acc[mt][nt][r] + bv;
        if (RELU) v = fmaxf(v, 0.f);
        if (OHALF) Cu[row * ldc + col] = f2h(v);
        else Cf[row * ldc + col] = v;
      }
    }
  }
}

// ---------------------------------------------------------------------------
// Encoders -- h is produced directly as pre-split, pre-swizzled bf16 hi/lo
// (split-then-MFMA is math-identical to r1's on-the-fly split of fp32 h)
// ---------------------------------------------------------------------------
DEVFN void wsplit(float v, unsigned short* hi, unsigned short* lo, long long o)
{
  unsigned short h = f2bf(v);
  hi[o] = h;
  lo[o] = f2bf(v - bf2f(h));
}

__global__ void node_enc(const float* __restrict__ x, const float* __restrict__ Wa,
                         const float* __restrict__ ba,
                         unsigned short* __restrict__ hbh, unsigned short* __restrict__ hbl)
{
  int n = blockIdx.x, c = threadIdx.x; // 128
  float acc = ba[c];
#pragma unroll
  for (int k = 0; k < 11; ++k) acc += x[n * 11 + k] * Wa[k * 128 + c];
  wsplit(fmaxf(acc, 0.f), hbh, hbl, ((long long)n << 7) + swk(n, c));
}

// writes split hi/lo DIRECTLY in CSR slot order, PRE-SWIZZLED for gll staging
__global__ void edge_enc(const float* __restrict__ eat, const float* __restrict__ We,
                         const float* __restrict__ be, const int* __restrict__ slot_of,
                         unsigned short* __restrict__ eh, unsigned short* __restrict__ el)
{
  int e = blockIdx.x, c = threadIdx.x; // 128
  float acc = be[c];
#pragma unroll
  for (int k = 0; k < 4; ++k) acc += eat[e * 4 + k] * We[k * 128 + c];
  float v = fmaxf(acc, 0.f);
  long long slot = slot_of[e];
  wsplit(v, eh, el, slot * 128 + swk((int)slot, c));
}

// ---------------------------------------------------------------------------
// CSR build: count -> scan (also inits cursor + s/invs) -> scatter
// ---------------------------------------------------------------------------
__global__ void count_deg(const int* __restrict__ dst, int* __restrict__ degi)
{
  int e = blockIdx.x * 256 + threadIdx.x;
  if (e < EE) atomicAdd(&degi[dst[e]], 1);
}

__global__ __launch_bounds__(1024) void scan_k(const int* __restrict__ degi,
                                               int* __restrict__ row_off,
                                               int* __restrict__ cursor,
                                               float* __restrict__ s_arr,
                                               float* __restrict__ invs)
{
  __shared__ int tsum[1024];
  int t = threadIdx.x;
  int local[16];
  int base = t * 16;
  int s = 0;
#pragma unroll
  for (int i = 0; i < 16; ++i) { local[i] = s; s += degi[base + i]; }
  tsum[t] = s;
  __syncthreads();
  for (int off = 1; off < 1024; off <<= 1) {
    int v = (t >= off) ? tsum[t - off] : 0;
    __syncthreads();
    tsum[t] += v;
    __syncthreads();
  }
  int prev = (t == 0) ? 0 : tsum[t - 1];
#pragma unroll
  for (int i = 0; i < 16; ++i) {
    int start = prev + local[i];
    row_off[base + i] = start;
    cursor[base + i] = start;
    int cnt = degi[base + i];
    float degc = fmaxf((float)cnt, 1.f);
    float sv = logf(degc + 1.f) / AVG_LOG_F;
    s_arr[base + i] = sv;
    invs[base + i] = 1.f / sv;
  }
  if (t == 1023) row_off[NN] = tsum[1023];
}

__global__ void scatter_k(const int* __restrict__ src, const int* __restrict__ dst,
                          int* __restrict__ cursor,
                          int* __restrict__ slot_of, int* __restrict__ esrc)
{
  int e = blockIdx.x * 256 + threadIdx.x;
  if (e >= EE) return;
  int d = dst[e];
  int slot = atomicAdd(&cursor[d], 1);
  slot_of[e] = slot;
  esrc[slot] = src[e];
}

// ---------------------------------------------------------------------------
// Weight folds (fp32) + transpose-split packers (fp32 -> bf16 hi/lo, [N][K])
// All packed operand arrays are PRE-SWIZZLED (swk) for global_load_lds staging.
// ---------------------------------------------------------------------------
__global__ __launch_bounds__(512) void fold_w(const float* __restrict__ We_conv,
                                              const float* __restrict__ Wpre,
                                              float* __restrict__ Wfold)
{
  int k = blockIdx.x & 127, l = blockIdx.x >> 7;
  int t = threadIdx.x >> 7, f = threadIdx.x & 127;
  const float* wc = We_conv + (long long)(l * 128 + k) * 128;
  const float* wp = Wpre + ((long long)((l * 4 + t) * 384 + 256)) * 128 + f;
  float acc = 0.f;
  for (int j = 0; j < 128; ++j) acc += wc[j] * wp[(long long)j * 128];
  Wfold[((long long)(l * 128 + k)) * 512 + threadIdx.x] = acc;
}

__global__ __launch_bounds__(512) void fold_b(const float* __restrict__ be_conv,
                                              const float* __restrict__ Wpre,
                                              const float* __restrict__ bpre,
                                              float* __restrict__ bfold)
{
  int l = blockIdx.x;
  int t = threadIdx.x >> 7, f = threadIdx.x & 127;
  const float* bc = be_conv + l * 128;
  const float* wp = Wpre + ((long long)((l * 4 + t) * 384 + 256)) * 128 + f;
  float acc = bpre[(l * 4 + t) * 128 + f];
  for (int j = 0; j < 128; ++j) acc += bc[j] * wp[(long long)j * 128];
  bfold[l * 512 + threadIdx.x] = acc;
}

// preABT[lt][n(256)][k(128)] (swizzled)
__global__ void tsplit_preAB(const float* __restrict__ Wpre,
                             unsigned short* __restrict__ hi, unsigned short* __restrict__ lo)
{
  int b = blockIdx.x; // 12*256
  int lt = b >> 8, n = b & 255, k = threadIdx.x; // 128
  int row = (n < 128) ? k : (128 + k);
  int f = n & 127;
  float v = Wpre[((long long)(lt * 384 + row)) * 128 + f];
  wsplit(v, hi, lo, ((long long)(lt * 256 + n)) * 128 + swk(n, k));
}

// WfoldT[lt][n(128)][k(128)] from Wfold[l][k][t*128+n] (swizzled)
__global__ void tsplit_fold(const float* __restrict__ Wfold,
                            unsigned short* __restrict__ hi, unsigned short* __restrict__ lo)
{
  int b = blockIdx.x; // 12*128
  int lt = b >> 7, n = b & 127, k = threadIdx.x; // 128
  int l = lt >> 2, t = lt & 3;
  float v = Wfold[((long long)(l * 128 + k)) * 512 + t * 128 + n];
  wsplit(v, hi, lo, ((long long)(lt * 128 + n)) * 128 + swk(n, k));
}

// post3T[lt][c(128, pad>=96 zero)][r(512)] (swizzled)
__global__ __launch_bounds__(512) void tsplit_post3(const float* __restrict__ Wpost,
                                                    unsigned short* __restrict__ hi,
                                                    unsigned short* __restrict__ lo)
{
  int b = blockIdx.x; // 12*128
  int lt = b >> 7, c = b & 127;
  int r = threadIdx.x; // 512
  float v = 0.f;
  if (c < 96)
    v = Wpost[((long long)(lt * 1664 + 128 + (c >> 5) * 512 + r)) * 32 + (c & 31)];
  wsplit(v, hi, lo, ((long long)(lt * 128 + c)) * 512 + swk(c, r));
}

// WxT[l][c(128)][k(128)] (swizzled)
__global__ void tsplit_wx(const float* __restrict__ Wpost,
                          unsigned short* __restrict__ hi, unsigned short* __restrict__ lo)
{
  int b = blockIdx.x; // 3*128
  int l = b >> 7, c = b & 127, k = threadIdx.x;
  float v = Wpost[((long long)((l * 4 + (c >> 5)) * 1664 + k)) * 32 + (c & 31)];
  wsplit(v, hi, lo, ((long long)(l * 128 + c)) * 128 + swk(c, k));
}

// WlinT[l][n][k] (swizzled)
__global__ void tsplit_lin(const float* __restrict__ Wlin,
                           unsigned short* __restrict__ hi, unsigned short* __restrict__ lo)
{
  int b = blockIdx.x; // 3*128
  int l = b >> 7, n = b & 127, k = threadIdx.x;
  float v = Wlin[((long long)(l * 128 + k)) * 128 + n];
  wsplit(v, hi, lo, ((long long)(l * 128 + n)) * 128 + swk(n, k));
}

// W1T[n(64)][k(128)] (swizzled)
__global__ void tsplit_w1(const float* __restrict__ W1,
                          unsigned short* __restrict__ hi, unsigned short* __restrict__ lo)
{
  int n = blockIdx.x; // 64
  int k = threadIdx.x; // 128
  wsplit(W1[k * 64 + n], hi, lo, (long long)n * 128 + swk(n, k));
}

// ---------------------------------------------------------------------------
// Per-tower aggregation, ALL FOUR towers in one block.
// Block 256 = 2 nodes x 4 towers x 32 lanes(x4 ch). Edges processed in
// chunks of 4: esrc batch-loaded first, then 8 independent loads in flight
// (breaks the esrc->ABs dependent-latency chain). AB and Mb slabs are fp16
// (10-bit mantissa: r5/r6 showed bf16's 7 bits exceed the error budget;
// fp16 rounding is 8x finer at identical bandwidth). Accumulation order per
// channel is IDENTICAL to the fp32 version.
// Output aggs bf16 [N][512], PRE-SWIZZLED (swk) for gll staging by the P gemm.
// ---------------------------------------------------------------------------
__global__ __launch_bounds__(256) void aggregate_ct(
    const unsigned short* __restrict__ ABb, const unsigned short* __restrict__ Mb,
    const int* __restrict__ row_off, const int* __restrict__ esrc,
    unsigned short* __restrict__ aggs)
{
  const int tid = threadIdx.x;
  const int c4 = (tid & 31) << 2;
  const int z = (tid >> 5) & 3;
  const int n = blockIdx.x * 2 + (tid >> 7);
  const unsigned short* M = Mb + (long long)z * EE * 128;
  const unsigned short* ABs = ABb + (long long)z * NN * 256;
  unsigned short* ag = aggs + (long long)z * NN * 512;
  const int beg = row_off[n], end = row_off[n + 1];
  const int cnt = end - beg;
  const float degc = fmaxf((float)cnt, 1.0f);
  const float4 aval = ld4hf(&ABs[(long long)n * 256 + c4]);

  float sum[4] = {0.f, 0.f, 0.f, 0.f}, sq[4] = {0.f, 0.f, 0.f, 0.f};
  float mn[4] = {INFINITY, INFINITY, INFINITY, INFINITY};
  float mx[4] = {-INFINITY, -INFINITY, -INFINITY, -INFINITY};

  auto upd = [&](const float4& mv, const float4& bv) {
    float m0 = aval.x + bv.x + mv.x;
    float m1 = aval.y + bv.y + mv.y;
    float m2 = aval.z + bv.z + mv.z;
    float m3 = aval.w + bv.w + mv.w;
    sum[0] += m0; sq[0] += m0 * m0; mn[0] = fminf(mn[0], m0); mx[0] = fmaxf(mx[0], m0);
    sum[1] += m1; sq[1] += m1 * m1; mn[1] = fminf(mn[1], m1); mx[1] = fmaxf(mx[1], m1);
    sum[2] += m2; sq[2] += m2 * m2; mn[2] = fminf(mn[2], m2); mx[2] = fmaxf(mx[2], m2);
    sum[3] += m3; sq[3] += m3 * m3; mn[3] = fminf(mn[3], m3); mx[3] = fmaxf(mx[3], m3);
  };

  for (int s0 = beg; s0 < end; s0 += 4) {
    const int e1 = min(s0 + 1, end - 1);
    const int e2 = min(s0 + 2, end - 1);
    const int e3 = min(s0 + 3, end - 1);
    const int sA = esrc[s0], sB = esrc[e1], sC = esrc[e2], sD = esrc[e3];
    const float4 mA = ld4hf(&M[(long long)s0 * 128 + c4]);
    const float4 mB = ld4hf(&M[(long long)e1 * 128 + c4]);
    const float4 mC = ld4hf(&M[(long long)e2 * 128 + c4]);
    const float4 mD = ld4hf(&M[(long long)e3 * 128 + c4]);
    const float4 bA = ld4hf(&ABs[(long long)sA * 256 + 128 + c4]);
    const float4 bB = ld4hf(&ABs[(long long)sB * 256 + 128 + c4]);
    const float4 bC = ld4hf(&ABs[(long long)sC * 256 + 128 + c4]);
    const float4 bD = ld4hf(&ABs[(long long)sD * 256 + 128 + c4]);
    upd(mA, bA);
    if (s0 + 1 < end) upd(mB, bB);
    if (s0 + 2 < end) upd(mC, bC);
    if (s0 + 3 < end) upd(mD, bD);
  }

  const float inv = 1.0f / degc;
  float mean[4], stdv[4];
#pragma unroll
  for (int j = 0; j < 4; ++j) {
    mean[j] = sum[j] * inv;
    float var = sq[j] * inv - mean[j] * mean[j];
    stdv[j] = sqrtf(fmaxf(var, 0.f) + 1e-5f);
    if (cnt == 0) { mn[j] = 0.f; mx[j] = 0.f; }
  }
  const int sc = swk(n, c4);
  const long long base = (long long)n * 512 + sc;
  ushort4 o;
  o.x = f2bf(mean[0]); o.y = f2bf(mean[1]); o.z = f2bf(mean[2]); o.w = f2bf(mean[3]);
  *(ushort4*)&ag[base] = o;
  o.x = f2bf(mn[0]); o.y = f2bf(mn[1]); o.z = f2bf(mn[2]); o.w = f2bf(mn[3]);
  *(ushort4*)&ag[base + 128] = o;
  o.x = f2bf(mx[0]); o.y = f2bf(mx[1]); o.z = f2bf(mx[2]); o.w = f2bf(mx[3]);
  *(ushort4*)&ag[base + 256] = o;
  o.x = f2bf(stdv[0]); o.y = f2bf(stdv[1]); o.z = f2bf(stdv[2]); o.w = f2bf(stdv[3]);
  *(ushort4*)&ag[base + 384] = o;
}

// ---------------------------------------------------------------------------
// BatchNorm stats over N rows, 128 cols + coefficient precompute + apply
// ---------------------------------------------------------------------------
__global__ __launch_bounds__(256) void bn_partial(const float* __restrict__ y,
                                                  float* __restrict__ colsum,
                                                  float* __restrict__ colsq)
{
  int c = threadIdx.x & 127;
  int rh = threadIdx.x >> 7;
  int r0 = blockIdx.x * 128;
  float s = 0.f, q = 0.f;
  for (int r = r0 + rh; r < r0 + 128; r += 2) {
    float v = y[(long long)r * 128 + c];
    s += v;
    q += v * v;
  }
  __shared__ float ps[256], pq[256];
  ps[threadIdx.x] = s;
  pq[threadIdx.x] = q;
  __syncthreads();
  if (threadIdx.x < 128) {
    atomicAdd(&colsum[c], ps[c] + ps[c + 128]);
    atomicAdd(&colsq[c], pq[c] + pq[c + 128]);
  }
}

// coef[c] = g*rsqrt(var+eps); coef[128+c] = b - mean*scale  (BN as FMA)
__global__ void bn_coef(const float* __restrict__ colsum, const float* __restrict__ colsq,
                        const float* __restrict__ g, const float* __restrict__ b,
                        float* __restrict__ coef)
{
  int c = threadIdx.x; // 128
  float mean = colsum[c] * (1.f / 16384.f);
  float var = colsq[c] * (1.f / 16384.f) - mean * mean;
  float sc = g[c] * rsqrtf(var + 1e-5f);
  coef[c] = sc;
  coef[128 + c] = b[c] - mean * sc;
}

// hbf = split(relu(y*scale + shift)) pre-swizzled
__global__ __launch_bounds__(256) void bn_apply(const float* __restrict__ y,
                                                const float* __restrict__ coef,
                                                unsigned short* __restrict__ hbh,
                                                unsigned short* __restrict__ hbl)
{
  int idx = blockIdx.x * 256 + threadIdx.x; // n*128+c
  int c = idx & 127, n = idx >> 7;
  float v = fmaxf(y[idx] * coef[c] + coef[128 + c], 0.f);
  wsplit(v, hbh, hbl, ((long long)n << 7) + swk(n, c));
}

// ---------------------------------------------------------------------------
// Global mean pool (BN+ReLU fused) + head
// ---------------------------------------------------------------------------
__global__ void pool_add(const float* __restrict__ y, const float* __restrict__ colsum,
                         const float* __restrict__ colsq, const float* __restrict__ g,
                         const float* __restrict__ b, const int* __restrict__ batch,
                         float* __restrict__ pooled, float* __restrict__ cntf)
{
  int n = blockIdx.x, c = threadIdx.x;
  float mean = colsum[c] * (1.f / 16384.f);
  float var = colsq[c] * (1.f / 16384.f) - mean * mean;
  float v = fmaxf((y[(long long)n * 128 + c] - mean) * rsqrtf(var + 1e-5f) * g[c] + b[c], 0.f);
  int bb = batch[n];
  atomicAdd(&pooled[(long long)bb * 128 + c], v);
  if (c == 0) atomicAdd(&cntf[bb], 1.f);
}

__global__ __launch_bounds__(256) void zstats(const float* __restrict__ z,
                                              float* __restrict__ zm, float* __restrict__ zv)
{
  int j = blockIdx.x; // 64 cols
  float s = 0.f, q = 0.f;
  for (int g = threadIdx.x; g < GG; g += 256) {
    float v = z[g * 64 + j];
    s += v;
    q += v * v;
  }
  __shared__ float ps[256], pq[256];
  ps[threadIdx.x] = s;
  pq[threadIdx.x] = q;
  __syncthreads();
  for (int st = 128; st > 0; st >>= 1) {
    if (threadIdx.x < st) {
      ps[threadIdx.x] += ps[threadIdx.x + st];
      pq[threadIdx.x] += pq[threadIdx.x + st];
    }
    __syncthreads();
  }
  if (threadIdx.x == 0) {
    float m = ps[0] / (float)GG;
    zm[j] = m;
    zv[j] = pq[0] / (float)GG - m * m;
  }
}

__global__ void final_out(const float* __restrict__ z, const float* __restrict__ zm,
                          const float* __restrict__ zv, const float* __restrict__ hg,
                          const float* __restrict__ hb, const float* __restrict__ W2,
                          const float* __restrict__ b2, float* __restrict__ out)
{
  int g = blockIdx.x;
  int j = threadIdx.x; // 64 = one wave
  float v = (z[g * 64 + j] - zm[j]) * rsqrtf(zv[j] + 1e-5f) * hg[j] + hb[j];
  float t = v * W2[j];
#pragma unroll
  for (int off = 32; off > 0; off >>= 1) t += __shfl_down(t, off);
  if (j == 0) out[g] = t + b2[0];
}

// ---------------------------------------------------------------------------
extern "C" void kernel_launch(void* const* d_in, const int* in_sizes, int n_in,
                              void* d_out, int out_size, void* d_ws, size_t ws_size,
                              hipStream_t stream)
{
  (void)in_sizes; (void)n_in; (void)out_size;
  const float* x = (const float*)d_in[0];
  const float* eat = (const float*)d_in[1];
  const int* ei = (const int*)d_in[2];
  const int* batch = (const int*)d_in[3];
  const float* Wa = (const float*)d_in[4];
  const float* ba = (const float*)d_in[5];
  const float* We = (const float*)d_in[6];
  const float* be = (const float*)d_in[7];
  const float* We_conv = (const float*)d_in[8];
  const float* be_conv = (const float*)d_in[9];
  const float* Wpre = (const float*)d_in[10];
  const float* bpre = (const float*)d_in[11];
  const float* Wpost = (const float*)d_in[12];
  const float* bpost = (const float*)d_in[13];
  const float* Wlin = (const float*)d_in[14];
  const float* blin = (const float*)d_in[15];
  const float* bng = (const float*)d_in[16];
  const float* bnb = (const float*)d_in[17];
  const float* W1 = (const float*)d_in[18];
  const float* b1 = (const float*)d_in[19];
  const float* hg = (const float*)d_in[20];
  const float* hb = (const float*)d_in[21];
  const float* W2 = (const float*)d_in[22];
  const float* b2 = (const float*)d_in[23];
  float* out = (float*)d_out;

  const int* srcI = ei;
  const int* dstI = ei + EE;

  char* ws = (char*)d_ws;
  size_t off = 0;
  auto alloc = [&](size_t bytes) -> char* {
    char* p = ws + off;
    off += (bytes + 255) & ~(size_t)255;
    return p;
  };

  unsigned short* hbf_h = (unsigned short*)alloc((size_t)NN * 128 * 2); // pre-split h
  unsigned short* hbf_l = (unsigned short*)alloc((size_t)NN * 128 * 2);
  float* hn = (float*)alloc((size_t)NN * 128 * 4);
  unsigned short* eah = (unsigned short*)alloc((size_t)EE * 128 * 2); // CSR slot order
  unsigned short* eal = (unsigned short*)alloc((size_t)EE * 128 * 2);
  unsigned short* AB = (unsigned short*)alloc((size_t)4 * NN * 256 * 2); // fp16 [T][N][256]
  char* Mregion = alloc((size_t)2 * EE * 128 * 4);           // Mb fp16 [4][E][128]; later P|Px fp32
  unsigned short* Mb = (unsigned short*)Mregion;
  float* P = (float*)Mregion;                                 // [N][384]
  float* Px = (float*)(Mregion + (size_t)NN * 384 * 4);       // [N][128]
  unsigned short* aggt = (unsigned short*)alloc((size_t)4 * NN * 512 * 2); // bf16 [T][N][512]
  float* s_arr = (float*)alloc((size_t)NN * 4);
  float* invs = (float*)alloc((size_t)NN * 4);
  int* degi = (int*)alloc((size_t)NN * 4);
  int* cursor = (int*)alloc((size_t)NN * 4);
  int* row_off = (int*)alloc((size_t)(NN + 1) * 4);
  int* slot_of = (int*)alloc((size_t)EE * 4);
  int* esrc = (int*)alloc((size_t)EE * 4);
  float* WfoldF = (float*)alloc((size_t)3 * 128 * 512 * 4);
  float* bfold = (float*)alloc((size_t)3 * 512 * 4);
  unsigned short* preABT_h = (unsigned short*)alloc((size_t)12 * 256 * 128 * 2);
  unsigned short* preABT_l = (unsigned short*)alloc((size_t)12 * 256 * 128 * 2);
  unsigned short* foldT_h = (unsigned short*)alloc((size_t)12 * 128 * 128 * 2);
  unsigned short* foldT_l = (unsigned short*)alloc((size_t)12 * 128 * 128 * 2);
  unsigned short* post3T_h = (unsigned short*)alloc((size_t)12 * 128 * 512 * 2);
  unsigned short* post3T_l = (unsigned short*)alloc((size_t)12 * 128 * 512 * 2);
  unsigned short* wxT_h = (unsigned short*)alloc((size_t)3 * 128 * 128 * 2);
  unsigned short* wxT_l = (unsigned short*)alloc((size_t)3 * 128 * 128 * 2);
  unsigned short* linT_h = (unsigned short*)alloc((size_t)3 * 128 * 128 * 2);
  unsigned short* linT_l = (unsigned short*)alloc((size_t)3 * 128 * 128 * 2);
  unsigned short* w1T_h = (unsigned short*)alloc((size_t)64 * 128 * 2);
  unsigned short* w1T_l = (unsigned short*)alloc((size_t)64 * 128 * 2);
  float* colstats = (float*)alloc(512 * 4); // two ping-pong buffers of 256
  float* bncoef = (float*)alloc(256 * 4);
  float* pooled = (float*)alloc((size_t)GG * 128 * 4);
  float* cntf = (float*)alloc((size_t)GG * 4);
  float* zbuf = (float*)alloc((size_t)GG * 64 * 4);
  float* zm = (float*)alloc(64 * 4);
  float* zv = (float*)alloc(64 * 4);

  if (off > ws_size) return; // bail rather than corrupt

  float* cs[2] = {colstats, colstats + 256};

  // ---- graph structure ----
  hipMemsetAsync(degi, 0, (size_t)NN * 4, stream);
  count_deg<<<EE / 256, 256, 0, stream>>>(dstI, degi);
  scan_k<<<1, 1024, 0, stream>>>(degi, row_off, cursor, s_arr, invs);
  scatter_k<<<EE / 256, 256, 0, stream>>>(srcI, dstI, cursor, slot_of, esrc);

  // ---- encoders + weight folds/packing ----
  node_enc<<<NN, 128, 0, stream>>>(x, Wa, ba, hbf_h, hbf_l);
  edge_enc<<<EE, 128, 0, stream>>>(eat, We, be, slot_of, eah, eal); // after scatter_k
  fold_w<<<384, 512, 0, stream>>>(We_conv, Wpre, WfoldF);
  fold_b<<<3, 512, 0, stream>>>(be_conv, Wpre, bpre, bfold);
  tsplit_preAB<<<12 * 256, 128, 0, stream>>>(Wpre, preABT_h, preABT_l);
  tsplit_fold<<<12 * 128, 128, 0, stream>>>(WfoldF, foldT_h, foldT_l);
  tsplit_post3<<<12 * 128, 512, 0, stream>>>(Wpost, post3T_h, post3T_l);
  tsplit_wx<<<3 * 128, 128, 0, stream>>>(Wpost, wxT_h, wxT_l);
  tsplit_lin<<<3 * 128, 128, 0, stream>>>(Wlin, linT_h, linT_l);
  tsplit_w1<<<64, 128, 0, stream>>>(W1, w1T_h, w1T_l);

  for (int l = 0; l < 3; ++l) {
    hipMemsetAsync(cs[l & 1], 0, 256 * 4, stream);
    // AB all towers: [N,128] @ [128,256] (z=4) -> fp16 [T][N][256]; A = hbf copy
    mgemm<5, 8, false, false, true><<<dim3(NN / 128, 2, 4), 256, 0, stream>>>(
        hbf_h, preABT_h + (size_t)l * 4 * 256 * 128, preABT_l + (size_t)l * 4 * 256 * 128,
        nullptr, (float*)AB, AuxP{(const float*)hbf_l, nullptr, nullptr, nullptr, nullptr},
        256, 128, 128, 256, 0, (long long)256 * 128, (long long)NN * 256, 0);
    // C all 4 towers (streaming, CSR-ordered ea): [E,128]@[128,128]+bfold -> fp16
    mgemm<5, 8, true, false, true><<<dim3(EE / 128, 1, 4), 256, 0, stream>>>(
        eah, foldT_h + (size_t)l * 4 * 128 * 128, foldT_l + (size_t)l * 4 * 128 * 128,
        bfold + l * 512, (float*)Mb,
        AuxP{(const float*)eal, nullptr, nullptr, nullptr, nullptr},
        128, 128, 128, 128, 0, (long long)128 * 128, (long long)EE * 128, 128);
    // stats over m = (A + B[src]) + C ; all 4 towers per block
    aggregate_ct<<<dim3(NN / 2, 1, 1), 256, 0, stream>>>(AB, Mb, row_off, esrc, aggt);
    // P all towers: bf16 [N,512] @ [512,96] (z=4, exact 96-col tile) -> P[:, z*96..]
    mgemm<1, 6, false, false, false><<<dim3(NN / 128, 1, 4), 256, 0, stream>>>(
        aggt, post3T_h + (size_t)l * 4 * 128 * 512, post3T_l + (size_t)l * 4 * 128 * 512,
        nullptr, P, AuxP{}, 96, 512, 512, 384,
        (long long)NN * 512, (long long)128 * 512, 96, 0);
    // Px: [N,128] @ [128,128]; A = hbf copy
    mgemm<5, 8, false, false, false><<<dim3(NN / 128, 1, 1), 256, 0, stream>>>(
        hbf_h, wxT_h + (size_t)l * 128 * 128, wxT_l + (size_t)l * 128 * 128,
        nullptr, Px, AuxP{(const float*)hbf_l, nullptr, nullptr, nullptr, nullptr},
        128, 128, 128, 128, 0, 0, 0, 0);
    // lin (post-combine fused in A-staging): [N,128] @ [128,128] + blin -> hn
    mgemm<3, 8, true, false, false><<<dim3(NN / 128, 1, 1), 256, 0, stream>>>(
        nullptr, linT_h + (size_t)l * 128 * 128, linT_l + (size_t)l * 128 * 128,
        blin + l * 128, hn, AuxP{P, Px, s_arr, invs, bpost + l * 128},
        128, 128, 128, 128, 0, 0, 0, 0);
    bn_partial<<<128, 256, 0, stream>>>(hn, cs[l & 1], cs[l & 1] + 128);
    if (l < 2) {
      bn_coef<<<1, 128, 0, stream>>>(cs[l & 1], cs[l & 1] + 128,
                                     bng + l * 128, bnb + l * 128, bncoef);
      bn_apply<<<NN * 128 / 256, 256, 0, stream>>>(hn, bncoef, hbf_h, hbf_l);
    }
  }

  // ---- pooling (BN+ReLU fused) + head ----
  hipMemsetAsync(pooled, 0, (size_t)GG * 128 * 4, stream);
  hipMemsetAsync(cntf, 0, (size_t)GG * 4, stream);
  pool_add<<<NN, 128, 0, stream>>>(hn, cs[0], cs[0] + 128,
                                   bng + 2 * 128, bnb + 2 * 128, batch, pooled, cntf);
  mgemm<4, 4, true, true, false><<<dim3(GG / 128, 1, 1), 256, 0, stream>>>(
      pooled, w1T_h, w1T_l, b1, zbuf,
      AuxP{cntf, nullptr, nullptr, nullptr, nullptr}, 64, 128, 128, 64, 0, 0, 0, 0);
  zstats<<<64, 256, 0, stream>>>(zbuf, zm, zv);
  final_out<<<GG, 64, 0, stream>>>(zbuf, zm, zv, hg, hb, W2, b2, out);
}

// Round 8
// 656.184 us; speedup vs baseline: 1.4481x; 1.1630x over previous
//
#include <hip/hip_runtime.h>
#include <hip/hip_bf16.h>

#define DEVFN static __device__ __forceinline__

constexpr int NN = 16384;
constexpr int EE = 65536;
constexpr int GG = 512;
constexpr float AVG_LOG_F = 1.0227308671603782f; // (sum d*log d, d=1..4, hist 1,2,3,4)/10

typedef _Float16 hfrag __attribute__((ext_vector_type(8))); // 8 fp16 = 4 VGPR (MFMA A/B)
typedef __attribute__((ext_vector_type(4))) float f4;       // MFMA C/D

// fp32 <-> fp16 (RNE, native v_cvt). r5/r6/r7 measured: bf16 (7-bit) slab
// rounding costs +0.0097 absmax; fp16 (10-bit) is noise-level. So ALL
// intermediate tensors and GEMM operands are fp16; GEMMs are single
// mfma_f32_16x16x32_f16 with fp32 accumulate.
DEVFN unsigned short f2h(float f) {
  _Float16 h = (_Float16)f;
  unsigned short r; __builtin_memcpy(&r, &h, 2); return r;
}
DEVFN float h2f(unsigned short s) {
  _Float16 h; __builtin_memcpy(&h, &s, 2); return (float)h;
}

// load 4 fp16 -> float4
DEVFN float4 ld4hf(const unsigned short* p) {
  ushort4 u = *(const ushort4*)p;
  float4 r;
  r.x = h2f(u.x); r.y = h2f(u.y); r.z = h2f(u.z); r.w = h2f(u.w);
  return r;
}

// XOR swizzle for packed fp16 [R][K] operand arrays staged with global_load_lds:
// element (row,k) lives at row*K + swk(row,k). Within each 32-wide K window the
// four 8-element slots are permuted by (row>>1)&3 so a wave's ds_read_b128
// fragment reads become a permutation of a contiguous 1 KB region ->
// bank-conflict-free. global_load_lds copies LINEARLY, so the swizzle is baked
// into the packed global layout (both-sides rule, #21).
DEVFN int swk(int row, int k) {
  return (k & ~31) + ((((k >> 3) & 3) ^ ((row >> 1) & 3)) << 3) + (k & 7);
}

// async global->LDS, 16 B per lane; LDS dest = wave-uniform base + lane*16
DEVFN void gll16(const unsigned short* g, unsigned short* l) {
  __builtin_amdgcn_global_load_lds(
      (__attribute__((address_space(1))) void*)g,
      (__attribute__((address_space(3))) void*)l, 16, 0, 0);
}

// aux pointer bundle for fused A-staging modes
struct AuxP {
  const float* p0;
  const float* p1;
  const float* p2;
  const float* p3;
  const float* p4;
};

// ---------------------------------------------------------------------------
// fp16 MFMA GEMM: C[M,Nc] = A[M,K] @ W[K,Nc], fp32 accumulate.
// A-staging modes (ASRC):
//   1: fp16 ushort input (pre-swizzled), gll copy
//   3: PNA post-combine fused: A = Px + P_id + s*P_amp + invs*P_att + bpost
//   4: fp32 / rowcount (p0=cntf) -- global mean pool divide (ds-write path)
// B (WT) pre-swizzled packed fp16, staged via global_load_lds.
// OHALF: epilogue stores fp16 (slabs consumed by aggregate_ct only).
// NT = column fragments (tile N = NT*16). r1 sync structure (measured best):
// double-buffered LDS, stage tile k+1 via gll before MFMA on tile k, one
// __syncthreads per step (its vmcnt/lgkm drain completes the prefetch).
// LDS 32 KB at NT=8 -> 5 blocks/CU (r7's 64 KB split version sat at 2).
// Block 256 = 4 waves; tile M=128, BK=32. M%128==0, K%32==0, col<Nc guarded.
// ---------------------------------------------------------------------------
template <int ASRC, int NT, bool BIAS, bool RELU, bool OHALF>
__global__ __launch_bounds__(256) void mgemm(
    const void* __restrict__ Av, const unsigned short* __restrict__ WT,
    const float* __restrict__ bias,
    float* __restrict__ C, AuxP aux,
    int Nc, int K, int lda, int ldc,
    long long bsA, long long bsW, long long bsC, int bsBias)
{
  constexpr bool COPYA = (ASRC == 1);
  constexpr int BST = NT * 16 * 32; // ushorts per B buffer

  const int z = blockIdx.z;
  WT += (long long)z * bsW;
  if (BIAS) bias += (long long)z * bsBias;
  float* Cf = C + (OHALF ? 0 : (long long)z * bsC);
  unsigned short* Cu = (unsigned short*)C + (OHALF ? (long long)z * bsC : 0);

  __shared__ __align__(16) unsigned short AhS[2 * 128 * 32];
  __shared__ __align__(16) unsigned short BhS[2 * BST];

  const int tid = threadIdx.x;
  const long long bm = (long long)blockIdx.x * 128;
  const int bn = blockIdx.y * (NT * 16);
  const int w = tid >> 6;
  const int lane = tid & 63;
  const int quad = lane >> 4;
  const int c16 = lane & 15;
  const int srow = lane >> 2;        // staging row within 16-row chunk
  const int sslot = (lane & 3) << 3; // staging slot (ushort offset)

  // ds-write-mode indices: each thread produces 16 A elements of one row-half
  const int arow = tid >> 1;
  const int sel = tid & 1;
  const long long rowsrc = bm + arow;

  f4 acc[2][NT];
#pragma unroll
  for (int mt = 0; mt < 2; ++mt)
#pragma unroll
    for (int nt = 0; nt < NT; ++nt) acc[mt][nt] = (f4){0.f, 0.f, 0.f, 0.f};

  // lane-invariant staging bases
  const unsigned short* whp = WT + (long long)(bn + srow) * K + sslot;

  const unsigned short* ahp = nullptr;
  if (COPYA)
    ahp = (const unsigned short*)Av + (long long)z * bsA + (bm + srow) * (long long)lda + sslot;

  // ds-write-mode A state (ASRC 3 / 4)
  float invdc = 1.f;
  float sv = 0.f, iv = 0.f;
  const float* apA = nullptr;
  const float* Prow_base = nullptr;
  const float* pxp_base = nullptr;
  if (!COPYA) {
    if (ASRC == 3) {
      Prow_base = aux.p0 + rowsrc * 384;
      pxp_base = aux.p1 + rowsrc * 128;
      sv = aux.p2[rowsrc];
      iv = aux.p3[rowsrc];
    } else {
      apA = (const float*)Av + (long long)z * bsA + rowsrc * lda;
      invdc = 1.f / fmaxf(aux.p0[rowsrc], 1.f);
    }
  }
  // swizzled LDS write offsets for ds-write-mode A
  const int swa = (arow >> 1) & 3;
  const int s0us = arow * 32 + (((2 * sel) ^ swa) << 3);
  const int s1us = arow * 32 + (((2 * sel + 1) ^ swa) << 3);

  // fragment-read swizzle: slot quad ^ ((row>>1)&3); row bits 1..2 == c16 bits
  const int swr8 = ((quad ^ ((c16 >> 1) & 3)) << 3);

  auto stageB = [&](int bi, int k0) {
#pragma unroll
    for (int ch = w; ch < NT; ch += 4)
      gll16(whp + (long long)ch * 16 * K + k0, BhS + bi * BST + ch * 512);
  };
  auto stageA = [&](int bi, int k0) {
#pragma unroll
    for (int ch = w; ch < 8; ch += 4)
      gll16(ahp + (long long)ch * 16 * lda + k0, AhS + bi * 4096 + ch * 512);
  };
  auto stageLoad = [&](int k0, float* va) {
    const int ck0 = k0 + sel * 16;
    if (ASRC == 3) {
      const float* Prow = Prow_base + ((ck0 >> 5) * 96) + (ck0 & 31);
      const float* pxp = pxp_base + ck0;
#pragma unroll
      for (int i = 0; i < 16; ++i)
        va[i] = pxp[i] + Prow[i] + sv * Prow[32 + i] + iv * Prow[64 + i] +
                aux.p4[ck0 + i];
    } else {
      *(float4*)&va[0] = *(const float4*)(apA + ck0);
      *(float4*)&va[4] = *(const float4*)(apA + ck0 + 4);
      *(float4*)&va[8] = *(const float4*)(apA + ck0 + 8);
      *(float4*)&va[12] = *(const float4*)(apA + ck0 + 12);
    }
  };
  auto stageWrite = [&](int bi, const float* va) {
    hfrag hv0, hv1;
#pragma unroll
    for (int i = 0; i < 16; ++i) {
      float x = va[i];
      if (ASRC == 4) x *= invdc;
      if (i < 8) hv0[i] = (_Float16)x;
      else       hv1[i - 8] = (_Float16)x;
    }
    *(hfrag*)&AhS[bi * 4096 + s0us] = hv0;
    *(hfrag*)&AhS[bi * 4096 + s1us] = hv1;
  };
  auto fragmfma = [&](int bi) {
    hfrag ah[2];
#pragma unroll
    for (int mt = 0; mt < 2; ++mt) {
      const int r = w * 32 + mt * 16 + c16;
      ah[mt] = *(const hfrag*)&AhS[bi * 4096 + r * 32 + swr8];
    }
#pragma unroll
    for (int nt = 0; nt < NT; ++nt) {
      const int r = nt * 16 + c16;
      hfrag bh = *(const hfrag*)&BhS[bi * BST + r * 32 + swr8];
#pragma unroll
      for (int mt = 0; mt < 2; ++mt)
        acc[mt][nt] = __builtin_amdgcn_mfma_f32_16x16x32_f16(ah[mt], bh, acc[mt][nt], 0, 0, 0);
    }
  };

  float va[16];
  const int nk = K >> 5;

  // prologue: fill buffer 0
  if (COPYA) {
    stageA(0, 0);
    stageB(0, 0);
  } else {
    stageLoad(0, va);
    stageB(0, 0);
    stageWrite(0, va);
  }
  __syncthreads();

  for (int kt = 0; kt < nk; ++kt) {
    const int bi = kt & 1;
    const bool pf = (kt + 1 < nk);
    if (pf) {
      stageB(bi ^ 1, (kt + 1) << 5);
      if (COPYA) stageA(bi ^ 1, (kt + 1) << 5);
      else stageLoad((kt + 1) << 5, va);
    }
    fragmfma(bi);
    if (!COPYA && pf) stageWrite(bi ^ 1, va);
    __syncthreads();
  }

  // epilogue: C/D layout col=lane&15, row=quad*4+reg
#pragma unroll
  for (int nt = 0; nt < NT; ++nt) {
    int col = bn + nt * 16 + c16;
    if (col >= Nc) continue;
    float bv = BIAS ? bias[col] : 0.f;
#pragma unroll
    for (int mt = 0; mt < 2; ++mt) {
#pragma unroll
      for (int r = 0; r < 4; ++r) {
        long long row = bm + w * 32 + mt * 16 + quad * 4 + r;
        float v = acc[mt][nt][r] + bv;
        if (RELU) v = fmaxf(v, 0.f);
        if (OHALF) Cu[row * ldc + col] = f2h(v);
        else Cf[row * ldc + col] = v;
      }
    }
  }
}

// ---------------------------------------------------------------------------
// Encoders -- h / ea produced directly as pre-swizzled fp16
// ---------------------------------------------------------------------------
__global__ void node_enc(const float* __restrict__ x, const float* __restrict__ Wa,
                         const float* __restrict__ ba, unsigned short* __restrict__ hb)
{
  int n = blockIdx.x, c = threadIdx.x; // 128
  float acc = ba[c];
#pragma unroll
  for (int k = 0; k < 11; ++k) acc += x[n * 11 + k] * Wa[k * 128 + c];
  hb[((long long)n << 7) + swk(n, c)] = f2h(fmaxf(acc, 0.f));
}

// writes fp16 DIRECTLY in CSR slot order, PRE-SWIZZLED for gll staging
__global__ void edge_enc(const float* __restrict__ eat, const float* __restrict__ We,
                         const float* __restrict__ be, const int* __restrict__ slot_of,
                         unsigned short* __restrict__ ef)
{
  int e = blockIdx.x, c = threadIdx.x; // 128
  float acc = be[c];
#pragma unroll
  for (int k = 0; k < 4; ++k) acc += eat[e * 4 + k] * We[k * 128 + c];
  long long slot = slot_of[e];
  ef[slot * 128 + swk((int)slot, c)] = f2h(fmaxf(acc, 0.f));
}

// ---------------------------------------------------------------------------
// CSR build: count -> scan (also inits cursor + s/invs) -> scatter
// ---------------------------------------------------------------------------
__global__ void count_deg(const int* __restrict__ dst, int* __restrict__ degi)
{
  int e = blockIdx.x * 256 + threadIdx.x;
  if (e < EE) atomicAdd(&degi[dst[e]], 1);
}

__global__ __launch_bounds__(1024) void scan_k(const int* __restrict__ degi,
                                               int* __restrict__ row_off,
                                               int* __restrict__ cursor,
                                               float* __restrict__ s_arr,
                                               float* __restrict__ invs)
{
  __shared__ int tsum[1024];
  int t = threadIdx.x;
  int local[16];
  int base = t * 16;
  int s = 0;
#pragma unroll
  for (int i = 0; i < 16; ++i) { local[i] = s; s += degi[base + i]; }
  tsum[t] = s;
  __syncthreads();
  for (int off = 1; off < 1024; off <<= 1) {
    int v = (t >= off) ? tsum[t - off] : 0;
    __syncthreads();
    tsum[t] += v;
    __syncthreads();
  }
  int prev = (t == 0) ? 0 : tsum[t - 1];
#pragma unroll
  for (int i = 0; i < 16; ++i) {
    int start = prev + local[i];
    row_off[base + i] = start;
    cursor[base + i] = start;
    int cnt = degi[base + i];
    float degc = fmaxf((float)cnt, 1.f);
    float sv = logf(degc + 1.f) / AVG_LOG_F;
    s_arr[base + i] = sv;
    invs[base + i] = 1.f / sv;
  }
  if (t == 1023) row_off[NN] = tsum[1023];
}

__global__ void scatter_k(const int* __restrict__ src, const int* __restrict__ dst,
                          int* __restrict__ cursor,
                          int* __restrict__ slot_of, int* __restrict__ esrc)
{
  int e = blockIdx.x * 256 + threadIdx.x;
  if (e >= EE) return;
  int d = dst[e];
  int slot = atomicAdd(&cursor[d], 1);
  slot_of[e] = slot;
  esrc[slot] = src[e];
}

// ---------------------------------------------------------------------------
// Weight folds (fp32) + transpose packers (fp32 -> fp16, [N][K], swizzled)
// ---------------------------------------------------------------------------
__global__ __launch_bounds__(512) void fold_w(const float* __restrict__ We_conv,
                                              const float* __restrict__ Wpre,
                                              float* __restrict__ Wfold)
{
  int k = blockIdx.x & 127, l = blockIdx.x >> 7;
  int t = threadIdx.x >> 7, f = threadIdx.x & 127;
  const float* wc = We_conv + (long long)(l * 128 + k) * 128;
  const float* wp = Wpre + ((long long)((l * 4 + t) * 384 + 256)) * 128 + f;
  float acc = 0.f;
  for (int j = 0; j < 128; ++j) acc += wc[j] * wp[(long long)j * 128];
  Wfold[((long long)(l * 128 + k)) * 512 + threadIdx.x] = acc;
}

__global__ __launch_bounds__(512) void fold_b(const float* __restrict__ be_conv,
                                              const float* __restrict__ Wpre,
                                              const float* __restrict__ bpre,
                                              float* __restrict__ bfold)
{
  int l = blockIdx.x;
  int t = threadIdx.x >> 7, f = threadIdx.x & 127;
  const float* bc = be_conv + l * 128;
  const float* wp = Wpre + ((long long)((l * 4 + t) * 384 + 256)) * 128 + f;
  float acc = bpre[(l * 4 + t) * 128 + f];
  for (int j = 0; j < 128; ++j) acc += bc[j] * wp[(long long)j * 128];
  bfold[l * 512 + threadIdx.x] = acc;
}

// preABT[lt][n(256)][k(128)] (swizzled fp16)
__global__ void tsplit_preAB(const float* __restrict__ Wpre,
                             unsigned short* __restrict__ o)
{
  int b = blockIdx.x; // 12*256
  int lt = b >> 8, n = b & 255, k = threadIdx.x; // 128
  int row = (n < 128) ? k : (128 + k);
  int f = n & 127;
  float v = Wpre[((long long)(lt * 384 + row)) * 128 + f];
  o[((long long)(lt * 256 + n)) * 128 + swk(n, k)] = f2h(v);
}

// WfoldT[lt][n(128)][k(128)] from Wfold[l][k][t*128+n] (swizzled fp16)
__global__ void tsplit_fold(const float* __restrict__ Wfold,
                            unsigned short* __restrict__ o)
{
  int b = blockIdx.x; // 12*128
  int lt = b >> 7, n = b & 127, k = threadIdx.x; // 128
  int l = lt >> 2, t = lt & 3;
  float v = Wfold[((long long)(l * 128 + k)) * 512 + t * 128 + n];
  o[((long long)(lt * 128 + n)) * 128 + swk(n, k)] = f2h(v);
}

// post3T[lt][c(128, pad>=96 zero)][r(512)] (swizzled fp16)
__global__ __launch_bounds__(512) void tsplit_post3(const float* __restrict__ Wpost,
                                                    unsigned short* __restrict__ o)
{
  int b = blockIdx.x; // 12*128
  int lt = b >> 7, c = b & 127;
  int r = threadIdx.x; // 512
  float v = 0.f;
  if (c < 96)
    v = Wpost[((long long)(lt * 1664 + 128 + (c >> 5) * 512 + r)) * 32 + (c & 31)];
  o[((long long)(lt * 128 + c)) * 512 + swk(c, r)] = f2h(v);
}

// WxT[l][c(128)][k(128)] (swizzled fp16)
__global__ void tsplit_wx(const float* __restrict__ Wpost,
                          unsigned short* __restrict__ o)
{
  int b = blockIdx.x; // 3*128
  int l = b >> 7, c = b & 127, k = threadIdx.x;
  float v = Wpost[((long long)((l * 4 + (c >> 5)) * 1664 + k)) * 32 + (c & 31)];
  o[((long long)(l * 128 + c)) * 128 + swk(c, k)] = f2h(v);
}

// WlinT[l][n][k] (swizzled fp16)
__global__ void tsplit_lin(const float* __restrict__ Wlin,
                           unsigned short* __restrict__ o)
{
  int b = blockIdx.x; // 3*128
  int l = b >> 7, n = b & 127, k = threadIdx.x;
  float v = Wlin[((long long)(l * 128 + k)) * 128 + n];
  o[((long long)(l * 128 + n)) * 128 + swk(n, k)] = f2h(v);
}

// W1T[n(64)][k(128)] (swizzled fp16)
__global__ void tsplit_w1(const float* __restrict__ W1,
                          unsigned short* __restrict__ o)
{
  int n = blockIdx.x; // 64
  int k = threadIdx.x; // 128
  o[(long long)n * 128 + swk(n, k)] = f2h(W1[k * 64 + n]);
}

// ---------------------------------------------------------------------------
// Per-tower aggregation, ALL FOUR towers in one block.
// Block 256 = 2 nodes x 4 towers x 32 lanes(x4 ch). Edges processed in
// chunks of 4: esrc batch-loaded first, then 8 independent loads in flight
// (breaks the esrc->ABs dependent-latency chain). AB and Mb slabs fp16.
// Output aggs fp16 [N][512] (finer than the old bf16 -- the former dominant
// quantizer), PRE-SWIZZLED (swk) for gll staging by the P gemm.
// ---------------------------------------------------------------------------
__global__ __launch_bounds__(256) void aggregate_ct(
    const unsigned short* __restrict__ ABb, const unsigned short* __restrict__ Mb,
    const int* __restrict__ row_off, const int* __restrict__ esrc,
    unsigned short* __restrict__ aggs)
{
  const int tid = threadIdx.x;
  const int c4 = (tid & 31) << 2;
  const int z = (tid >> 5) & 3;
  const int n = blockIdx.x * 2 + (tid >> 7);
  const unsigned short* M = Mb + (long long)z * EE * 128;
  const unsigned short* ABs = ABb + (long long)z * NN * 256;
  unsigned short* ag = aggs + (long long)z * NN * 512;
  const int beg = row_off[n], end = row_off[n + 1];
  const int cnt = end - beg;
  const float degc = fmaxf((float)cnt, 1.0f);
  const float4 aval = ld4hf(&ABs[(long long)n * 256 + c4]);

  float sum[4] = {0.f, 0.f, 0.f, 0.f}, sq[4] = {0.f, 0.f, 0.f, 0.f};
  float mn[4] = {INFINITY, INFINITY, INFINITY, INFINITY};
  float mx[4] = {-INFINITY, -INFINITY, -INFINITY, -INFINITY};

  auto upd = [&](const float4& mv, const float4& bv) {
    float m0 = aval.x + bv.x + mv.x;
    float m1 = aval.y + bv.y + mv.y;
    float m2 = aval.z + bv.z + mv.z;
    float m3 = aval.w + bv.w + mv.w;
    sum[0] += m0; sq[0] += m0 * m0; mn[0] = fminf(mn[0], m0); mx[0] = fmaxf(mx[0], m0);
    sum[1] += m1; sq[1] += m1 * m1; mn[1] = fminf(mn[1], m1); mx[1] = fmaxf(mx[1], m1);
    sum[2] += m2; sq[2] += m2 * m2; mn[2] = fminf(mn[2], m2); mx[2] = fmaxf(mx[2], m2);
    sum[3] += m3; sq[3] += m3 * m3; mn[3] = fminf(mn[3], m3); mx[3] = fmaxf(mx[3], m3);
  };

  for (int s0 = beg; s0 < end; s0 += 4) {
    const int e1 = min(s0 + 1, end - 1);
    const int e2 = min(s0 + 2, end - 1);
    const int e3 = min(s0 + 3, end - 1);
    const int sA = esrc[s0], sB = esrc[e1], sC = esrc[e2], sD = esrc[e3];
    const float4 mA = ld4hf(&M[(long long)s0 * 128 + c4]);
    const float4 mB = ld4hf(&M[(long long)e1 * 128 + c4]);
    const float4 mC = ld4hf(&M[(long long)e2 * 128 + c4]);
    const float4 mD = ld4hf(&M[(long long)e3 * 128 + c4]);
    const float4 bA = ld4hf(&ABs[(long long)sA * 256 + 128 + c4]);
    const float4 bB = ld4hf(&ABs[(long long)sB * 256 + 128 + c4]);
    const float4 bC = ld4hf(&ABs[(long long)sC * 256 + 128 + c4]);
    const float4 bD = ld4hf(&ABs[(long long)sD * 256 + 128 + c4]);
    upd(mA, bA);
    if (s0 + 1 < end) upd(mB, bB);
    if (s0 + 2 < end) upd(mC, bC);
    if (s0 + 3 < end) upd(mD, bD);
  }

  const float inv = 1.0f / degc;
  float mean[4], stdv[4];
#pragma unroll
  for (int j = 0; j < 4; ++j) {
    mean[j] = sum[j] * inv;
    float var = sq[j] * inv - mean[j] * mean[j];
    stdv[j] = sqrtf(fmaxf(var, 0.f) + 1e-5f);
    if (cnt == 0) { mn[j] = 0.f; mx[j] = 0.f; }
  }
  const int sc = swk(n, c4);
  const long long base = (long long)n * 512 + sc;
  ushort4 o;
  o.x = f2h(mean[0]); o.y = f2h(mean[1]); o.z = f2h(mean[2]); o.w = f2h(mean[3]);
  *(ushort4*)&ag[base] = o;
  o.x = f2h(mn[0]); o.y = f2h(mn[1]); o.z = f2h(mn[2]); o.w = f2h(mn[3]);
  *(ushort4*)&ag[base + 128] = o;
  o.x = f2h(mx[0]); o.y = f2h(mx[1]); o.z = f2h(mx[2]); o.w = f2h(mx[3]);
  *(ushort4*)&ag[base + 256] = o;
  o.x = f2h(stdv[0]); o.y = f2h(stdv[1]); o.z = f2h(stdv[2]); o.w = f2h(stdv[3]);
  *(ushort4*)&ag[base + 384] = o;
}

// ---------------------------------------------------------------------------
// BatchNorm stats over N rows, 128 cols + coefficient precompute + apply
// ---------------------------------------------------------------------------
__global__ __launch_bounds__(256) void bn_partial(const float* __restrict__ y,
                                                  float* __restrict__ colsum,
                                                  float* __restrict__ colsq)
{
  int c = threadIdx.x & 127;
  int rh = threadIdx.x >> 7;
  int r0 = blockIdx.x * 128;
  float s = 0.f, q = 0.f;
  for (int r = r0 + rh; r < r0 + 128; r += 2) {
    float v = y[(long long)r * 128 + c];
    s += v;
    q += v * v;
  }
  __shared__ float ps[256], pq[256];
  ps[threadIdx.x] = s;
  pq[threadIdx.x] = q;
  __syncthreads();
  if (threadIdx.x < 128) {
    atomicAdd(&colsum[c], ps[c] + ps[c + 128]);
    atomicAdd(&colsq[c], pq[c] + pq[c + 128]);
  }
}

// coef[c] = g*rsqrt(var+eps); coef[128+c] = b - mean*scale  (BN as FMA)
__global__ void bn_coef(const float* __restrict__ colsum, const float* __restrict__ colsq,
                        const float* __restrict__ g, const float* __restrict__ b,
                        float* __restrict__ coef)
{
  int c = threadIdx.x; // 128
  float mean = colsum[c] * (1.f / 16384.f);
  float var = colsq[c] * (1.f / 16384.f) - mean * mean;
  float sc = g[c] * rsqrtf(var + 1e-5f);
  coef[c] = sc;
  coef[128 + c] = b[c] - mean * sc;
}

// hb = fp16(relu(y*scale + shift)) pre-swizzled
__global__ __launch_bounds__(256) void bn_apply(const float* __restrict__ y,
                                                const float* __restrict__ coef,
                                                unsigned short* __restrict__ hb)
{
  int idx = blockIdx.x * 256 + threadIdx.x; // n*128+c
  int c = idx & 127, n = idx >> 7;
  float v = fmaxf(y[idx] * coef[c] + coef[128 + c], 0.f);
  hb[((long long)n << 7) + swk(n, c)] = f2h(v);
}

// ---------------------------------------------------------------------------
// Global mean pool (BN+ReLU fused) + head
// ---------------------------------------------------------------------------
__global__ void pool_add(const float* __restrict__ y, const float* __restrict__ colsum,
                         const float* __restrict__ colsq, const float* __restrict__ g,
                         const float* __restrict__ b, const int* __restrict__ batch,
                         float* __restrict__ pooled, float* __restrict__ cntf)
{
  int n = blockIdx.x, c = threadIdx.x;
  float mean = colsum[c] * (1.f / 16384.f);
  float var = colsq[c] * (1.f / 16384.f) - mean * mean;
  float v = fmaxf((y[(long long)n * 128 + c] - mean) * rsqrtf(var + 1e-5f) * g[c] + b[c], 0.f);
  int bb = batch[n];
  atomicAdd(&pooled[(long long)bb * 128 + c], v);
  if (c == 0) atomicAdd(&cntf[bb], 1.f);
}

__global__ __launch_bounds__(256) void zstats(const float* __restrict__ z,
                                              float* __restrict__ zm, float* __restrict__ zv)
{
  int j = blockIdx.x; // 64 cols
  float s = 0.f, q = 0.f;
  for (int g = threadIdx.x; g < GG; g += 256) {
    float v = z[g * 64 + j];
    s += v;
    q += v * v;
  }
  __shared__ float ps[256], pq[256];
  ps[threadIdx.x] = s;
  pq[threadIdx.x] = q;
  __syncthreads();
  for (int st = 128; st > 0; st >>= 1) {
    if (threadIdx.x < st) {
      ps[threadIdx.x] += ps[threadIdx.x + st];
      pq[threadIdx.x] += pq[threadIdx.x + st];
    }
    __syncthreads();
  }
  if (threadIdx.x == 0) {
    float m = ps[0] / (float)GG;
    zm[j] = m;
    zv[j] = pq[0] / (float)GG - m * m;
  }
}

__global__ void final_out(const float* __restrict__ z, const float* __restrict__ zm,
                          const float* __restrict__ zv, const float* __restrict__ hg,
                          const float* __restrict__ hb, const float* __restrict__ W2,
                          const float* __restrict__ b2, float* __restrict__ out)
{
  int g = blockIdx.x;
  int j = threadIdx.x; // 64 = one wave
  float v = (z[g * 64 + j] - zm[j]) * rsqrtf(zv[j] + 1e-5f) * hg[j] + hb[j];
  float t = v * W2[j];
#pragma unroll
  for (int off = 32; off > 0; off >>= 1) t += __shfl_down(t, off);
  if (j == 0) out[g] = t + b2[0];
}

// ---------------------------------------------------------------------------
extern "C" void kernel_launch(void* const* d_in, const int* in_sizes, int n_in,
                              void* d_out, int out_size, void* d_ws, size_t ws_size,
                              hipStream_t stream)
{
  (void)in_sizes; (void)n_in; (void)out_size;
  const float* x = (const float*)d_in[0];
  const float* eat = (const float*)d_in[1];
  const int* ei = (const int*)d_in[2];
  const int* batch = (const int*)d_in[3];
  const float* Wa = (const float*)d_in[4];
  const float* ba = (const float*)d_in[5];
  const float* We = (const float*)d_in[6];
  const float* be = (const float*)d_in[7];
  const float* We_conv = (const float*)d_in[8];
  const float* be_conv = (const float*)d_in[9];
  const float* Wpre = (const float*)d_in[10];
  const float* bpre = (const float*)d_in[11];
  const float* Wpost = (const float*)d_in[12];
  const float* bpost = (const float*)d_in[13];
  const float* Wlin = (const float*)d_in[14];
  const float* blin = (const float*)d_in[15];
  const float* bng = (const float*)d_in[16];
  const float* bnb = (const float*)d_in[17];
  const float* W1 = (const float*)d_in[18];
  const float* b1 = (const float*)d_in[19];
  const float* hg = (const float*)d_in[20];
  const float* hb = (const float*)d_in[21];
  const float* W2 = (const float*)d_in[22];
  const float* b2 = (const float*)d_in[23];
  float* out = (float*)d_out;

  const int* srcI = ei;
  const int* dstI = ei + EE;

  char* ws = (char*)d_ws;
  size_t off = 0;
  auto alloc = [&](size_t bytes) -> char* {
    char* p = ws + off;
    off += (bytes + 255) & ~(size_t)255;
    return p;
  };

  unsigned short* hbf = (unsigned short*)alloc((size_t)NN * 128 * 2); // fp16 h
  float* hn = (float*)alloc((size_t)NN * 128 * 4);
  unsigned short* eaf = (unsigned short*)alloc((size_t)EE * 128 * 2); // fp16 ea, CSR order
  unsigned short* AB = (unsigned short*)alloc((size_t)4 * NN * 256 * 2); // fp16 [T][N][256]
  char* Mregion = alloc((size_t)4 * EE * 128 * 2);           // Mb fp16 [4][E][128]; later P|Px fp32
  unsigned short* Mb = (unsigned short*)Mregion;
  float* P = (float*)Mregion;                                 // [N][384]
  float* Px = (float*)(Mregion + (size_t)NN * 384 * 4);       // [N][128]
  unsigned short* aggt = (unsigned short*)alloc((size_t)4 * NN * 512 * 2); // fp16 [T][N][512]
  float* s_arr = (float*)alloc((size_t)NN * 4);
  float* invs = (float*)alloc((size_t)NN * 4);
  int* degi = (int*)alloc((size_t)NN * 4);
  int* cursor = (int*)alloc((size_t)NN * 4);
  int* row_off = (int*)alloc((size_t)(NN + 1) * 4);
  int* slot_of = (int*)alloc((size_t)EE * 4);
  int* esrc = (int*)alloc((size_t)EE * 4);
  float* WfoldF = (float*)alloc((size_t)3 * 128 * 512 * 4);
  float* bfold = (float*)alloc((size_t)3 * 512 * 4);
  unsigned short* preABT = (unsigned short*)alloc((size_t)12 * 256 * 128 * 2);
  unsigned short* foldT = (unsigned short*)alloc((size_t)12 * 128 * 128 * 2);
  unsigned short* post3T = (unsigned short*)alloc((size_t)12 * 128 * 512 * 2);
  unsigned short* wxT = (unsigned short*)alloc((size_t)3 * 128 * 128 * 2);
  unsigned short* linT = (unsigned short*)alloc((size_t)3 * 128 * 128 * 2);
  unsigned short* w1T = (unsigned short*)alloc((size_t)64 * 128 * 2);
  float* colstats = (float*)alloc(512 * 4); // two ping-pong buffers of 256
  float* bncoef = (float*)alloc(256 * 4);
  float* pooled = (float*)alloc((size_t)GG * 128 * 4);
  float* cntf = (float*)alloc((size_t)GG * 4);
  float* zbuf = (float*)alloc((size_t)GG * 64 * 4);
  float* zm = (float*)alloc(64 * 4);
  float* zv = (float*)alloc(64 * 4);

  if (off > ws_size) return; // bail rather than corrupt

  float* cs[2] = {colstats, colstats + 256};

  // ---- graph structure ----
  hipMemsetAsync(degi, 0, (size_t)NN * 4, stream);
  count_deg<<<EE / 256, 256, 0, stream>>>(dstI, degi);
  scan_k<<<1, 1024, 0, stream>>>(degi, row_off, cursor, s_arr, invs);
  scatter_k<<<EE / 256, 256, 0, stream>>>(srcI, dstI, cursor, slot_of, esrc);

  // ---- encoders + weight folds/packing ----
  node_enc<<<NN, 128, 0, stream>>>(x, Wa, ba, hbf);
  edge_enc<<<EE, 128, 0, stream>>>(eat, We, be, slot_of, eaf); // after scatter_k
  fold_w<<<384, 512, 0, stream>>>(We_conv, Wpre, WfoldF);
  fold_b<<<3, 512, 0, stream>>>(be_conv, Wpre, bpre, bfold);
  tsplit_preAB<<<12 * 256, 128, 0, stream>>>(Wpre, preABT);
  tsplit_fold<<<12 * 128, 128, 0, stream>>>(WfoldF, foldT);
  tsplit_post3<<<12 * 128, 512, 0, stream>>>(Wpost, post3T);
  tsplit_wx<<<3 * 128, 128, 0, stream>>>(Wpost, wxT);
  tsplit_lin<<<3 * 128, 128, 0, stream>>>(Wlin, linT);
  tsplit_w1<<<64, 128, 0, stream>>>(W1, w1T);

  for (int l = 0; l < 3; ++l) {
    hipMemsetAsync(cs[l & 1], 0, 256 * 4, stream);
    // AB all towers: [N,128] @ [128,256] (z=4) -> fp16 [T][N][256]; A = hbf copy
    mgemm<1, 8, false, false, true><<<dim3(NN / 128, 2, 4), 256, 0, stream>>>(
        hbf, preABT + (size_t)l * 4 * 256 * 128, nullptr, (float*)AB, AuxP{},
        256, 128, 128, 256, 0, (long long)256 * 128, (long long)NN * 256, 0);
    // C all 4 towers (streaming, CSR-ordered ea): [E,128]@[128,128]+bfold -> fp16
    mgemm<1, 8, true, false, true><<<dim3(EE / 128, 1, 4), 256, 0, stream>>>(
        eaf, foldT + (size_t)l * 4 * 128 * 128, bfold + l * 512, (float*)Mb, AuxP{},
        128, 128, 128, 128, 0, (long long)128 * 128, (long long)EE * 128, 128);
    // stats over m = (A + B[src]) + C ; all 4 towers per block
    aggregate_ct<<<dim3(NN / 2, 1, 1), 256, 0, stream>>>(AB, Mb, row_off, esrc, aggt);
    // P all towers: fp16 [N,512] @ [512,96] (z=4, exact 96-col tile) -> P[:, z*96..]
    mgemm<1, 6, false, false, false><<<dim3(NN / 128, 1, 4), 256, 0, stream>>>(
        aggt, post3T + (size_t)l * 4 * 128 * 512, nullptr, P, AuxP{},
        96, 512, 512, 384, (long long)NN * 512, (long long)128 * 512, 96, 0);
    // Px: [N,128] @ [128,128]; A = hbf copy
    mgemm<1, 8, false, false, false><<<dim3(NN / 128, 1, 1), 256, 0, stream>>>(
        hbf, wxT + (size_t)l * 128 * 128, nullptr, Px, AuxP{},
        128, 128, 128, 128, 0, 0, 0, 0);
    // lin (post-combine fused in A-staging): [N,128] @ [128,128] + blin -> hn
    mgemm<3, 8, true, false, false><<<dim3(NN / 128, 1, 1), 256, 0, stream>>>(
        nullptr, linT + (size_t)l * 128 * 128, blin + l * 128, hn,
        AuxP{P, Px, s_arr, invs, bpost + l * 128},
        128, 128, 128, 128, 0, 0, 0, 0);
    bn_partial<<<128, 256, 0, stream>>>(hn, cs[l & 1], cs[l & 1] + 128);
    if (l < 2) {
      bn_coef<<<1, 128, 0, stream>>>(cs[l & 1], cs[l & 1] + 128,
                                     bng + l * 128, bnb + l * 128, bncoef);
      bn_apply<<<NN * 128 / 256, 256, 0, stream>>>(hn, bncoef, hbf);
    }
  }

  // ---- pooling (BN+ReLU fused) + head ----
  hipMemsetAsync(pooled, 0, (size_t)GG * 128 * 4, stream);
  hipMemsetAsync(cntf, 0, (size_t)GG * 4, stream);
  pool_add<<<NN, 128, 0, stream>>>(hn, cs[0], cs[0] + 128,
                                   bng + 2 * 128, bnb + 2 * 128, batch, pooled, cntf);
  mgemm<4, 4, true, true, false><<<dim3(GG / 128, 1, 1), 256, 0, stream>>>(
      pooled, w1T, b1, zbuf, AuxP{cntf, nullptr, nullptr, nullptr, nullptr},
      64, 128, 128, 64, 0, 0, 0, 0);
  zstats<<<64, 256, 0, stream>>>(zbuf, zm, zv);
  final_out<<<GG, 64, 0, stream>>>(zbuf, zm, zv, hg, hb, W2, b2, out);
}

// Round 9
// 596.712 us; speedup vs baseline: 1.5924x; 1.0997x over previous
//
#include <hip/hip_runtime.h>
#include <hip/hip_bf16.h>

#define DEVFN static __device__ __forceinline__

constexpr int NN = 16384;
constexpr int EE = 65536;
constexpr int GG = 512;
constexpr float AVG_LOG_F = 1.0227308671603782f; // (sum d*log d, d=1..4, hist 1,2,3,4)/10

typedef _Float16 hfrag __attribute__((ext_vector_type(8))); // 8 fp16 = 4 VGPR (MFMA A/B)
typedef __attribute__((ext_vector_type(4))) float f4;       // MFMA C/D

// fp32 <-> fp16 (RNE, native v_cvt). Measured (r5-r8): bf16 slabs +0.0097
// absmax; fp16 slabs noise-level. All intermediates + GEMM operands fp16.
DEVFN unsigned short f2h(float f) {
  _Float16 h = (_Float16)f;
  unsigned short r; __builtin_memcpy(&r, &h, 2); return r;
}
DEVFN float h2f(unsigned short s) {
  _Float16 h; __builtin_memcpy(&h, &s, 2); return (float)h;
}

// load 4 fp16 -> float4
DEVFN float4 ld4hf(const unsigned short* p) {
  ushort4 u = *(const ushort4*)p;
  float4 r;
  r.x = h2f(u.x); r.y = h2f(u.y); r.z = h2f(u.z); r.w = h2f(u.w);
  return r;
}

// XOR swizzle for packed fp16 [R][K] operand arrays staged with global_load_lds:
// element (row,k) lives at row*K + swk(row,k). Within each 32-wide K window the
// four 8-element slots are permuted by (row>>1)&3 so a wave's ds_read_b128
// fragment reads become a permutation of a contiguous 1 KB region ->
// bank-conflict-free. global_load_lds copies LINEARLY, so the swizzle is baked
// into the packed global layout (both-sides rule, #21).
DEVFN int swk(int row, int k) {
  return (k & ~31) + ((((k >> 3) & 3) ^ ((row >> 1) & 3)) << 3) + (k & 7);
}

// async global->LDS, 16 B per lane; LDS dest = wave-uniform base + lane*16
DEVFN void gll16(const unsigned short* g, unsigned short* l) {
  __builtin_amdgcn_global_load_lds(
      (__attribute__((address_space(1))) void*)g,
      (__attribute__((address_space(3))) void*)l, 16, 0, 0);
}

// aux pointer bundle for fused A-staging modes
struct AuxP {
  const float* p0;
  const float* p1;
  const float* p2;
  const float* p3;
  const float* p4;
};

// ---------------------------------------------------------------------------
// fp16 MFMA GEMM: C[M,Nc] = A[M,K] @ W[K,Nc], fp32 accumulate.
// A-staging modes (ASRC):
//   1: fp16 ushort input (pre-swizzled), gll copy
//   3: lin-fused: K=256 two-phase. k<128: A = P_id + s*P_amp + invs*P_att +
//      bpost (ds-write path; p0=P, p2=s, p3=invs, p4=bpost). k>=128: A = hbf
//      (Av, gll copy) against the folded Wx@Wlin half of B. Epilogue also
//      accumulates BN column stats into p1 (colsum|colsq) -- replaces
//      bn_partial.
//   4: fp32 / rowcount (p0=cntf) -- global mean pool divide (ds-write path)
// B (WT) pre-swizzled packed fp16, staged via global_load_lds.
// OHALF: epilogue stores fp16 (slabs consumed by aggregate_ct only).
// NT = column fragments (tile N = NT*16). r1 sync structure (measured best):
// double-buffered LDS, stage tile k+1 via gll before MFMA on tile k, one
// __syncthreads per step (its vmcnt/lgkm drain completes the prefetch).
// Block 256 = 4 waves; tile M=128, BK=32. M%128==0, K%32==0, col<Nc guarded.
// ---------------------------------------------------------------------------
template <int ASRC, int NT, bool BIAS, bool RELU, bool OHALF>
__global__ __launch_bounds__(256) void mgemm(
    const void* __restrict__ Av, const unsigned short* __restrict__ WT,
    const float* __restrict__ bias,
    float* __restrict__ C, AuxP aux,
    int Nc, int K, int lda, int ldc,
    long long bsA, long long bsW, long long bsC, int bsBias)
{
  constexpr bool COPYA = (ASRC == 1);
  constexpr int BST = NT * 16 * 32; // ushorts per B buffer

  const int z = blockIdx.z;
  WT += (long long)z * bsW;
  if (BIAS) bias += (long long)z * bsBias;
  float* Cf = C + (OHALF ? 0 : (long long)z * bsC);
  unsigned short* Cu = (unsigned short*)C + (OHALF ? (long long)z * bsC : 0);

  __shared__ __align__(16) unsigned short AhS[2 * 128 * 32];
  __shared__ __align__(16) unsigned short BhS[2 * BST];

  const int tid = threadIdx.x;
  const long long bm = (long long)blockIdx.x * 128;
  const int bn = blockIdx.y * (NT * 16);
  const int w = tid >> 6;
  const int lane = tid & 63;
  const int quad = lane >> 4;
  const int c16 = lane & 15;
  const int srow = lane >> 2;        // staging row within 16-row chunk
  const int sslot = (lane & 3) << 3; // staging slot (ushort offset)

  // ds-write-mode indices: each thread produces 16 A elements of one row-half
  const int arow = tid >> 1;
  const int sel = tid & 1;
  const long long rowsrc = bm + arow;

  f4 acc[2][NT];
#pragma unroll
  for (int mt = 0; mt < 2; ++mt)
#pragma unroll
    for (int nt = 0; nt < NT; ++nt) acc[mt][nt] = (f4){0.f, 0.f, 0.f, 0.f};

  // lane-invariant staging bases
  const unsigned short* whp = WT + (long long)(bn + srow) * K + sslot;

  const unsigned short* ahp = nullptr;
  if (COPYA || ASRC == 3)
    ahp = (const unsigned short*)Av + (long long)z * bsA + (bm + srow) * (long long)lda + sslot;

  // ds-write-mode A state (ASRC 3 / 4)
  float invdc = 1.f;
  float sv = 0.f, iv = 0.f;
  const float* apA = nullptr;
  const float* Prow_base = nullptr;
  if (ASRC == 3) {
    Prow_base = aux.p0 + rowsrc * 384;
    sv = aux.p2[rowsrc];
    iv = aux.p3[rowsrc];
  } else if (ASRC == 4) {
    apA = (const float*)Av + (long long)z * bsA + rowsrc * lda;
    invdc = 1.f / fmaxf(aux.p0[rowsrc], 1.f);
  }
  // swizzled LDS write offsets for ds-write-mode A
  const int swa = (arow >> 1) & 3;
  const int s0us = arow * 32 + (((2 * sel) ^ swa) << 3);
  const int s1us = arow * 32 + (((2 * sel + 1) ^ swa) << 3);

  // fragment-read swizzle: slot quad ^ ((row>>1)&3); row bits 1..2 == c16 bits
  const int swr8 = ((quad ^ ((c16 >> 1) & 3)) << 3);

  auto stageB = [&](int bi, int k0) {
#pragma unroll
    for (int ch = w; ch < NT; ch += 4)
      gll16(whp + (long long)ch * 16 * K + k0, BhS + bi * BST + ch * 512);
  };
  auto stageA = [&](int bi, int k0) { // gll copy of A rows (k0 relative to lda)
#pragma unroll
    for (int ch = w; ch < 8; ch += 4)
      gll16(ahp + (long long)ch * 16 * lda + k0, AhS + bi * 4096 + ch * 512);
  };
  auto stageLoad = [&](int k0, float* va) {
    const int ck0 = k0 + sel * 16;
    if (ASRC == 3) {
      const float* Prow = Prow_base + ((ck0 >> 5) * 96) + (ck0 & 31);
#pragma unroll
      for (int i = 0; i < 16; ++i)
        va[i] = Prow[i] + sv * Prow[32 + i] + iv * Prow[64 + i] + aux.p4[ck0 + i];
    } else {
      *(float4*)&va[0] = *(const float4*)(apA + ck0);
      *(float4*)&va[4] = *(const float4*)(apA + ck0 + 4);
      *(float4*)&va[8] = *(const float4*)(apA + ck0 + 8);
      *(float4*)&va[12] = *(const float4*)(apA + ck0 + 12);
    }
  };
  auto stageWrite = [&](int bi, const float* va) {
    hfrag hv0, hv1;
#pragma unroll
    for (int i = 0; i < 16; ++i) {
      float x = va[i];
      if (ASRC == 4) x *= invdc;
      if (i < 8) hv0[i] = (_Float16)x;
      else       hv1[i - 8] = (_Float16)x;
    }
    *(hfrag*)&AhS[bi * 4096 + s0us] = hv0;
    *(hfrag*)&AhS[bi * 4096 + s1us] = hv1;
  };
  auto fragmfma = [&](int bi) {
    hfrag ah[2];
#pragma unroll
    for (int mt = 0; mt < 2; ++mt) {
      const int r = w * 32 + mt * 16 + c16;
      ah[mt] = *(const hfrag*)&AhS[bi * 4096 + r * 32 + swr8];
    }
#pragma unroll
    for (int nt = 0; nt < NT; ++nt) {
      const int r = nt * 16 + c16;
      hfrag bh = *(const hfrag*)&BhS[bi * BST + r * 32 + swr8];
#pragma unroll
      for (int mt = 0; mt < 2; ++mt)
        acc[mt][nt] = __builtin_amdgcn_mfma_f32_16x16x32_f16(ah[mt], bh, acc[mt][nt], 0, 0, 0);
    }
  };

  float va[16];
  const int nk = K >> 5;

  // prologue: fill buffer 0 (ASRC3's tile 0 is ds-mode)
  if (COPYA) {
    stageA(0, 0);
    stageB(0, 0);
  } else {
    stageLoad(0, va);
    stageB(0, 0);
    stageWrite(0, va);
  }
  __syncthreads();

  for (int kt = 0; kt < nk; ++kt) {
    const int bi = kt & 1;
    const bool pf = (kt + 1 < nk);
    bool nextds = false;
    if (pf) {
      const int k0 = (kt + 1) << 5;
      stageB(bi ^ 1, k0);
      if (COPYA) {
        stageA(bi ^ 1, k0);
      } else if (ASRC == 3 && k0 >= 128) {
        stageA(bi ^ 1, k0 - 128); // copy phase: A = hbf (x-through path)
      } else {
        stageLoad(k0, va);
        nextds = true;
      }
    }
    fragmfma(bi);
    if (nextds) stageWrite(bi ^ 1, va);
    __syncthreads();
  }

  // epilogue: C/D layout col=lane&15, row=quad*4+reg
  float ls[NT], lq[NT];
#pragma unroll
  for (int nt = 0; nt < NT; ++nt) { ls[nt] = 0.f; lq[nt] = 0.f; }
#pragma unroll
  for (int nt = 0; nt < NT; ++nt) {
    int col = bn + nt * 16 + c16;
    if (col >= Nc) continue;
    float bv = BIAS ? bias[col] : 0.f;
#pragma unroll
    for (int mt = 0; mt < 2; ++mt) {
#pragma unroll
      for (int r = 0; r < 4; ++r) {
        long long row = bm + w * 32 + mt * 16 + quad * 4 + r;
        float v = acc[mt][nt][r] + bv;
        if (RELU) v = fmaxf(v, 0.f);
        if (ASRC == 3) { ls[nt] += v; lq[nt] += v * v; }
        if (OHALF) Cu[row * ldc + col] = f2h(v);
        else Cf[row * ldc + col] = v;
      }
    }
  }
  if constexpr (ASRC == 3) {
    // fused BN column partial stats (replaces bn_partial): LDS reduce + atomics
    float* csum = (float*)AhS;  // reuse LDS (all waves past final barrier)
    float* csq = csum + 128;
    if (tid < 256 && tid >= 128) {} // keep lanes uniform
    if (tid < 128) { csum[tid] = 0.f; csq[tid] = 0.f; }
    __syncthreads();
#pragma unroll
    for (int nt = 0; nt < NT; ++nt) {
      int col = bn + nt * 16 + c16;
      atomicAdd(&csum[col], ls[nt]);
      atomicAdd(&csq[col], lq[nt]);
    }
    __syncthreads();
    float* colsum = (float*)aux.p1;
    if (tid < 128) {
      atomicAdd(&colsum[tid], csum[tid]);
      atomicAdd(&colsum[128 + tid], csq[tid]);
    }
  }
}

// ---------------------------------------------------------------------------
// Encoders -- h / ea produced directly as pre-swizzled fp16
// ---------------------------------------------------------------------------
__global__ void node_enc(const float* __restrict__ x, const float* __restrict__ Wa,
                         const float* __restrict__ ba, unsigned short* __restrict__ hb)
{
  int n = blockIdx.x, c = threadIdx.x; // 128
  float acc = ba[c];
#pragma unroll
  for (int k = 0; k < 11; ++k) acc += x[n * 11 + k] * Wa[k * 128 + c];
  hb[((long long)n << 7) + swk(n, c)] = f2h(fmaxf(acc, 0.f));
}

// writes fp16 DIRECTLY in CSR slot order, PRE-SWIZZLED for gll staging
__global__ void edge_enc(const float* __restrict__ eat, const float* __restrict__ We,
                         const float* __restrict__ be, const int* __restrict__ slot_of,
                         unsigned short* __restrict__ ef)
{
  int e = blockIdx.x, c = threadIdx.x; // 128
  float acc = be[c];
#pragma unroll
  for (int k = 0; k < 4; ++k) acc += eat[e * 4 + k] * We[k * 128 + c];
  long long slot = slot_of[e];
  ef[slot * 128 + swk((int)slot, c)] = f2h(fmaxf(acc, 0.f));
}

// ---------------------------------------------------------------------------
// CSR build: count -> scan (also inits cursor + s/invs) -> scatter
// ---------------------------------------------------------------------------
__global__ void count_deg(const int* __restrict__ dst, int* __restrict__ degi)
{
  int e = blockIdx.x * 256 + threadIdx.x;
  if (e < EE) atomicAdd(&degi[dst[e]], 1);
}

__global__ __launch_bounds__(1024) void scan_k(const int* __restrict__ degi,
                                               int* __restrict__ row_off,
                                               int* __restrict__ cursor,
                                               float* __restrict__ s_arr,
                                               float* __restrict__ invs)
{
  __shared__ int tsum[1024];
  int t = threadIdx.x;
  int local[16];
  int base = t * 16;
  int s = 0;
#pragma unroll
  for (int i = 0; i < 16; ++i) { local[i] = s; s += degi[base + i]; }
  tsum[t] = s;
  __syncthreads();
  for (int off = 1; off < 1024; off <<= 1) {
    int v = (t >= off) ? tsum[t - off] : 0;
    __syncthreads();
    tsum[t] += v;
    __syncthreads();
  }
  int prev = (t == 0) ? 0 : tsum[t - 1];
#pragma unroll
  for (int i = 0; i < 16; ++i) {
    int start = prev + local[i];
    row_off[base + i] = start;
    cursor[base + i] = start;
    int cnt = degi[base + i];
    float degc = fmaxf((float)cnt, 1.f);
    float sv = logf(degc + 1.f) / AVG_LOG_F;
    s_arr[base + i] = sv;
    invs[base + i] = 1.f / sv;
  }
  if (t == 1023) row_off[NN] = tsum[1023];
}

__global__ void scatter_k(const int* __restrict__ src, const int* __restrict__ dst,
                          int* __restrict__ cursor,
                          int* __restrict__ slot_of, int* __restrict__ esrc)
{
  int e = blockIdx.x * 256 + threadIdx.x;
  if (e >= EE) return;
  int d = dst[e];
  int slot = atomicAdd(&cursor[d], 1);
  slot_of[e] = slot;
  esrc[slot] = src[e];
}

// ---------------------------------------------------------------------------
// Weight folds (fp32)
// ---------------------------------------------------------------------------
__global__ __launch_bounds__(512) void fold_w(const float* __restrict__ We_conv,
                                              const float* __restrict__ Wpre,
                                              float* __restrict__ Wfold)
{
  int k = blockIdx.x & 127, l = blockIdx.x >> 7;
  int t = threadIdx.x >> 7, f = threadIdx.x & 127;
  const float* wc = We_conv + (long long)(l * 128 + k) * 128;
  const float* wp = Wpre + ((long long)((l * 4 + t) * 384 + 256)) * 128 + f;
  float acc = 0.f;
  for (int j = 0; j < 128; ++j) acc += wc[j] * wp[(long long)j * 128];
  Wfold[((long long)(l * 128 + k)) * 512 + threadIdx.x] = acc;
}

__global__ __launch_bounds__(512) void fold_b(const float* __restrict__ be_conv,
                                              const float* __restrict__ Wpre,
                                              const float* __restrict__ bpre,
                                              float* __restrict__ bfold)
{
  int l = blockIdx.x;
  int t = threadIdx.x >> 7, f = threadIdx.x & 127;
  const float* bc = be_conv + l * 128;
  const float* wp = Wpre + ((long long)((l * 4 + t) * 384 + 256)) * 128 + f;
  float acc = bpre[(l * 4 + t) * 128 + f];
  for (int j = 0; j < 128; ++j) acc += bc[j] * wp[(long long)j * 128];
  bfold[l * 512 + threadIdx.x] = acc;
}

// ---------------------------------------------------------------------------
// pack_all: ALL fp32 -> fp16 swizzled weight packers in ONE launch.
// Segments by blockIdx (128 threads each):
//  [0,3072)      preABT[lt][n(256)][k(128)]
//  [3072,4608)   foldT[lt][n(128)][k(128)]   (reads WfoldF, after fold_w)
//  [4608,6144)   post3T[lt][c(128)][r(512)]  (4 r per thread)
//  [6144,6528)   linT2 lo-half: Wlin transpose [l][n][k<128]
//  [6528,6912)   linT2 hi-half: Wxl[l][o][128+kk] = sum_c Wx[kk][c]*Wlin[c][o]
//  [6912,6976)   w1T[n(64)][k(128)]
// ---------------------------------------------------------------------------
__global__ __launch_bounds__(128) void pack_all(
    const float* __restrict__ Wpre, const float* __restrict__ WfoldF,
    const float* __restrict__ Wpost, const float* __restrict__ Wlin,
    const float* __restrict__ W1,
    unsigned short* __restrict__ preABT, unsigned short* __restrict__ foldT,
    unsigned short* __restrict__ post3T, unsigned short* __restrict__ linT2,
    unsigned short* __restrict__ w1T)
{
  const int b = blockIdx.x;
  const int t = threadIdx.x;
  if (b < 3072) {                       // preABT
    int lt = b >> 8, n = b & 255, k = t;
    int row = (n < 128) ? k : (128 + k);
    int f = n & 127;
    float v = Wpre[((long long)(lt * 384 + row)) * 128 + f];
    preABT[((long long)(lt * 256 + n)) * 128 + swk(n, k)] = f2h(v);
  } else if (b < 4608) {                // foldT
    int b2 = b - 3072;
    int lt = b2 >> 7, n = b2 & 127, k = t;
    int l = lt >> 2, tw = lt & 3;
    float v = WfoldF[((long long)(l * 128 + k)) * 512 + tw * 128 + n];
    foldT[((long long)(lt * 128 + n)) * 128 + swk(n, k)] = f2h(v);
  } else if (b < 6144) {                // post3T
    int b3 = b - 4608;
    int lt = b3 >> 7, c = b3 & 127;
#pragma unroll
    for (int j = 0; j < 4; ++j) {
      int r = t + 128 * j;
      float v = 0.f;
      if (c < 96)
        v = Wpost[((long long)(lt * 1664 + 128 + (c >> 5) * 512 + r)) * 32 + (c & 31)];
      post3T[((long long)(lt * 128 + c)) * 512 + swk(c, r)] = f2h(v);
    }
  } else if (b < 6528) {                // linT2 low half: Wlin^T
    int b4 = b - 6144;
    int l = b4 >> 7, n = b4 & 127, k = t;
    float v = Wlin[((long long)(l * 128 + k)) * 128 + n];
    linT2[((long long)(l * 128 + n)) * 256 + swk(n, k)] = f2h(v);
  } else if (b < 6912) {                // linT2 high half: Wxl fold
    int b5 = b - 6528;
    int l = b5 >> 7, kk = b5 & 127, o = t;
    float acc = 0.f;
    for (int c = 0; c < 128; ++c) {
      float wx = Wpost[((long long)((l * 4 + (c >> 5)) * 1664 + kk)) * 32 + (c & 31)];
      acc += wx * Wlin[((long long)(l * 128 + c)) * 128 + o];
    }
    linT2[((long long)(l * 128 + o)) * 256 + swk(o, 128 + kk)] = f2h(acc);
  } else {                              // w1T
    int n = b - 6912, k = t;
    w1T[(long long)n * 128 + swk(n, k)] = f2h(W1[k * 64 + n]);
  }
}

// ---------------------------------------------------------------------------
// Per-tower aggregation, ALL FOUR towers in one block.
// Block 256 = 2 nodes x 4 towers x 32 lanes(x4 ch). Edges processed in
// chunks of 4: esrc batch-loaded first, then 8 independent loads in flight
// (breaks the esrc->ABs dependent-latency chain). AB and Mb slabs fp16.
// Output aggs fp16 [N][512], PRE-SWIZZLED (swk) for gll staging by the P gemm.
// ---------------------------------------------------------------------------
__global__ __launch_bounds__(256) void aggregate_ct(
    const unsigned short* __restrict__ ABb, const unsigned short* __restrict__ Mb,
    const int* __restrict__ row_off, const int* __restrict__ esrc,
    unsigned short* __restrict__ aggs)
{
  const int tid = threadIdx.x;
  const int c4 = (tid & 31) << 2;
  const int z = (tid >> 5) & 3;
  const int n = blockIdx.x * 2 + (tid >> 7);
  const unsigned short* M = Mb + (long long)z * EE * 128;
  const unsigned short* ABs = ABb + (long long)z * NN * 256;
  unsigned short* ag = aggs + (long long)z * NN * 512;
  const int beg = row_off[n], end = row_off[n + 1];
  const int cnt = end - beg;
  const float degc = fmaxf((float)cnt, 1.0f);
  const float4 aval = ld4hf(&ABs[(long long)n * 256 + c4]);

  float sum[4] = {0.f, 0.f, 0.f, 0.f}, sq[4] = {0.f, 0.f, 0.f, 0.f};
  float mn[4] = {INFINITY, INFINITY, INFINITY, INFINITY};
  float mx[4] = {-INFINITY, -INFINITY, -INFINITY, -INFINITY};

  auto upd = [&](const float4& mv, const float4& bv) {
    float m0 = aval.x + bv.x + mv.x;
    float m1 = aval.y + bv.y + mv.y;
    float m2 = aval.z + bv.z + mv.z;
    float m3 = aval.w + bv.w + mv.w;
    sum[0] += m0; sq[0] += m0 * m0; mn[0] = fminf(mn[0], m0); mx[0] = fmaxf(mx[0], m0);
    sum[1] += m1; sq[1] += m1 * m1; mn[1] = fminf(mn[1], m1); mx[1] = fmaxf(mx[1], m1);
    sum[2] += m2; sq[2] += m2 * m2; mn[2] = fminf(mn[2], m2); mx[2] = fmaxf(mx[2], m2);
    sum[3] += m3; sq[3] += m3 * m3; mn[3] = fminf(mn[3], m3); mx[3] = fmaxf(mx[3], m3);
  };

  for (int s0 = beg; s0 < end; s0 += 4) {
    const int e1 = min(s0 + 1, end - 1);
    const int e2 = min(s0 + 2, end - 1);
    const int e3 = min(s0 + 3, end - 1);
    const int sA = esrc[s0], sB = esrc[e1], sC = esrc[e2], sD = esrc[e3];
    const float4 mA = ld4hf(&M[(long long)s0 * 128 + c4]);
    const float4 mB = ld4hf(&M[(long long)e1 * 128 + c4]);
    const float4 mC = ld4hf(&M[(long long)e2 * 128 + c4]);
    const float4 mD = ld4hf(&M[(long long)e3 * 128 + c4]);
    const float4 bA = ld4hf(&ABs[(long long)sA * 256 + 128 + c4]);
    const float4 bB = ld4hf(&ABs[(long long)sB * 256 + 128 + c4]);
    const float4 bC = ld4hf(&ABs[(long long)sC * 256 + 128 + c4]);
    const float4 bD = ld4hf(&ABs[(long long)sD * 256 + 128 + c4]);
    upd(mA, bA);
    if (s0 + 1 < end) upd(mB, bB);
    if (s0 + 2 < end) upd(mC, bC);
    if (s0 + 3 < end) upd(mD, bD);
  }

  const float inv = 1.0f / degc;
  float mean[4], stdv[4];
#pragma unroll
  for (int j = 0; j < 4; ++j) {
    mean[j] = sum[j] * inv;
    float var = sq[j] * inv - mean[j] * mean[j];
    stdv[j] = sqrtf(fmaxf(var, 0.f) + 1e-5f);
    if (cnt == 0) { mn[j] = 0.f; mx[j] = 0.f; }
  }
  const int sc = swk(n, c4);
  const long long base = (long long)n * 512 + sc;
  ushort4 o;
  o.x = f2h(mean[0]); o.y = f2h(mean[1]); o.z = f2h(mean[2]); o.w = f2h(mean[3]);
  *(ushort4*)&ag[base] = o;
  o.x = f2h(mn[0]); o.y = f2h(mn[1]); o.z = f2h(mn[2]); o.w = f2h(mn[3]);
  *(ushort4*)&ag[base + 128] = o;
  o.x = f2h(mx[0]); o.y = f2h(mx[1]); o.z = f2h(mx[2]); o.w = f2h(mx[3]);
  *(ushort4*)&ag[base + 256] = o;
  o.x = f2h(stdv[0]); o.y = f2h(stdv[1]); o.z = f2h(stdv[2]); o.w = f2h(stdv[3]);
  *(ushort4*)&ag[base + 384] = o;
}

// ---------------------------------------------------------------------------
// BN coefficient precompute + apply
// ---------------------------------------------------------------------------
// coef[c] = g*rsqrt(var+eps); coef[128+c] = b - mean*scale  (BN as FMA)
__global__ void bn_coef(const float* __restrict__ colsum, const float* __restrict__ colsq,
                        const float* __restrict__ g, const float* __restrict__ b,
                        float* __restrict__ coef)
{
  int c = threadIdx.x; // 128
  float mean = colsum[c] * (1.f / 16384.f);
  float var = colsq[c] * (1.f / 16384.f) - mean * mean;
  float sc = g[c] * rsqrtf(var + 1e-5f);
  coef[c] = sc;
  coef[128 + c] = b[c] - mean * sc;
}

// hb = fp16(relu(y*scale + shift)) pre-swizzled
__global__ __launch_bounds__(256) void bn_apply(const float* __restrict__ y,
                                                const float* __restrict__ coef,
                                                unsigned short* __restrict__ hb)
{
  int idx = blockIdx.x * 256 + threadIdx.x; // n*128+c
  int c = idx & 127, n = idx >> 7;
  float v = fmaxf(y[idx] * coef[c] + coef[128 + c], 0.f);
  hb[((long long)n << 7) + swk(n, c)] = f2h(v);
}

// ---------------------------------------------------------------------------
// Global mean pool (BN+ReLU fused) + head
// ---------------------------------------------------------------------------
__global__ void pool_add(const float* __restrict__ y, const float* __restrict__ colsum,
                         const float* __restrict__ colsq, const float* __restrict__ g,
                         const float* __restrict__ b, const int* __restrict__ batch,
                         float* __restrict__ pooled, float* __restrict__ cntf)
{
  int n = blockIdx.x, c = threadIdx.x;
  float mean = colsum[c] * (1.f / 16384.f);
  float var = colsq[c] * (1.f / 16384.f) - mean * mean;
  float v = fmaxf((y[(long long)n * 128 + c] - mean) * rsqrtf(var + 1e-5f) * g[c] + b[c], 0.f);
  int bb = batch[n];
  atomicAdd(&pooled[(long long)bb * 128 + c], v);
  if (c == 0) atomicAdd(&cntf[bb], 1.f);
}

__global__ __launch_bounds__(256) void zstats(const float* __restrict__ z,
                                              float* __restrict__ zm, float* __restrict__ zv)
{
  int j = blockIdx.x; // 64 cols
  float s = 0.f, q = 0.f;
  for (int g = threadIdx.x; g < GG; g += 256) {
    float v = z[g * 64 + j];
    s += v;
    q += v * v;
  }
  __shared__ float ps[256], pq[256];
  ps[threadIdx.x] = s;
  pq[threadIdx.x] = q;
  __syncthreads();
  for (int st = 128; st > 0; st >>= 1) {
    if (threadIdx.x < st) {
      ps[threadIdx.x] += ps[threadIdx.x + st];
      pq[threadIdx.x] += pq[threadIdx.x + st];
    }
    __syncthreads();
  }
  if (threadIdx.x == 0) {
    float m = ps[0] / (float)GG;
    zm[j] = m;
    zv[j] = pq[0] / (float)GG - m * m;
  }
}

__global__ void final_out(const float* __restrict__ z, const float* __restrict__ zm,
                          const float* __restrict__ zv, const float* __restrict__ hg,
                          const float* __restrict__ hb, const float* __restrict__ W2,
                          const float* __restrict__ b2, float* __restrict__ out)
{
  int g = blockIdx.x;
  int j = threadIdx.x; // 64 = one wave
  float v = (z[g * 64 + j] - zm[j]) * rsqrtf(zv[j] + 1e-5f) * hg[j] + hb[j];
  float t = v * W2[j];
#pragma unroll
  for (int off = 32; off > 0; off >>= 1) t += __shfl_down(t, off);
  if (j == 0) out[g] = t + b2[0];
}

// ---------------------------------------------------------------------------
extern "C" void kernel_launch(void* const* d_in, const int* in_sizes, int n_in,
                              void* d_out, int out_size, void* d_ws, size_t ws_size,
                              hipStream_t stream)
{
  (void)in_sizes; (void)n_in; (void)out_size;
  const float* x = (const float*)d_in[0];
  const float* eat = (const float*)d_in[1];
  const int* ei = (const int*)d_in[2];
  const int* batch = (const int*)d_in[3];
  const float* Wa = (const float*)d_in[4];
  const float* ba = (const float*)d_in[5];
  const float* We = (const float*)d_in[6];
  const float* be = (const float*)d_in[7];
  const float* We_conv = (const float*)d_in[8];
  const float* be_conv = (const float*)d_in[9];
  const float* Wpre = (const float*)d_in[10];
  const float* bpre = (const float*)d_in[11];
  const float* Wpost = (const float*)d_in[12];
  const float* bpost = (const float*)d_in[13];
  const float* Wlin = (const float*)d_in[14];
  const float* blin = (const float*)d_in[15];
  const float* bng = (const float*)d_in[16];
  const float* bnb = (const float*)d_in[17];
  const float* W1 = (const float*)d_in[18];
  const float* b1 = (const float*)d_in[19];
  const float* hg = (const float*)d_in[20];
  const float* hb = (const float*)d_in[21];
  const float* W2 = (const float*)d_in[22];
  const float* b2 = (const float*)d_in[23];
  float* out = (float*)d_out;

  const int* srcI = ei;
  const int* dstI = ei + EE;

  char* ws = (char*)d_ws;
  size_t off = 0;
  auto alloc = [&](size_t bytes) -> char* {
    char* p = ws + off;
    off += (bytes + 255) & ~(size_t)255;
    return p;
  };

  unsigned short* hbf = (unsigned short*)alloc((size_t)NN * 128 * 2); // fp16 h
  float* hn = (float*)alloc((size_t)NN * 128 * 4);
  unsigned short* eaf = (unsigned short*)alloc((size_t)EE * 128 * 2); // fp16 ea, CSR order
  unsigned short* AB = (unsigned short*)alloc((size_t)4 * NN * 256 * 2); // fp16 [T][N][256]
  char* Mregion = alloc((size_t)4 * EE * 128 * 2);           // Mb fp16 [4][E][128]; later P fp32
  unsigned short* Mb = (unsigned short*)Mregion;
  float* P = (float*)Mregion;                                 // [N][384]
  unsigned short* aggt = (unsigned short*)alloc((size_t)4 * NN * 512 * 2); // fp16 [T][N][512]
  float* s_arr = (float*)alloc((size_t)NN * 4);
  float* invs = (float*)alloc((size_t)NN * 4);
  int* degi = (int*)alloc((size_t)NN * 4);
  int* cursor = (int*)alloc((size_t)NN * 4);
  int* row_off = (int*)alloc((size_t)(NN + 1) * 4);
  int* slot_of = (int*)alloc((size_t)EE * 4);
  int* esrc = (int*)alloc((size_t)EE * 4);
  float* WfoldF = (float*)alloc((size_t)3 * 128 * 512 * 4);
  float* bfold = (float*)alloc((size_t)3 * 512 * 4);
  unsigned short* preABT = (unsigned short*)alloc((size_t)12 * 256 * 128 * 2);
  unsigned short* foldT = (unsigned short*)alloc((size_t)12 * 128 * 128 * 2);
  unsigned short* post3T = (unsigned short*)alloc((size_t)12 * 128 * 512 * 2);
  unsigned short* linT2 = (unsigned short*)alloc((size_t)3 * 128 * 256 * 2); // [Wlin^T | Wx@Wlin]
  unsigned short* w1T = (unsigned short*)alloc((size_t)64 * 128 * 2);
  float* colstats = (float*)alloc(512 * 4); // two ping-pong buffers of 256
  float* bncoef = (float*)alloc(256 * 4);
  float* pooled = (float*)alloc((size_t)GG * 128 * 4);
  float* cntf = (float*)alloc((size_t)GG * 4);
  float* zbuf = (float*)alloc((size_t)GG * 64 * 4);
  float* zm = (float*)alloc(64 * 4);
  float* zv = (float*)alloc(64 * 4);

  if (off > ws_size) return; // bail rather than corrupt

  float* cs[2] = {colstats, colstats + 256};

  // ---- graph structure ----
  hipMemsetAsync(degi, 0, (size_t)NN * 4, stream);
  count_deg<<<EE / 256, 256, 0, stream>>>(dstI, degi);
  scan_k<<<1, 1024, 0, stream>>>(degi, row_off, cursor, s_arr, invs);
  scatter_k<<<EE / 256, 256, 0, stream>>>(srcI, dstI, cursor, slot_of, esrc);

  // ---- encoders + weight folds/packing ----
  node_enc<<<NN, 128, 0, stream>>>(x, Wa, ba, hbf);
  edge_enc<<<EE, 128, 0, stream>>>(eat, We, be, slot_of, eaf); // after scatter_k
  fold_w<<<384, 512, 0, stream>>>(We_conv, Wpre, WfoldF);
  fold_b<<<3, 512, 0, stream>>>(be_conv, Wpre, bpre, bfold);
  pack_all<<<6976, 128, 0, stream>>>(Wpre, WfoldF, Wpost, Wlin, W1,
                                     preABT, foldT, post3T, linT2, w1T);

  for (int l = 0; l < 3; ++l) {
    hipMemsetAsync(cs[l & 1], 0, 256 * 4, stream);
    // AB all towers: [N,128] @ [128,256] (z=4) -> fp16 [T][N][256]; A = hbf copy
    mgemm<1, 8, false, false, true><<<dim3(NN / 128, 2, 4), 256, 0, stream>>>(
        hbf, preABT + (size_t)l * 4 * 256 * 128, nullptr, (float*)AB, AuxP{},
        256, 128, 128, 256, 0, (long long)256 * 128, (long long)NN * 256, 0);
    // C all 4 towers (streaming, CSR-ordered ea): [E,128]@[128,128]+bfold -> fp16
    mgemm<1, 8, true, false, true><<<dim3(EE / 128, 1, 4), 256, 0, stream>>>(
        eaf, foldT + (size_t)l * 4 * 128 * 128, bfold + l * 512, (float*)Mb, AuxP{},
        128, 128, 128, 128, 0, (long long)128 * 128, (long long)EE * 128, 128);
    // stats over m = (A + B[src]) + C ; all 4 towers per block
    aggregate_ct<<<dim3(NN / 2, 1, 1), 256, 0, stream>>>(AB, Mb, row_off, esrc, aggt);
    // P all towers: fp16 [N,512] @ [512,96] (z=4, exact 96-col tile) -> P[:, z*96..]
    mgemm<1, 6, false, false, false><<<dim3(NN / 128, 1, 4), 256, 0, stream>>>(
        aggt, post3T + (size_t)l * 4 * 128 * 512, nullptr, P, AuxP{},
        96, 512, 512, 384, (long long)NN * 512, (long long)128 * 512, 96, 0);
    // lin (K=256 two-phase: P-combine | hbf x-through vs folded Wx@Wlin),
    // + blin; epilogue fuses BN column stats into cs[l&1]
    mgemm<3, 8, true, false, false><<<dim3(NN / 128, 1, 1), 256, 0, stream>>>(
        hbf, linT2 + (size_t)l * 128 * 256, blin + l * 128, hn,
        AuxP{P, cs[l & 1], s_arr, invs, bpost + l * 128},
        128, 256, 128, 128, 0, 0, 0, 0);
    if (l < 2) {
      bn_coef<<<1, 128, 0, stream>>>(cs[l & 1], cs[l & 1] + 128,
                                     bng + l * 128, bnb + l * 128, bncoef);
      bn_apply<<<NN * 128 / 256, 256, 0, stream>>>(hn, bncoef, hbf);
    }
  }

  // ---- pooling (BN+ReLU fused) + head ----
  hipMemsetAsync(pooled, 0, (size_t)GG * 128 * 4, stream);
  hipMemsetAsync(cntf, 0, (size_t)GG * 4, stream);
  pool_add<<<NN, 128, 0, stream>>>(hn, cs[0], cs[0] + 128,
                                   bng + 2 * 128, bnb + 2 * 128, batch, pooled, cntf);
  mgemm<4, 4, true, true, false><<<dim3(GG / 128, 1, 1), 256, 0, stream>>>(
      pooled, w1T, b1, zbuf, AuxP{cntf, nullptr, nullptr, nullptr, nullptr},
      64, 128, 128, 64, 0, 0, 0, 0);
  zstats<<<64, 256, 0, stream>>>(zbuf, zm, zv);
  final_out<<<GG, 64, 0, stream>>>(zbuf, zm, zv, hg, hb, W2, b2, out);
}

// Round 10
// 570.032 us; speedup vs baseline: 1.6669x; 1.0468x over previous
//
#include <hip/hip_runtime.h>
#include <hip/hip_bf16.h>

#define DEVFN static __device__ __forceinline__

constexpr int NN = 16384;
constexpr int EE = 65536;
constexpr int GG = 512;
constexpr float AVG_LOG_F = 1.0227308671603782f; // (sum d*log d, d=1..4, hist 1,2,3,4)/10

typedef _Float16 hfrag __attribute__((ext_vector_type(8))); // 8 fp16 = 4 VGPR (MFMA A/B)
typedef __attribute__((ext_vector_type(4))) float f4;       // MFMA C/D

// fp32 <-> fp16 (RNE, native v_cvt). Measured (r5-r8): bf16 slabs +0.0097
// absmax; fp16 slabs noise-level. All intermediates + GEMM operands fp16.
DEVFN unsigned short f2h(float f) {
  _Float16 h = (_Float16)f;
  unsigned short r; __builtin_memcpy(&r, &h, 2); return r;
}
DEVFN float h2f(unsigned short s) {
  _Float16 h; __builtin_memcpy(&h, &s, 2); return (float)h;
}

// load 4 fp16 -> float4
DEVFN float4 ld4hf(const unsigned short* p) {
  ushort4 u = *(const ushort4*)p;
  float4 r;
  r.x = h2f(u.x); r.y = h2f(u.y); r.z = h2f(u.z); r.w = h2f(u.w);
  return r;
}

// XOR swizzle for packed fp16 [R][K] operand arrays staged with global_load_lds:
// element (row,k) lives at row*K + swk(row,k). Within each 32-wide K window the
// four 8-element slots are permuted by (row>>1)&3 so a wave's ds_read_b128
// fragment reads become a permutation of a contiguous 1 KB region ->
// bank-conflict-free. global_load_lds copies LINEARLY, so the swizzle is baked
// into the packed global layout (both-sides rule, #21).
DEVFN int swk(int row, int k) {
  return (k & ~31) + ((((k >> 3) & 3) ^ ((row >> 1) & 3)) << 3) + (k & 7);
}

// async global->LDS, 16 B per lane; LDS dest = wave-uniform base + lane*16
DEVFN void gll16(const unsigned short* g, unsigned short* l) {
  __builtin_amdgcn_global_load_lds(
      (__attribute__((address_space(1))) void*)g,
      (__attribute__((address_space(3))) void*)l, 16, 0, 0);
}

// aux pointer bundle for fused A-staging modes
struct AuxP {
  const float* p0;
  const float* p1;
  const float* p2;
  const float* p3;
  const float* p4;
};

// ---------------------------------------------------------------------------
// Merged AB + C GEMM (one dispatch per layer; both are copy-mode K=128 NT=8).
//  bid < 1024 : AB role. A = hbf [N,128]; W = preABT tower z rows [bn..bn+128);
//               out fp16 AB[z][N][256], no bias. (z=bid>>8, y=(bid>>7)&1)
//  bid >= 1024: C role.  A = eaf [E,128] (CSR order); W = foldT tower z;
//               out fp16 Mb[z][E][128], bias = bfold. (z=idx>>9, xm=idx&511)
// r1 sync structure: double-buffered LDS, gll stage tile k+1 before MFMA on
// tile k, one __syncthreads per step. LDS 32 KB -> 5 blocks/CU.
// ---------------------------------------------------------------------------
__global__ __launch_bounds__(256) void abc_gemm(
    const unsigned short* __restrict__ hbf, const unsigned short* __restrict__ preABT_l,
    unsigned short* __restrict__ AB,
    const unsigned short* __restrict__ eaf, const unsigned short* __restrict__ foldT_l,
    const float* __restrict__ bfold_l, unsigned short* __restrict__ Mb)
{
  __shared__ __align__(16) unsigned short AhS[2 * 4096];
  __shared__ __align__(16) unsigned short BhS[2 * 4096];

  const int bid = blockIdx.x;
  const unsigned short* Abase;
  const unsigned short* Wbase;
  const float* bias = nullptr;
  unsigned short* Cu;
  int ldc, bn;
  long long bm;
  if (bid < 1024) {
    const int z = bid >> 8, y = (bid >> 7) & 1, xm = bid & 127;
    Abase = hbf;
    Wbase = preABT_l + (size_t)z * 256 * 128;
    Cu = AB + (size_t)z * NN * 256;
    ldc = 256; bn = y * 128; bm = (long long)xm * 128;
  } else {
    const int idx = bid - 1024;
    const int z = idx >> 9, xm = idx & 511;
    Abase = eaf;
    Wbase = foldT_l + (size_t)z * 128 * 128;
    bias = bfold_l + z * 128;
    Cu = Mb + (size_t)z * EE * 128;
    ldc = 128; bn = 0; bm = (long long)xm * 128;
  }

  const int tid = threadIdx.x;
  const int w = tid >> 6;
  const int lane = tid & 63;
  const int quad = lane >> 4;
  const int c16 = lane & 15;
  const int srow = lane >> 2;
  const int sslot = (lane & 3) << 3;

  f4 acc[2][8];
#pragma unroll
  for (int mt = 0; mt < 2; ++mt)
#pragma unroll
    for (int nt = 0; nt < 8; ++nt) acc[mt][nt] = (f4){0.f, 0.f, 0.f, 0.f};

  const unsigned short* whp = Wbase + (long long)(bn + srow) * 128 + sslot;
  const unsigned short* ahp = Abase + (bm + srow) * 128 + sslot;
  const int swr8 = ((quad ^ ((c16 >> 1) & 3)) << 3);

  auto stage = [&](int bi, int k0) {
#pragma unroll
    for (int ch = w; ch < 8; ch += 4) {
      gll16(ahp + (long long)ch * 16 * 128 + k0, AhS + bi * 4096 + ch * 512);
      gll16(whp + (long long)ch * 16 * 128 + k0, BhS + bi * 4096 + ch * 512);
    }
  };
  auto fragmfma = [&](int bi) {
    hfrag ah[2];
#pragma unroll
    for (int mt = 0; mt < 2; ++mt)
      ah[mt] = *(const hfrag*)&AhS[bi * 4096 + (w * 32 + mt * 16 + c16) * 32 + swr8];
#pragma unroll
    for (int nt = 0; nt < 8; ++nt) {
      hfrag bh = *(const hfrag*)&BhS[bi * 4096 + (nt * 16 + c16) * 32 + swr8];
#pragma unroll
      for (int mt = 0; mt < 2; ++mt)
        acc[mt][nt] = __builtin_amdgcn_mfma_f32_16x16x32_f16(ah[mt], bh, acc[mt][nt], 0, 0, 0);
    }
  };

  stage(0, 0);
  __syncthreads();
#pragma unroll
  for (int kt = 0; kt < 4; ++kt) {
    const int bi = kt & 1;
    if (kt < 3) stage(bi ^ 1, (kt + 1) << 5);
    fragmfma(bi);
    __syncthreads();
  }

  // epilogue: C/D layout col=lane&15, row=quad*4+reg; fp16 store
#pragma unroll
  for (int nt = 0; nt < 8; ++nt) {
    const int col = bn + nt * 16 + c16;
    const float bv = bias ? bias[nt * 16 + c16] : 0.f;
#pragma unroll
    for (int mt = 0; mt < 2; ++mt) {
#pragma unroll
      for (int r = 0; r < 4; ++r) {
        long long row = bm + w * 32 + mt * 16 + quad * 4 + r;
        Cu[row * ldc + col] = f2h(acc[mt][nt][r] + bv);
      }
    }
  }
}

// ---------------------------------------------------------------------------
// fp16 MFMA GEMM (templated modes): C[M,Nc] = A[M,K] @ W[K,Nc], fp32 acc.
// A-staging modes (ASRC):
//   1: fp16 ushort input (pre-swizzled), gll copy       [P gemm]
//   3: lin-fused: K=256 two-phase. k<128: A = P_id + s*P_amp + invs*P_att +
//      bpost (ds-write; p0=P fp16, p2=s, p3=invs, p4=bpost). k>=128: A = hbf
//      (Av, gll copy) vs folded Wx@Wlin half of B. Epilogue accumulates BN
//      column stats into p1 (colsum|colsq).
//   4: fp32 / rowcount (p0=cntf) -- global mean pool divide (ds-write)
// OHALF: epilogue stores fp16. NT = column fragments. r1 sync structure.
// ---------------------------------------------------------------------------
template <int ASRC, int NT, bool BIAS, bool RELU, bool OHALF>
__global__ __launch_bounds__(256) void mgemm(
    const void* __restrict__ Av, const unsigned short* __restrict__ WT,
    const float* __restrict__ bias,
    float* __restrict__ C, AuxP aux,
    int Nc, int K, int lda, int ldc,
    long long bsA, long long bsW, long long bsC, int bsBias)
{
  constexpr bool COPYA = (ASRC == 1);
  constexpr int BST = NT * 16 * 32; // ushorts per B buffer

  const int z = blockIdx.z;
  WT += (long long)z * bsW;
  if (BIAS) bias += (long long)z * bsBias;
  float* Cf = C + (OHALF ? 0 : (long long)z * bsC);
  unsigned short* Cu = (unsigned short*)C + (OHALF ? (long long)z * bsC : 0);

  __shared__ __align__(16) unsigned short AhS[2 * 128 * 32];
  __shared__ __align__(16) unsigned short BhS[2 * BST];

  const int tid = threadIdx.x;
  const long long bm = (long long)blockIdx.x * 128;
  const int bn = blockIdx.y * (NT * 16);
  const int w = tid >> 6;
  const int lane = tid & 63;
  const int quad = lane >> 4;
  const int c16 = lane & 15;
  const int srow = lane >> 2;        // staging row within 16-row chunk
  const int sslot = (lane & 3) << 3; // staging slot (ushort offset)

  // ds-write-mode indices: each thread produces 16 A elements of one row-half
  const int arow = tid >> 1;
  const int sel = tid & 1;
  const long long rowsrc = bm + arow;

  f4 acc[2][NT];
#pragma unroll
  for (int mt = 0; mt < 2; ++mt)
#pragma unroll
    for (int nt = 0; nt < NT; ++nt) acc[mt][nt] = (f4){0.f, 0.f, 0.f, 0.f};

  // lane-invariant staging bases
  const unsigned short* whp = WT + (long long)(bn + srow) * K + sslot;

  const unsigned short* ahp = nullptr;
  if (COPYA || ASRC == 3)
    ahp = (const unsigned short*)Av + (long long)z * bsA + (bm + srow) * (long long)lda + sslot;

  // ds-write-mode A state (ASRC 3 / 4)
  float invdc = 1.f;
  float sv = 0.f, iv = 0.f;
  const float* apA = nullptr;
  const unsigned short* Prow_base = nullptr;
  if (ASRC == 3) {
    Prow_base = (const unsigned short*)aux.p0 + rowsrc * 384;
    sv = aux.p2[rowsrc];
    iv = aux.p3[rowsrc];
  } else if (ASRC == 4) {
    apA = (const float*)Av + (long long)z * bsA + rowsrc * lda;
    invdc = 1.f / fmaxf(aux.p0[rowsrc], 1.f);
  }
  // swizzled LDS write offsets for ds-write-mode A
  const int swa = (arow >> 1) & 3;
  const int s0us = arow * 32 + (((2 * sel) ^ swa) << 3);
  const int s1us = arow * 32 + (((2 * sel + 1) ^ swa) << 3);

  // fragment-read swizzle: slot quad ^ ((row>>1)&3); row bits 1..2 == c16 bits
  const int swr8 = ((quad ^ ((c16 >> 1) & 3)) << 3);

  auto stageB = [&](int bi, int k0) {
#pragma unroll
    for (int ch = w; ch < NT; ch += 4)
      gll16(whp + (long long)ch * 16 * K + k0, BhS + bi * BST + ch * 512);
  };
  auto stageA = [&](int bi, int k0) { // gll copy of A rows (k0 relative to lda)
#pragma unroll
    for (int ch = w; ch < 8; ch += 4)
      gll16(ahp + (long long)ch * 16 * lda + k0, AhS + bi * 4096 + ch * 512);
  };
  auto stageLoad = [&](int k0, float* va) {
    const int ck0 = k0 + sel * 16;
    if (ASRC == 3) {
      const unsigned short* Prow = Prow_base + ((ck0 >> 5) * 96) + (ck0 & 31);
      float4 pid0 = ld4hf(Prow), pid1 = ld4hf(Prow + 4);
      float4 pid2 = ld4hf(Prow + 8), pid3 = ld4hf(Prow + 12);
      float4 pam0 = ld4hf(Prow + 32), pam1 = ld4hf(Prow + 36);
      float4 pam2 = ld4hf(Prow + 40), pam3 = ld4hf(Prow + 44);
      float4 pat0 = ld4hf(Prow + 64), pat1 = ld4hf(Prow + 68);
      float4 pat2 = ld4hf(Prow + 72), pat3 = ld4hf(Prow + 76);
      float pid[16] = {pid0.x, pid0.y, pid0.z, pid0.w, pid1.x, pid1.y, pid1.z, pid1.w,
                       pid2.x, pid2.y, pid2.z, pid2.w, pid3.x, pid3.y, pid3.z, pid3.w};
      float pam[16] = {pam0.x, pam0.y, pam0.z, pam0.w, pam1.x, pam1.y, pam1.z, pam1.w,
                       pam2.x, pam2.y, pam2.z, pam2.w, pam3.x, pam3.y, pam3.z, pam3.w};
      float pat[16] = {pat0.x, pat0.y, pat0.z, pat0.w, pat1.x, pat1.y, pat1.z, pat1.w,
                       pat2.x, pat2.y, pat2.z, pat2.w, pat3.x, pat3.y, pat3.z, pat3.w};
#pragma unroll
      for (int i = 0; i < 16; ++i)
        va[i] = pid[i] + sv * pam[i] + iv * pat[i] + aux.p4[ck0 + i];
    } else {
      *(float4*)&va[0] = *(const float4*)(apA + ck0);
      *(float4*)&va[4] = *(const float4*)(apA + ck0 + 4);
      *(float4*)&va[8] = *(const float4*)(apA + ck0 + 8);
      *(float4*)&va[12] = *(const float4*)(apA + ck0 + 12);
    }
  };
  auto stageWrite = [&](int bi, const float* va) {
    hfrag hv0, hv1;
#pragma unroll
    for (int i = 0; i < 16; ++i) {
      float x = va[i];
      if (ASRC == 4) x *= invdc;
      if (i < 8) hv0[i] = (_Float16)x;
      else       hv1[i - 8] = (_Float16)x;
    }
    *(hfrag*)&AhS[bi * 4096 + s0us] = hv0;
    *(hfrag*)&AhS[bi * 4096 + s1us] = hv1;
  };
  auto fragmfma = [&](int bi) {
    hfrag ah[2];
#pragma unroll
    for (int mt = 0; mt < 2; ++mt) {
      const int r = w * 32 + mt * 16 + c16;
      ah[mt] = *(const hfrag*)&AhS[bi * 4096 + r * 32 + swr8];
    }
#pragma unroll
    for (int nt = 0; nt < NT; ++nt) {
      const int r = nt * 16 + c16;
      hfrag bh = *(const hfrag*)&BhS[bi * BST + r * 32 + swr8];
#pragma unroll
      for (int mt = 0; mt < 2; ++mt)
        acc[mt][nt] = __builtin_amdgcn_mfma_f32_16x16x32_f16(ah[mt], bh, acc[mt][nt], 0, 0, 0);
    }
  };

  float va[16];
  const int nk = K >> 5;

  // prologue: fill buffer 0 (ASRC3's tile 0 is ds-mode)
  if (COPYA) {
    stageA(0, 0);
    stageB(0, 0);
  } else {
    stageLoad(0, va);
    stageB(0, 0);
    stageWrite(0, va);
  }
  __syncthreads();

  for (int kt = 0; kt < nk; ++kt) {
    const int bi = kt & 1;
    const bool pf = (kt + 1 < nk);
    bool nextds = false;
    if (pf) {
      const int k0 = (kt + 1) << 5;
      stageB(bi ^ 1, k0);
      if (COPYA) {
        stageA(bi ^ 1, k0);
      } else if (ASRC == 3 && k0 >= 128) {
        stageA(bi ^ 1, k0 - 128); // copy phase: A = hbf (x-through path)
      } else {
        stageLoad(k0, va);
        nextds = true;
      }
    }
    fragmfma(bi);
    if (nextds) stageWrite(bi ^ 1, va);
    __syncthreads();
  }

  // epilogue: C/D layout col=lane&15, row=quad*4+reg
  float ls[NT], lq[NT];
#pragma unroll
  for (int nt = 0; nt < NT; ++nt) { ls[nt] = 0.f; lq[nt] = 0.f; }
#pragma unroll
  for (int nt = 0; nt < NT; ++nt) {
    int col = bn + nt * 16 + c16;
    if (col >= Nc) continue;
    float bv = BIAS ? bias[col] : 0.f;
#pragma unroll
    for (int mt = 0; mt < 2; ++mt) {
#pragma unroll
      for (int r = 0; r < 4; ++r) {
        long long row = bm + w * 32 + mt * 16 + quad * 4 + r;
        float v = acc[mt][nt][r] + bv;
        if (RELU) v = fmaxf(v, 0.f);
        if (ASRC == 3) { ls[nt] += v; lq[nt] += v * v; }
        if (OHALF) Cu[row * ldc + col] = f2h(v);
        else Cf[row * ldc + col] = v;
      }
    }
  }
  if constexpr (ASRC == 3) {
    // fused BN column partial stats: LDS reduce + one global atomic per col
    float* csum = (float*)AhS;  // reuse LDS (all waves past final barrier)
    float* csq = csum + 128;
    if (tid < 128) { csum[tid] = 0.f; csq[tid] = 0.f; }
    __syncthreads();
#pragma unroll
    for (int nt = 0; nt < NT; ++nt) {
      int col = bn + nt * 16 + c16;
      atomicAdd(&csum[col], ls[nt]);
      atomicAdd(&csq[col], lq[nt]);
    }
    __syncthreads();
    float* colsum = (float*)aux.p1;
    if (tid < 128) {
      atomicAdd(&colsum[tid], csum[tid]);
      atomicAdd(&colsum[128 + tid], csq[tid]);
    }
  }
}

// ---------------------------------------------------------------------------
// edge encoder: fp16 DIRECTLY in CSR slot order, PRE-SWIZZLED; 2 edges/block
// ---------------------------------------------------------------------------
__global__ __launch_bounds__(256) void edge_enc(
    const float* __restrict__ eat, const float* __restrict__ We,
    const float* __restrict__ be, const int* __restrict__ slot_of,
    unsigned short* __restrict__ ef)
{
  int e = blockIdx.x * 2 + (threadIdx.x >> 7);
  int c = threadIdx.x & 127;
  float acc = be[c];
#pragma unroll
  for (int k = 0; k < 4; ++k) acc += eat[e * 4 + k] * We[k * 128 + c];
  long long slot = slot_of[e];
  ef[slot * 128 + swk((int)slot, c)] = f2h(fmaxf(acc, 0.f));
}

// ---------------------------------------------------------------------------
// CSR build: count -> scan (also inits cursor + s/invs) -> scatter
// ---------------------------------------------------------------------------
__global__ void count_deg(const int* __restrict__ dst, int* __restrict__ degi)
{
  int e = blockIdx.x * 256 + threadIdx.x;
  if (e < EE) atomicAdd(&degi[dst[e]], 1);
}

__global__ __launch_bounds__(1024) void scan_k(const int* __restrict__ degi,
                                               int* __restrict__ row_off,
                                               int* __restrict__ cursor,
                                               float* __restrict__ s_arr,
                                               float* __restrict__ invs)
{
  __shared__ int tsum[1024];
  int t = threadIdx.x;
  int local[16];
  int base = t * 16;
  int s = 0;
#pragma unroll
  for (int i = 0; i < 16; ++i) { local[i] = s; s += degi[base + i]; }
  tsum[t] = s;
  __syncthreads();
  for (int off = 1; off < 1024; off <<= 1) {
    int v = (t >= off) ? tsum[t - off] : 0;
    __syncthreads();
    tsum[t] += v;
    __syncthreads();
  }
  int prev = (t == 0) ? 0 : tsum[t - 1];
#pragma unroll
  for (int i = 0; i < 16; ++i) {
    int start = prev + local[i];
    row_off[base + i] = start;
    cursor[base + i] = start;
    int cnt = degi[base + i];
    float degc = fmaxf((float)cnt, 1.f);
    float sv = logf(degc + 1.f) / AVG_LOG_F;
    s_arr[base + i] = sv;
    invs[base + i] = 1.f / sv;
  }
  if (t == 1023) row_off[NN] = tsum[1023];
}

__global__ void scatter_k(const int* __restrict__ src, const int* __restrict__ dst,
                          int* __restrict__ cursor,
                          int* __restrict__ slot_of, int* __restrict__ esrc)
{
  int e = blockIdx.x * 256 + threadIdx.x;
  if (e >= EE) return;
  int d = dst[e];
  int slot = atomicAdd(&cursor[d], 1);
  slot_of[e] = slot;
  esrc[slot] = src[e];
}

// ---------------------------------------------------------------------------
// Weight folds (fp32)
// ---------------------------------------------------------------------------
__global__ __launch_bounds__(512) void fold_w(const float* __restrict__ We_conv,
                                              const float* __restrict__ Wpre,
                                              float* __restrict__ Wfold)
{
  int k = blockIdx.x & 127, l = blockIdx.x >> 7;
  int t = threadIdx.x >> 7, f = threadIdx.x & 127;
  const float* wc = We_conv + (long long)(l * 128 + k) * 128;
  const float* wp = Wpre + ((long long)((l * 4 + t) * 384 + 256)) * 128 + f;
  float acc = 0.f;
  for (int j = 0; j < 128; ++j) acc += wc[j] * wp[(long long)j * 128];
  Wfold[((long long)(l * 128 + k)) * 512 + threadIdx.x] = acc;
}

__global__ __launch_bounds__(512) void fold_b(const float* __restrict__ be_conv,
                                              const float* __restrict__ Wpre,
                                              const float* __restrict__ bpre,
                                              float* __restrict__ bfold)
{
  int l = blockIdx.x;
  int t = threadIdx.x >> 7, f = threadIdx.x & 127;
  const float* bc = be_conv + l * 128;
  const float* wp = Wpre + ((long long)((l * 4 + t) * 384 + 256)) * 128 + f;
  float acc = bpre[(l * 4 + t) * 128 + f];
  for (int j = 0; j < 128; ++j) acc += bc[j] * wp[(long long)j * 128];
  bfold[l * 512 + threadIdx.x] = acc;
}

// ---------------------------------------------------------------------------
// pack_all: ALL fp32 -> fp16 swizzled packers + node encoder in ONE launch.
// Segments by blockIdx (128 threads each):
//  [0,3072)      preABT[lt][n(256)][k(128)]
//  [3072,4608)   foldT[lt][n(128)][k(128)]   (reads WfoldF, after fold_w)
//  [4608,6144)   post3T[lt][c(128)][r(512)]  (4 r per thread)
//  [6144,6528)   linT2 lo-half: Wlin transpose [l][n][k<128]
//  [6528,6912)   linT2 hi-half: Wxl[l][o][128+kk] = sum_c Wx[kk][c]*Wlin[c][o]
//  [6912,6976)   w1T[n(64)][k(128)]
//  [6976,23360)  node_enc: hbf[n] = fp16(relu(x@Wa+ba)) swizzled
// ---------------------------------------------------------------------------
__global__ __launch_bounds__(128) void pack_all(
    const float* __restrict__ Wpre, const float* __restrict__ WfoldF,
    const float* __restrict__ Wpost, const float* __restrict__ Wlin,
    const float* __restrict__ W1,
    const float* __restrict__ x, const float* __restrict__ Wa,
    const float* __restrict__ ba,
    unsigned short* __restrict__ preABT, unsigned short* __restrict__ foldT,
    unsigned short* __restrict__ post3T, unsigned short* __restrict__ linT2,
    unsigned short* __restrict__ w1T, unsigned short* __restrict__ hbf)
{
  const int b = blockIdx.x;
  const int t = threadIdx.x;
  if (b < 3072) {                       // preABT
    int lt = b >> 8, n = b & 255, k = t;
    int row = (n < 128) ? k : (128 + k);
    int f = n & 127;
    float v = Wpre[((long long)(lt * 384 + row)) * 128 + f];
    preABT[((long long)(lt * 256 + n)) * 128 + swk(n, k)] = f2h(v);
  } else if (b < 4608) {                // foldT
    int b2 = b - 3072;
    int lt = b2 >> 7, n = b2 & 127, k = t;
    int l = lt >> 2, tw = lt & 3;
    float v = WfoldF[((long long)(l * 128 + k)) * 512 + tw * 128 + n];
    foldT[((long long)(lt * 128 + n)) * 128 + swk(n, k)] = f2h(v);
  } else if (b < 6144) {                // post3T
    int b3 = b - 4608;
    int lt = b3 >> 7, c = b3 & 127;
#pragma unroll
    for (int j = 0; j < 4; ++j) {
      int r = t + 128 * j;
      float v = 0.f;
      if (c < 96)
        v = Wpost[((long long)(lt * 1664 + 128 + (c >> 5) * 512 + r)) * 32 + (c & 31)];
      post3T[((long long)(lt * 128 + c)) * 512 + swk(c, r)] = f2h(v);
    }
  } else if (b < 6528) {                // linT2 low half: Wlin^T
    int b4 = b - 6144;
    int l = b4 >> 7, n = b4 & 127, k = t;
    float v = Wlin[((long long)(l * 128 + k)) * 128 + n];
    linT2[((long long)(l * 128 + n)) * 256 + swk(n, k)] = f2h(v);
  } else if (b < 6912) {                // linT2 high half: Wxl fold
    int b5 = b - 6528;
    int l = b5 >> 7, kk = b5 & 127, o = t;
    float acc = 0.f;
    for (int c = 0; c < 128; ++c) {
      float wx = Wpost[((long long)((l * 4 + (c >> 5)) * 1664 + kk)) * 32 + (c & 31)];
      acc += wx * Wlin[((long long)(l * 128 + c)) * 128 + o];
    }
    linT2[((long long)(l * 128 + o)) * 256 + swk(o, 128 + kk)] = f2h(acc);
  } else if (b < 6976) {                // w1T
    int n = b - 6912, k = t;
    w1T[(long long)n * 128 + swk(n, k)] = f2h(W1[k * 64 + n]);
  } else {                              // node_enc
    int n = b - 6976, c = t;
    float acc = ba[c];
#pragma unroll
    for (int k = 0; k < 11; ++k) acc += x[n * 11 + k] * Wa[k * 128 + c];
    hbf[((long long)n << 7) + swk(n, c)] = f2h(fmaxf(acc, 0.f));
  }
}

// ---------------------------------------------------------------------------
// Per-tower aggregation, ALL FOUR towers in one block.
// Block 256 = 2 nodes x 4 towers x 32 lanes(x4 ch). Edges processed in
// chunks of 4: esrc batch-loaded first, then 8 independent loads in flight
// (breaks the esrc->ABs dependent-latency chain). AB and Mb slabs fp16.
// Output aggs fp16 [N][512], PRE-SWIZZLED (swk) for gll staging by the P gemm.
// ---------------------------------------------------------------------------
__global__ __launch_bounds__(256) void aggregate_ct(
    const unsigned short* __restrict__ ABb, const unsigned short* __restrict__ Mb,
    const int* __restrict__ row_off, const int* __restrict__ esrc,
    unsigned short* __restrict__ aggs)
{
  const int tid = threadIdx.x;
  const int c4 = (tid & 31) << 2;
  const int z = (tid >> 5) & 3;
  const int n = blockIdx.x * 2 + (tid >> 7);
  const unsigned short* M = Mb + (long long)z * EE * 128;
  const unsigned short* ABs = ABb + (long long)z * NN * 256;
  unsigned short* ag = aggs + (long long)z * NN * 512;
  const int beg = row_off[n], end = row_off[n + 1];
  const int cnt = end - beg;
  const float degc = fmaxf((float)cnt, 1.0f);
  const float4 aval = ld4hf(&ABs[(long long)n * 256 + c4]);

  float sum[4] = {0.f, 0.f, 0.f, 0.f}, sq[4] = {0.f, 0.f, 0.f, 0.f};
  float mn[4] = {INFINITY, INFINITY, INFINITY, INFINITY};
  float mx[4] = {-INFINITY, -INFINITY, -INFINITY, -INFINITY};

  auto upd = [&](const float4& mv, const float4& bv) {
    float m0 = aval.x + bv.x + mv.x;
    float m1 = aval.y + bv.y + mv.y;
    float m2 = aval.z + bv.z + mv.z;
    float m3 = aval.w + bv.w + mv.w;
    sum[0] += m0; sq[0] += m0 * m0; mn[0] = fminf(mn[0], m0); mx[0] = fmaxf(mx[0], m0);
    sum[1] += m1; sq[1] += m1 * m1; mn[1] = fminf(mn[1], m1); mx[1] = fmaxf(mx[1], m1);
    sum[2] += m2; sq[2] += m2 * m2; mn[2] = fminf(mn[2], m2); mx[2] = fmaxf(mx[2], m2);
    sum[3] += m3; sq[3] += m3 * m3; mn[3] = fminf(mn[3], m3); mx[3] = fmaxf(mx[3], m3);
  };

  for (int s0 = beg; s0 < end; s0 += 4) {
    const int e1 = min(s0 + 1, end - 1);
    const int e2 = min(s0 + 2, end - 1);
    const int e3 = min(s0 + 3, end - 1);
    const int sA = esrc[s0], sB = esrc[e1], sC = esrc[e2], sD = esrc[e3];
    const float4 mA = ld4hf(&M[(long long)s0 * 128 + c4]);
    const float4 mB = ld4hf(&M[(long long)e1 * 128 + c4]);
    const float4 mC = ld4hf(&M[(long long)e2 * 128 + c4]);
    const float4 mD = ld4hf(&M[(long long)e3 * 128 + c4]);
    const float4 bA = ld4hf(&ABs[(long long)sA * 256 + 128 + c4]);
    const float4 bB = ld4hf(&ABs[(long long)sB * 256 + 128 + c4]);
    const float4 bC = ld4hf(&ABs[(long long)sC * 256 + 128 + c4]);
    const float4 bD = ld4hf(&ABs[(long long)sD * 256 + 128 + c4]);
    upd(mA, bA);
    if (s0 + 1 < end) upd(mB, bB);
    if (s0 + 2 < end) upd(mC, bC);
    if (s0 + 3 < end) upd(mD, bD);
  }

  const float inv = 1.0f / degc;
  float mean[4], stdv[4];
#pragma unroll
  for (int j = 0; j < 4; ++j) {
    mean[j] = sum[j] * inv;
    float var = sq[j] * inv - mean[j] * mean[j];
    stdv[j] = sqrtf(fmaxf(var, 0.f) + 1e-5f);
    if (cnt == 0) { mn[j] = 0.f; mx[j] = 0.f; }
  }
  const int sc = swk(n, c4);
  const long long base = (long long)n * 512 + sc;
  ushort4 o;
  o.x = f2h(mean[0]); o.y = f2h(mean[1]); o.z = f2h(mean[2]); o.w = f2h(mean[3]);
  *(ushort4*)&ag[base] = o;
  o.x = f2h(mn[0]); o.y = f2h(mn[1]); o.z = f2h(mn[2]); o.w = f2h(mn[3]);
  *(ushort4*)&ag[base + 128] = o;
  o.x = f2h(mx[0]); o.y = f2h(mx[1]); o.z = f2h(mx[2]); o.w = f2h(mx[3]);
  *(ushort4*)&ag[base + 256] = o;
  o.x = f2h(stdv[0]); o.y = f2h(stdv[1]); o.z = f2h(stdv[2]); o.w = f2h(stdv[3]);
  *(ushort4*)&ag[base + 384] = o;
}

// ---------------------------------------------------------------------------
// BN apply (coef computed inline from colstats -- bn_coef kernel deleted)
// hb = fp16(relu(hn*scale + shift)) pre-swizzled; hn is fp16
// ---------------------------------------------------------------------------
__global__ __launch_bounds__(256) void bn_apply(const unsigned short* __restrict__ hn,
                                                const float* __restrict__ cs,
                                                const float* __restrict__ g,
                                                const float* __restrict__ b,
                                                unsigned short* __restrict__ hb)
{
  int idx = blockIdx.x * 256 + threadIdx.x; // n*128+c
  int c = idx & 127, n = idx >> 7;
  float mean = cs[c] * (1.f / 16384.f);
  float var = cs[128 + c] * (1.f / 16384.f) - mean * mean;
  float sc = g[c] * rsqrtf(var + 1e-5f);
  float v = fmaxf(h2f(hn[idx]) * sc + (b[c] - mean * sc), 0.f);
  hb[((long long)n << 7) + swk(n, c)] = f2h(v);
}

// ---------------------------------------------------------------------------
// Global mean pool (BN+ReLU fused) + head
// ---------------------------------------------------------------------------
__global__ void pool_add(const unsigned short* __restrict__ y, const float* __restrict__ cs,
                         const float* __restrict__ g, const float* __restrict__ b,
                         const int* __restrict__ batch,
                         float* __restrict__ pooled, float* __restrict__ cntf)
{
  int n = blockIdx.x, c = threadIdx.x;
  float mean = cs[c] * (1.f / 16384.f);
  float var = cs[128 + c] * (1.f / 16384.f) - mean * mean;
  float v = fmaxf((h2f(y[(long long)n * 128 + c]) - mean) * rsqrtf(var + 1e-5f) * g[c] + b[c], 0.f);
  int bb = batch[n];
  atomicAdd(&pooled[(long long)bb * 128 + c], v);
  if (c == 0) atomicAdd(&cntf[bb], 1.f);
}

__global__ __launch_bounds__(256) void zstats(const float* __restrict__ z,
                                              float* __restrict__ zm, float* __restrict__ zv)
{
  int j = blockIdx.x; // 64 cols
  float s = 0.f, q = 0.f;
  for (int g = threadIdx.x; g < GG; g += 256) {
    float v = z[g * 64 + j];
    s += v;
    q += v * v;
  }
  __shared__ float ps[256], pq[256];
  ps[threadIdx.x] = s;
  pq[threadIdx.x] = q;
  __syncthreads();
  for (int st = 128; st > 0; st >>= 1) {
    if (threadIdx.x < st) {
      ps[threadIdx.x] += ps[threadIdx.x + st];
      pq[threadIdx.x] += pq[threadIdx.x + st];
    }
    __syncthreads();
  }
  if (threadIdx.x == 0) {
    float m = ps[0] / (float)GG;
    zm[j] = m;
    zv[j] = pq[0] / (float)GG - m * m;
  }
}

__global__ void final_out(const float* __restrict__ z, const float* __restrict__ zm,
                          const float* __restrict__ zv, const float* __restrict__ hg,
                          const float* __restrict__ hb, const float* __restrict__ W2,
                          const float* __restrict__ b2, float* __restrict__ out)
{
  int g = blockIdx.x;
  int j = threadIdx.x; // 64 = one wave
  float v = (z[g * 64 + j] - zm[j]) * rsqrtf(zv[j] + 1e-5f) * hg[j] + hb[j];
  float t = v * W2[j];
#pragma unroll
  for (int off = 32; off > 0; off >>= 1) t += __shfl_down(t, off);
  if (j == 0) out[g] = t + b2[0];
}

// ---------------------------------------------------------------------------
extern "C" void kernel_launch(void* const* d_in, const int* in_sizes, int n_in,
                              void* d_out, int out_size, void* d_ws, size_t ws_size,
                              hipStream_t stream)
{
  (void)in_sizes; (void)n_in; (void)out_size;
  const float* x = (const float*)d_in[0];
  const float* eat = (const float*)d_in[1];
  const int* ei = (const int*)d_in[2];
  const int* batch = (const int*)d_in[3];
  const float* Wa = (const float*)d_in[4];
  const float* ba = (const float*)d_in[5];
  const float* We = (const float*)d_in[6];
  const float* be = (const float*)d_in[7];
  const float* We_conv = (const float*)d_in[8];
  const float* be_conv = (const float*)d_in[9];
  const float* Wpre = (const float*)d_in[10];
  const float* bpre = (const float*)d_in[11];
  const float* Wpost = (const float*)d_in[12];
  const float* bpost = (const float*)d_in[13];
  const float* Wlin = (const float*)d_in[14];
  const float* blin = (const float*)d_in[15];
  const float* bng = (const float*)d_in[16];
  const float* bnb = (const float*)d_in[17];
  const float* W1 = (const float*)d_in[18];
  const float* b1 = (const float*)d_in[19];
  const float* hg = (const float*)d_in[20];
  const float* hb = (const float*)d_in[21];
  const float* W2 = (const float*)d_in[22];
  const float* b2 = (const float*)d_in[23];
  float* out = (float*)d_out;

  const int* srcI = ei;
  const int* dstI = ei + EE;

  char* ws = (char*)d_ws;
  size_t off = 0;
  auto alloc = [&](size_t bytes) -> char* {
    char* p = ws + off;
    off += (bytes + 255) & ~(size_t)255;
    return p;
  };

  unsigned short* hbf = (unsigned short*)alloc((size_t)NN * 128 * 2); // fp16 h
  unsigned short* hn = (unsigned short*)alloc((size_t)NN * 128 * 2);  // fp16 hn
  unsigned short* eaf = (unsigned short*)alloc((size_t)EE * 128 * 2); // fp16 ea, CSR order
  unsigned short* AB = (unsigned short*)alloc((size_t)4 * NN * 256 * 2); // fp16 [T][N][256]
  char* Mregion = alloc((size_t)4 * EE * 128 * 2);           // Mb fp16 [4][E][128]; later P fp16
  unsigned short* Mb = (unsigned short*)Mregion;
  unsigned short* P = (unsigned short*)Mregion;               // fp16 [N][384]
  unsigned short* aggt = (unsigned short*)alloc((size_t)4 * NN * 512 * 2); // fp16 [T][N][512]
  float* s_arr = (float*)alloc((size_t)NN * 4);
  float* invs = (float*)alloc((size_t)NN * 4);
  int* degi = (int*)alloc((size_t)NN * 4);
  int* cursor = (int*)alloc((size_t)NN * 4);
  int* row_off = (int*)alloc((size_t)(NN + 1) * 4);
  int* slot_of = (int*)alloc((size_t)EE * 4);
  int* esrc = (int*)alloc((size_t)EE * 4);
  float* WfoldF = (float*)alloc((size_t)3 * 128 * 512 * 4);
  float* bfold = (float*)alloc((size_t)3 * 512 * 4);
  unsigned short* preABT = (unsigned short*)alloc((size_t)12 * 256 * 128 * 2);
  unsigned short* foldT = (unsigned short*)alloc((size_t)12 * 128 * 128 * 2);
  unsigned short* post3T = (unsigned short*)alloc((size_t)12 * 128 * 512 * 2);
  unsigned short* linT2 = (unsigned short*)alloc((size_t)3 * 128 * 256 * 2); // [Wlin^T | Wx@Wlin]
  unsigned short* w1T = (unsigned short*)alloc((size_t)64 * 128 * 2);
  float* colstats = (float*)alloc(3 * 256 * 4); // one 256-buffer per layer
  float* pooled = (float*)alloc((size_t)GG * 128 * 4);
  float* cntf = (float*)alloc((size_t)GG * 4);
  float* zbuf = (float*)alloc((size_t)GG * 64 * 4);
  float* zm = (float*)alloc(64 * 4);
  float* zv = (float*)alloc(64 * 4);

  if (off > ws_size) return; // bail rather than corrupt

  // ---- graph structure ----
  hipMemsetAsync(degi, 0, (size_t)NN * 4, stream);
  hipMemsetAsync(colstats, 0, 3 * 256 * 4, stream);
  count_deg<<<EE / 256, 256, 0, stream>>>(dstI, degi);
  scan_k<<<1, 1024, 0, stream>>>(degi, row_off, cursor, s_arr, invs);
  scatter_k<<<EE / 256, 256, 0, stream>>>(srcI, dstI, cursor, slot_of, esrc);

  // ---- encoders + weight folds/packing ----
  edge_enc<<<EE / 2, 256, 0, stream>>>(eat, We, be, slot_of, eaf); // after scatter_k
  fold_w<<<384, 512, 0, stream>>>(We_conv, Wpre, WfoldF);
  fold_b<<<3, 512, 0, stream>>>(be_conv, Wpre, bpre, bfold);
  pack_all<<<6976 + NN, 128, 0, stream>>>(Wpre, WfoldF, Wpost, Wlin, W1, x, Wa, ba,
                                          preABT, foldT, post3T, linT2, w1T, hbf);

  for (int l = 0; l < 3; ++l) {
    float* cs_l = colstats + l * 256;
    // merged AB (z=4, both col-halves) + C (z=4) gemms, one dispatch
    abc_gemm<<<3072, 256, 0, stream>>>(
        hbf, preABT + (size_t)l * 4 * 256 * 128, AB,
        eaf, foldT + (size_t)l * 4 * 128 * 128, bfold + l * 512, Mb);
    // stats over m = (A + B[src]) + C ; all 4 towers per block
    aggregate_ct<<<dim3(NN / 2, 1, 1), 256, 0, stream>>>(AB, Mb, row_off, esrc, aggt);
    // P all towers: fp16 [N,512] @ [512,96] (z=4, exact 96-col tile) -> fp16 P
    mgemm<1, 6, false, false, true><<<dim3(NN / 128, 1, 4), 256, 0, stream>>>(
        aggt, post3T + (size_t)l * 4 * 128 * 512, nullptr, (float*)P, AuxP{},
        96, 512, 512, 384, (long long)NN * 512, (long long)128 * 512, 96, 0);
    // lin (K=256 two-phase: P-combine | hbf x-through vs folded Wx@Wlin),
    // + blin; epilogue fuses BN column stats into cs_l; output fp16 hn
    mgemm<3, 8, true, false, true><<<dim3(NN / 128, 1, 1), 256, 0, stream>>>(
        hbf, linT2 + (size_t)l * 128 * 256, blin + l * 128, (float*)hn,
        AuxP{(const float*)P, cs_l, s_arr, invs, bpost + l * 128},
        128, 256, 128, 128, 0, 0, 0, 0);
    if (l < 2)
      bn_apply<<<NN * 128 / 256, 256, 0, stream>>>(hn, cs_l, bng + l * 128,
                                                   bnb + l * 128, hbf);
  }

  // ---- pooling (BN+ReLU fused) + head ----
  hipMemsetAsync(pooled, 0, (size_t)GG * 128 * 4, stream);
  hipMemsetAsync(cntf, 0, (size_t)GG * 4, stream);
  pool_add<<<NN, 128, 0, stream>>>(hn, colstats + 2 * 256,
                                   bng + 2 * 128, bnb + 2 * 128, batch, pooled, cntf);
  mgemm<4, 4, true, true, false><<<dim3(GG / 128, 1, 1), 256, 0, stream>>>(
      pooled, w1T, b1, zbuf, AuxP{cntf, nullptr, nullptr, nullptr, nullptr},
      64, 128, 128, 64, 0, 0, 0, 0);
  zstats<<<64, 256, 0, stream>>>(zbuf, zm, zv);
  final_out<<<GG, 64, 0, stream>>>(zbuf, zm, zv, hg, hb, W2, b2, out);
}

// Round 11
// 554.105 us; speedup vs baseline: 1.7149x; 1.0287x over previous
//
#include <hip/hip_runtime.h>
#include <hip/hip_bf16.h>

#define DEVFN static __device__ __forceinline__

constexpr int NN = 16384;
constexpr int EE = 65536;
constexpr int GG = 512;
constexpr float AVG_LOG_F = 1.0227308671603782f; // (sum d*log d, d=1..4, hist 1,2,3,4)/10

typedef _Float16 hfrag __attribute__((ext_vector_type(8))); // 8 fp16 = 4 VGPR (MFMA A/B)
typedef __attribute__((ext_vector_type(4))) float f4;       // MFMA C/D
typedef __attribute__((ext_vector_type(8))) unsigned short us8v; // 16B fp16 vector

// fp32 <-> fp16 (RNE, native v_cvt). Measured (r5-r8): bf16 slabs +0.0097
// absmax; fp16 slabs noise-level. All intermediates + GEMM operands fp16.
DEVFN unsigned short f2h(float f) {
  _Float16 h = (_Float16)f;
  unsigned short r; __builtin_memcpy(&r, &h, 2); return r;
}
DEVFN float h2f(unsigned short s) {
  _Float16 h; __builtin_memcpy(&h, &s, 2); return (float)h;
}

// load 4 fp16 -> float4
DEVFN float4 ld4hf(const unsigned short* p) {
  ushort4 u = *(const ushort4*)p;
  float4 r;
  r.x = h2f(u.x); r.y = h2f(u.y); r.z = h2f(u.z); r.w = h2f(u.w);
  return r;
}
// load 8 fp16 (single 16B) -> float[8]
DEVFN void ld8hf(const unsigned short* p, float* o) {
  us8v v = *(const us8v*)p;
#pragma unroll
  for (int i = 0; i < 8; ++i) o[i] = h2f(v[i]);
}

// XOR swizzle for packed fp16 [R][K] operand arrays staged with global_load_lds:
// element (row,k) lives at row*K + swk(row,k). Within each 32-wide K window the
// four 8-element slots are permuted by (row>>1)&3 so a wave's ds_read_b128
// fragment reads become a permutation of a contiguous 1 KB region ->
// bank-conflict-free. global_load_lds copies LINEARLY, so the swizzle is baked
// into the packed global layout (both-sides rule, #21).
DEVFN int swk(int row, int k) {
  return (k & ~31) + ((((k >> 3) & 3) ^ ((row >> 1) & 3)) << 3) + (k & 7);
}

// async global->LDS, 16 B per lane; LDS dest = wave-uniform base + lane*16
DEVFN void gll16(const unsigned short* g, unsigned short* l) {
  __builtin_amdgcn_global_load_lds(
      (__attribute__((address_space(1))) void*)g,
      (__attribute__((address_space(3))) void*)l, 16, 0, 0);
}

// aux pointer bundle for fused A-staging modes
struct AuxP {
  const float* p0;
  const float* p1;
  const float* p2;
  const float* p3;
  const float* p4;
};

// ---------------------------------------------------------------------------
// Merged AB + C GEMM (one dispatch per layer; both are copy-mode K=128 NT=8).
//  bid < 1024 : AB role. A = hbf [N,128]; W = preABT tower z rows [bn..bn+128);
//               out fp16 AB[z][N][256], no bias. (z=bid>>8, y=(bid>>7)&1)
//  bid >= 1024: C role.  A = eaf [E,128] (CSR order); W = foldT tower z;
//               out fp16 Mb[z][E][128], bias = bfold. (z=idx>>9, xm=idx&511)
// r1 sync structure: double-buffered LDS, gll stage tile k+1 before MFMA on
// tile k, one __syncthreads per step. LDS 32 KB -> 5 blocks/CU.
// Epilogue: acc -> LDS repack (staging LDS is free after last barrier) ->
// fully-coalesced 16B global stores (r10 PMC: 2B scalar stores cost +27%
// WRITE_SIZE; this converts ~100 MB of stores to full-line writes).
// ---------------------------------------------------------------------------
__global__ __launch_bounds__(256) void abc_gemm(
    const unsigned short* __restrict__ hbf, const unsigned short* __restrict__ preABT_l,
    unsigned short* __restrict__ AB,
    const unsigned short* __restrict__ eaf, const unsigned short* __restrict__ foldT_l,
    const float* __restrict__ bfold_l, unsigned short* __restrict__ Mb)
{
  __shared__ __align__(16) unsigned short S[16384]; // 32 KB staging; epilogue repack
  unsigned short* AhS = S;
  unsigned short* BhS = S + 8192;

  const int bid = blockIdx.x;
  const unsigned short* Abase;
  const unsigned short* Wbase;
  const float* bias = nullptr;
  unsigned short* Cu;
  int ldc, bn;
  long long bm;
  if (bid < 1024) {
    const int z = bid >> 8, y = (bid >> 7) & 1, xm = bid & 127;
    Abase = hbf;
    Wbase = preABT_l + (size_t)z * 256 * 128;
    Cu = AB + (size_t)z * NN * 256;
    ldc = 256; bn = y * 128; bm = (long long)xm * 128;
  } else {
    const int idx = bid - 1024;
    const int z = idx >> 9, xm = idx & 511;
    Abase = eaf;
    Wbase = foldT_l + (size_t)z * 128 * 128;
    bias = bfold_l + z * 128;
    Cu = Mb + (size_t)z * EE * 128;
    ldc = 128; bn = 0; bm = (long long)xm * 128;
  }

  const int tid = threadIdx.x;
  const int w = tid >> 6;
  const int lane = tid & 63;
  const int quad = lane >> 4;
  const int c16 = lane & 15;
  const int srow = lane >> 2;
  const int sslot = (lane & 3) << 3;

  f4 acc[2][8];
#pragma unroll
  for (int mt = 0; mt < 2; ++mt)
#pragma unroll
    for (int nt = 0; nt < 8; ++nt) acc[mt][nt] = (f4){0.f, 0.f, 0.f, 0.f};

  const unsigned short* whp = Wbase + (long long)(bn + srow) * 128 + sslot;
  const unsigned short* ahp = Abase + (bm + srow) * 128 + sslot;
  const int swr8 = ((quad ^ ((c16 >> 1) & 3)) << 3);

  auto stage = [&](int bi, int k0) {
#pragma unroll
    for (int ch = w; ch < 8; ch += 4) {
      gll16(ahp + (long long)ch * 16 * 128 + k0, AhS + bi * 4096 + ch * 512);
      gll16(whp + (long long)ch * 16 * 128 + k0, BhS + bi * 4096 + ch * 512);
    }
  };
  auto fragmfma = [&](int bi) {
    hfrag ah[2];
#pragma unroll
    for (int mt = 0; mt < 2; ++mt)
      ah[mt] = *(const hfrag*)&AhS[bi * 4096 + (w * 32 + mt * 16 + c16) * 32 + swr8];
#pragma unroll
    for (int nt = 0; nt < 8; ++nt) {
      hfrag bh = *(const hfrag*)&BhS[bi * 4096 + (nt * 16 + c16) * 32 + swr8];
#pragma unroll
      for (int mt = 0; mt < 2; ++mt)
        acc[mt][nt] = __builtin_amdgcn_mfma_f32_16x16x32_f16(ah[mt], bh, acc[mt][nt], 0, 0, 0);
    }
  };

  stage(0, 0);
  __syncthreads();
#pragma unroll
  for (int kt = 0; kt < 4; ++kt) {
    const int bi = kt & 1;
    if (kt < 3) stage(bi ^ 1, (kt + 1) << 5);
    fragmfma(bi);
    __syncthreads();
  }

  // epilogue phase 1: acc -> LDS [row][colLocal] fp16 (staging LDS is free)
#pragma unroll
  for (int nt = 0; nt < 8; ++nt) {
    const int colL = nt * 16 + c16;
    const float bv = bias ? bias[colL] : 0.f;
#pragma unroll
    for (int mt = 0; mt < 2; ++mt) {
#pragma unroll
      for (int r = 0; r < 4; ++r) {
        const int row = w * 32 + mt * 16 + quad * 4 + r;
        S[row * 128 + colL] = f2h(acc[mt][nt][r] + bv);
      }
    }
  }
  __syncthreads();
  // epilogue phase 2: coalesced 16B stores (each wave writes 1 KB runs)
#pragma unroll
  for (int p = 0; p < 8; ++p) {
    const int row = p * 16 + (tid >> 4);
    const int co = (tid & 15) * 8; // ushort offset, 16B chunk
    *(uint4*)&Cu[(bm + row) * ldc + bn + co] = *(const uint4*)&S[row * 128 + co];
  }
}

// ---------------------------------------------------------------------------
// fp16 MFMA GEMM (templated modes): C[M,Nc] = A[M,K] @ W[K,Nc], fp32 acc.
// A-staging modes (ASRC):
//   1: fp16 ushort input (pre-swizzled), gll copy       [P gemm]
//   3: lin-fused: K=256 two-phase. k<128: A = P_id + s*P_amp + invs*P_att +
//      bpost (ds-write; p0=P fp16, p2=s, p3=invs, p4=bpost). k>=128: A = hbf
//      (Av, gll copy) vs folded Wx@Wlin half of B. Epilogue accumulates BN
//      column stats into p1 (colsum|colsq).
//   4: fp32 / rowcount (p0=cntf) -- global mean pool divide (ds-write)
// OHALF: epilogue stores fp16. NT = column fragments. r1 sync structure.
// ---------------------------------------------------------------------------
template <int ASRC, int NT, bool BIAS, bool RELU, bool OHALF>
__global__ __launch_bounds__(256) void mgemm(
    const void* __restrict__ Av, const unsigned short* __restrict__ WT,
    const float* __restrict__ bias,
    float* __restrict__ C, AuxP aux,
    int Nc, int K, int lda, int ldc,
    long long bsA, long long bsW, long long bsC, int bsBias)
{
  constexpr bool COPYA = (ASRC == 1);
  constexpr int BST = NT * 16 * 32; // ushorts per B buffer

  const int z = blockIdx.z;
  WT += (long long)z * bsW;
  if (BIAS) bias += (long long)z * bsBias;
  float* Cf = C + (OHALF ? 0 : (long long)z * bsC);
  unsigned short* Cu = (unsigned short*)C + (OHALF ? (long long)z * bsC : 0);

  __shared__ __align__(16) unsigned short AhS[2 * 128 * 32];
  __shared__ __align__(16) unsigned short BhS[2 * BST];

  const int tid = threadIdx.x;
  const long long bm = (long long)blockIdx.x * 128;
  const int bn = blockIdx.y * (NT * 16);
  const int w = tid >> 6;
  const int lane = tid & 63;
  const int quad = lane >> 4;
  const int c16 = lane & 15;
  const int srow = lane >> 2;        // staging row within 16-row chunk
  const int sslot = (lane & 3) << 3; // staging slot (ushort offset)

  // ds-write-mode indices: each thread produces 16 A elements of one row-half
  const int arow = tid >> 1;
  const int sel = tid & 1;
  const long long rowsrc = bm + arow;

  f4 acc[2][NT];
#pragma unroll
  for (int mt = 0; mt < 2; ++mt)
#pragma unroll
    for (int nt = 0; nt < NT; ++nt) acc[mt][nt] = (f4){0.f, 0.f, 0.f, 0.f};

  // lane-invariant staging bases
  const unsigned short* whp = WT + (long long)(bn + srow) * K + sslot;

  const unsigned short* ahp = nullptr;
  if (COPYA || ASRC == 3)
    ahp = (const unsigned short*)Av + (long long)z * bsA + (bm + srow) * (long long)lda + sslot;

  // ds-write-mode A state (ASRC 3 / 4)
  float invdc = 1.f;
  float sv = 0.f, iv = 0.f;
  const float* apA = nullptr;
  const unsigned short* Prow_base = nullptr;
  if (ASRC == 3) {
    Prow_base = (const unsigned short*)aux.p0 + rowsrc * 384;
    sv = aux.p2[rowsrc];
    iv = aux.p3[rowsrc];
  } else if (ASRC == 4) {
    apA = (const float*)Av + (long long)z * bsA + rowsrc * lda;
    invdc = 1.f / fmaxf(aux.p0[rowsrc], 1.f);
  }
  // swizzled LDS write offsets for ds-write-mode A
  const int swa = (arow >> 1) & 3;
  const int s0us = arow * 32 + (((2 * sel) ^ swa) << 3);
  const int s1us = arow * 32 + (((2 * sel + 1) ^ swa) << 3);

  // fragment-read swizzle: slot quad ^ ((row>>1)&3); row bits 1..2 == c16 bits
  const int swr8 = ((quad ^ ((c16 >> 1) & 3)) << 3);

  auto stageB = [&](int bi, int k0) {
#pragma unroll
    for (int ch = w; ch < NT; ch += 4)
      gll16(whp + (long long)ch * 16 * K + k0, BhS + bi * BST + ch * 512);
  };
  auto stageA = [&](int bi, int k0) { // gll copy of A rows (k0 relative to lda)
#pragma unroll
    for (int ch = w; ch < 8; ch += 4)
      gll16(ahp + (long long)ch * 16 * lda + k0, AhS + bi * 4096 + ch * 512);
  };
  auto stageLoad = [&](int k0, float* va) {
    const int ck0 = k0 + sel * 16;
    if (ASRC == 3) {
      const unsigned short* Prow = Prow_base + ((ck0 >> 5) * 96) + (ck0 & 31);
      float pid[16], pam[16], pat[16];
      ld8hf(Prow, pid); ld8hf(Prow + 8, pid + 8);
      ld8hf(Prow + 32, pam); ld8hf(Prow + 40, pam + 8);
      ld8hf(Prow + 64, pat); ld8hf(Prow + 72, pat + 8);
#pragma unroll
      for (int i = 0; i < 16; ++i)
        va[i] = pid[i] + sv * pam[i] + iv * pat[i] + aux.p4[ck0 + i];
    } else {
      *(float4*)&va[0] = *(const float4*)(apA + ck0);
      *(float4*)&va[4] = *(const float4*)(apA + ck0 + 4);
      *(float4*)&va[8] = *(const float4*)(apA + ck0 + 8);
      *(float4*)&va[12] = *(const float4*)(apA + ck0 + 12);
    }
  };
  auto stageWrite = [&](int bi, const float* va) {
    hfrag hv0, hv1;
#pragma unroll
    for (int i = 0; i < 16; ++i) {
      float x = va[i];
      if (ASRC == 4) x *= invdc;
      if (i < 8) hv0[i] = (_Float16)x;
      else       hv1[i - 8] = (_Float16)x;
    }
    *(hfrag*)&AhS[bi * 4096 + s0us] = hv0;
    *(hfrag*)&AhS[bi * 4096 + s1us] = hv1;
  };
  auto fragmfma = [&](int bi) {
    hfrag ah[2];
#pragma unroll
    for (int mt = 0; mt < 2; ++mt) {
      const int r = w * 32 + mt * 16 + c16;
      ah[mt] = *(const hfrag*)&AhS[bi * 4096 + r * 32 + swr8];
    }
#pragma unroll
    for (int nt = 0; nt < NT; ++nt) {
      const int r = nt * 16 + c16;
      hfrag bh = *(const hfrag*)&BhS[bi * BST + r * 32 + swr8];
#pragma unroll
      for (int mt = 0; mt < 2; ++mt)
        acc[mt][nt] = __builtin_amdgcn_mfma_f32_16x16x32_f16(ah[mt], bh, acc[mt][nt], 0, 0, 0);
    }
  };

  float va[16];
  const int nk = K >> 5;

  // prologue: fill buffer 0 (ASRC3's tile 0 is ds-mode)
  if (COPYA) {
    stageA(0, 0);
    stageB(0, 0);
  } else {
    stageLoad(0, va);
    stageB(0, 0);
    stageWrite(0, va);
  }
  __syncthreads();

  for (int kt = 0; kt < nk; ++kt) {
    const int bi = kt & 1;
    const bool pf = (kt + 1 < nk);
    bool nextds = false;
    if (pf) {
      const int k0 = (kt + 1) << 5;
      stageB(bi ^ 1, k0);
      if (COPYA) {
        stageA(bi ^ 1, k0);
      } else if (ASRC == 3 && k0 >= 128) {
        stageA(bi ^ 1, k0 - 128); // copy phase: A = hbf (x-through path)
      } else {
        stageLoad(k0, va);
        nextds = true;
      }
    }
    fragmfma(bi);
    if (nextds) stageWrite(bi ^ 1, va);
    __syncthreads();
  }

  // epilogue: C/D layout col=lane&15, row=quad*4+reg
  float ls[NT], lq[NT];
#pragma unroll
  for (int nt = 0; nt < NT; ++nt) { ls[nt] = 0.f; lq[nt] = 0.f; }
#pragma unroll
  for (int nt = 0; nt < NT; ++nt) {
    int col = bn + nt * 16 + c16;
    if (col >= Nc) continue;
    float bv = BIAS ? bias[col] : 0.f;
#pragma unroll
    for (int mt = 0; mt < 2; ++mt) {
#pragma unroll
      for (int r = 0; r < 4; ++r) {
        long long row = bm + w * 32 + mt * 16 + quad * 4 + r;
        float v = acc[mt][nt][r] + bv;
        if (RELU) v = fmaxf(v, 0.f);
        if (ASRC == 3) { ls[nt] += v; lq[nt] += v * v; }
        if (OHALF) Cu[row * ldc + col] = f2h(v);
        else Cf[row * ldc + col] = v;
      }
    }
  }
  if constexpr (ASRC == 3) {
    // fused BN column partial stats: LDS reduce + one global atomic per col
    float* csum = (float*)AhS;  // reuse LDS (all waves past final barrier)
    float* csq = csum + 128;
    if (tid < 128) { csum[tid] = 0.f; csq[tid] = 0.f; }
    __syncthreads();
#pragma unroll
    for (int nt = 0; nt < NT; ++nt) {
      int col = bn + nt * 16 + c16;
      atomicAdd(&csum[col], ls[nt]);
      atomicAdd(&csq[col], lq[nt]);
    }
    __syncthreads();
    float* colsum = (float*)aux.p1;
    if (tid < 128) {
      atomicAdd(&colsum[tid], csum[tid]);
      atomicAdd(&colsum[128 + tid], csq[tid]);
    }
  }
}

// ---------------------------------------------------------------------------
// edge encoder: fp16 DIRECTLY in CSR slot order, PRE-SWIZZLED; 2 edges/block
// ---------------------------------------------------------------------------
__global__ __launch_bounds__(256) void edge_enc(
    const float* __restrict__ eat, const float* __restrict__ We,
    const float* __restrict__ be, const int* __restrict__ slot_of,
    unsigned short* __restrict__ ef)
{
  int e = blockIdx.x * 2 + (threadIdx.x >> 7);
  int c = threadIdx.x & 127;
  float acc = be[c];
#pragma unroll
  for (int k = 0; k < 4; ++k) acc += eat[e * 4 + k] * We[k * 128 + c];
  long long slot = slot_of[e];
  ef[slot * 128 + swk((int)slot, c)] = f2h(fmaxf(acc, 0.f));
}

// ---------------------------------------------------------------------------
// CSR build: count -> scan (also inits cursor + s/invs) -> scatter
// ---------------------------------------------------------------------------
__global__ void count_deg(const int* __restrict__ dst, int* __restrict__ degi)
{
  int e = blockIdx.x * 256 + threadIdx.x;
  if (e < EE) atomicAdd(&degi[dst[e]], 1);
}

__global__ __launch_bounds__(1024) void scan_k(const int* __restrict__ degi,
                                               int* __restrict__ row_off,
                                               int* __restrict__ cursor,
                                               float* __restrict__ s_arr,
                                               float* __restrict__ invs)
{
  __shared__ int tsum[1024];
  int t = threadIdx.x;
  int local[16];
  int base = t * 16;
  int s = 0;
#pragma unroll
  for (int i = 0; i < 16; ++i) { local[i] = s; s += degi[base + i]; }
  tsum[t] = s;
  __syncthreads();
  for (int off = 1; off < 1024; off <<= 1) {
    int v = (t >= off) ? tsum[t - off] : 0;
    __syncthreads();
    tsum[t] += v;
    __syncthreads();
  }
  int prev = (t == 0) ? 0 : tsum[t - 1];
#pragma unroll
  for (int i = 0; i < 16; ++i) {
    int start = prev + local[i];
    row_off[base + i] = start;
    cursor[base + i] = start;
    int cnt = degi[base + i];
    float degc = fmaxf((float)cnt, 1.f);
    float sv = logf(degc + 1.f) / AVG_LOG_F;
    s_arr[base + i] = sv;
    invs[base + i] = 1.f / sv;
  }
  if (t == 1023) row_off[NN] = tsum[1023];
}

__global__ void scatter_k(const int* __restrict__ src, const int* __restrict__ dst,
                          int* __restrict__ cursor,
                          int* __restrict__ slot_of, int* __restrict__ esrc)
{
  int e = blockIdx.x * 256 + threadIdx.x;
  if (e >= EE) return;
  int d = dst[e];
  int slot = atomicAdd(&cursor[d], 1);
  slot_of[e] = slot;
  esrc[slot] = src[e];
}

// ---------------------------------------------------------------------------
// Weight folds (fp32)
// ---------------------------------------------------------------------------
__global__ __launch_bounds__(512) void fold_w(const float* __restrict__ We_conv,
                                              const float* __restrict__ Wpre,
                                              float* __restrict__ Wfold)
{
  int k = blockIdx.x & 127, l = blockIdx.x >> 7;
  int t = threadIdx.x >> 7, f = threadIdx.x & 127;
  const float* wc = We_conv + (long long)(l * 128 + k) * 128;
  const float* wp = Wpre + ((long long)((l * 4 + t) * 384 + 256)) * 128 + f;
  float acc = 0.f;
  for (int j = 0; j < 128; ++j) acc += wc[j] * wp[(long long)j * 128];
  Wfold[((long long)(l * 128 + k)) * 512 + threadIdx.x] = acc;
}

__global__ __launch_bounds__(512) void fold_b(const float* __restrict__ be_conv,
                                              const float* __restrict__ Wpre,
                                              const float* __restrict__ bpre,
                                              float* __restrict__ bfold)
{
  int l = blockIdx.x;
  int t = threadIdx.x >> 7, f = threadIdx.x & 127;
  const float* bc = be_conv + l * 128;
  const float* wp = Wpre + ((long long)((l * 4 + t) * 384 + 256)) * 128 + f;
  float acc = bpre[(l * 4 + t) * 128 + f];
  for (int j = 0; j < 128; ++j) acc += bc[j] * wp[(long long)j * 128];
  bfold[l * 512 + threadIdx.x] = acc;
}

// ---------------------------------------------------------------------------
// pack_all: ALL fp32 -> fp16 swizzled packers + node encoder in ONE launch.
// Segments by blockIdx (128 threads each):
//  [0,3072)      preABT[lt][n(256)][k(128)]
//  [3072,4608)   foldT[lt][n(128)][k(128)]   (reads WfoldF, after fold_w)
//  [4608,6144)   post3T[lt][c(128)][r(512)]  (4 r per thread)
//  [6144,6528)   linT2 lo-half: Wlin transpose [l][n][k<128]
//  [6528,6912)   linT2 hi-half: Wxl[l][o][128+kk] = sum_c Wx[kk][c]*Wlin[c][o]
//  [6912,6976)   w1T[n(64)][k(128)]
//  [6976,23360)  node_enc: hbf[n] = fp16(relu(x@Wa+ba)) swizzled
// ---------------------------------------------------------------------------
__global__ __launch_bounds__(128) void pack_all(
    const float* __restrict__ Wpre, const float* __restrict__ WfoldF,
    const float* __restrict__ Wpost, const float* __restrict__ Wlin,
    const float* __restrict__ W1,
    const float* __restrict__ x, const float* __restrict__ Wa,
    const float* __restrict__ ba,
    unsigned short* __restrict__ preABT, unsigned short* __restrict__ foldT,
    unsigned short* __restrict__ post3T, unsigned short* __restrict__ linT2,
    unsigned short* __restrict__ w1T, unsigned short* __restrict__ hbf)
{
  const int b = blockIdx.x;
  const int t = threadIdx.x;
  if (b < 3072) {                       // preABT
    int lt = b >> 8, n = b & 255, k = t;
    int row = (n < 128) ? k : (128 + k);
    int f = n & 127;
    float v = Wpre[((long long)(lt * 384 + row)) * 128 + f];
    preABT[((long long)(lt * 256 + n)) * 128 + swk(n, k)] = f2h(v);
  } else if (b < 4608) {                // foldT
    int b2 = b - 3072;
    int lt = b2 >> 7, n = b2 & 127, k = t;
    int l = lt >> 2, tw = lt & 3;
    float v = WfoldF[((long long)(l * 128 + k)) * 512 + tw * 128 + n];
    foldT[((long long)(lt * 128 + n)) * 128 + swk(n, k)] = f2h(v);
  } else if (b < 6144) {                // post3T
    int b3 = b - 4608;
    int lt = b3 >> 7, c = b3 & 127;
#pragma unroll
    for (int j = 0; j < 4; ++j) {
      int r = t + 128 * j;
      float v = 0.f;
      if (c < 96)
        v = Wpost[((long long)(lt * 1664 + 128 + (c >> 5) * 512 + r)) * 32 + (c & 31)];
      post3T[((long long)(lt * 128 + c)) * 512 + swk(c, r)] = f2h(v);
    }
  } else if (b < 6528) {                // linT2 low half: Wlin^T
    int b4 = b - 6144;
    int l = b4 >> 7, n = b4 & 127, k = t;
    float v = Wlin[((long long)(l * 128 + k)) * 128 + n];
    linT2[((long long)(l * 128 + n)) * 256 + swk(n, k)] = f2h(v);
  } else if (b < 6912) {                // linT2 high half: Wxl fold
    int b5 = b - 6528;
    int l = b5 >> 7, kk = b5 & 127, o = t;
    float acc = 0.f;
    for (int c = 0; c < 128; ++c) {
      float wx = Wpost[((long long)((l * 4 + (c >> 5)) * 1664 + kk)) * 32 + (c & 31)];
      acc += wx * Wlin[((long long)(l * 128 + c)) * 128 + o];
    }
    linT2[((long long)(l * 128 + o)) * 256 + swk(o, 128 + kk)] = f2h(acc);
  } else if (b < 6976) {                // w1T
    int n = b - 6912, k = t;
    w1T[(long long)n * 128 + swk(n, k)] = f2h(W1[k * 64 + n]);
  } else {                              // node_enc
    int n = b - 6976, c = t;
    float acc = ba[c];
#pragma unroll
    for (int k = 0; k < 11; ++k) acc += x[n * 11 + k] * Wa[k * 128 + c];
    hbf[((long long)n << 7) + swk(n, c)] = f2h(fmaxf(acc, 0.f));
  }
}

// ---------------------------------------------------------------------------
// Per-tower aggregation, ALL FOUR towers in one block, 16B loads.
// Block 256 = 4 nodes x 4 towers x 16 lanes (8 ch each, single us8v load).
// Edges processed in chunks of 4: esrc batch-loaded first, then 8 independent
// 16B loads in flight (breaks the esrc->ABs dependent-latency chain).
// AB and Mb slabs fp16. Accumulation order per channel identical to scalar.
// Output aggs fp16 [N][512], PRE-SWIZZLED (swk) for gll staging by the P gemm.
// ---------------------------------------------------------------------------
__global__ __launch_bounds__(256) void aggregate_ct(
    const unsigned short* __restrict__ ABb, const unsigned short* __restrict__ Mb,
    const int* __restrict__ row_off, const int* __restrict__ esrc,
    unsigned short* __restrict__ aggs)
{
  const int tid = threadIdx.x;
  const int c8 = (tid & 15) << 3;     // 8 channels per lane
  const int z = (tid >> 4) & 3;       // tower
  const int n = blockIdx.x * 4 + (tid >> 6);
  const unsigned short* M = Mb + (long long)z * EE * 128;
  const unsigned short* ABs = ABb + (long long)z * NN * 256;
  unsigned short* ag = aggs + (long long)z * NN * 512;
  const int beg = row_off[n], end = row_off[n + 1];
  const int cnt = end - beg;
  const float degc = fmaxf((float)cnt, 1.0f);
  float aval[8];
  ld8hf(&ABs[(long long)n * 256 + c8], aval);

  float sum[8], sq[8], mn[8], mx[8];
#pragma unroll
  for (int j = 0; j < 8; ++j) {
    sum[j] = 0.f; sq[j] = 0.f; mn[j] = INFINITY; mx[j] = -INFINITY;
  }

  auto upd = [&](const float* mv, const float* bv) {
#pragma unroll
    for (int j = 0; j < 8; ++j) {
      float m = aval[j] + bv[j] + mv[j];
      sum[j] += m; sq[j] += m * m;
      mn[j] = fminf(mn[j], m); mx[j] = fmaxf(mx[j], m);
    }
  };

  for (int s0 = beg; s0 < end; s0 += 4) {
    const int e1 = min(s0 + 1, end - 1);
    const int e2 = min(s0 + 2, end - 1);
    const int e3 = min(s0 + 3, end - 1);
    const int sA = esrc[s0], sB = esrc[e1], sC = esrc[e2], sD = esrc[e3];
    float mA[8], mB[8], mC[8], mD[8], bA[8], bB[8], bC[8], bD[8];
    ld8hf(&M[(long long)s0 * 128 + c8], mA);
    ld8hf(&M[(long long)e1 * 128 + c8], mB);
    ld8hf(&M[(long long)e2 * 128 + c8], mC);
    ld8hf(&M[(long long)e3 * 128 + c8], mD);
    ld8hf(&ABs[(long long)sA * 256 + 128 + c8], bA);
    ld8hf(&ABs[(long long)sB * 256 + 128 + c8], bB);
    ld8hf(&ABs[(long long)sC * 256 + 128 + c8], bC);
    ld8hf(&ABs[(long long)sD * 256 + 128 + c8], bD);
    upd(mA, bA);
    if (s0 + 1 < end) upd(mB, bB);
    if (s0 + 2 < end) upd(mC, bC);
    if (s0 + 3 < end) upd(mD, bD);
  }

  const float inv = 1.0f / degc;
  us8v omean, omin, omax, ostd;
#pragma unroll
  for (int j = 0; j < 8; ++j) {
    float mean = sum[j] * inv;
    float var = sq[j] * inv - mean * mean;
    float stdv = sqrtf(fmaxf(var, 0.f) + 1e-5f);
    float mnv = (cnt > 0) ? mn[j] : 0.f;
    float mxv = (cnt > 0) ? mx[j] : 0.f;
    omean[j] = f2h(mean);
    omin[j] = f2h(mnv);
    omax[j] = f2h(mxv);
    ostd[j] = f2h(stdv);
  }
  const int sc = swk(n, c8);
  const long long base = (long long)n * 512 + sc;
  *(us8v*)&ag[base] = omean;
  *(us8v*)&ag[base + 128] = omin;
  *(us8v*)&ag[base + 256] = omax;
  *(us8v*)&ag[base + 384] = ostd;
}

// ---------------------------------------------------------------------------
// BN apply (coef computed inline from colstats)
// hb = fp16(relu(hn*scale + shift)) pre-swizzled; hn is fp16
// ---------------------------------------------------------------------------
__global__ __launch_bounds__(256) void bn_apply(const unsigned short* __restrict__ hn,
                                                const float* __restrict__ cs,
                                                const float* __restrict__ g,
                                                const float* __restrict__ b,
                                                unsigned short* __restrict__ hb)
{
  int idx = blockIdx.x * 256 + threadIdx.x; // n*128+c
  int c = idx & 127, n = idx >> 7;
  float mean = cs[c] * (1.f / 16384.f);
  float var = cs[128 + c] * (1.f / 16384.f) - mean * mean;
  float sc = g[c] * rsqrtf(var + 1e-5f);
  float v = fmaxf(h2f(hn[idx]) * sc + (b[c] - mean * sc), 0.f);
  hb[((long long)n << 7) + swk(n, c)] = f2h(v);
}

// ---------------------------------------------------------------------------
// Global mean pool (BN+ReLU fused) + head
// ---------------------------------------------------------------------------
__global__ void pool_add(const unsigned short* __restrict__ y, const float* __restrict__ cs,
                         const float* __restrict__ g, const float* __restrict__ b,
                         const int* __restrict__ batch,
                         float* __restrict__ pooled, float* __restrict__ cntf)
{
  int n = blockIdx.x, c = threadIdx.x;
  float mean = cs[c] * (1.f / 16384.f);
  float var = cs[128 + c] * (1.f / 16384.f) - mean * mean;
  float v = fmaxf((h2f(y[(long long)n * 128 + c]) - mean) * rsqrtf(var + 1e-5f) * g[c] + b[c], 0.f);
  int bb = batch[n];
  atomicAdd(&pooled[(long long)bb * 128 + c], v);
  if (c == 0) atomicAdd(&cntf[bb], 1.f);
}

__global__ __launch_bounds__(256) void zstats(const float* __restrict__ z,
                                              float* __restrict__ zm, float* __restrict__ zv)
{
  int j = blockIdx.x; // 64 cols
  float s = 0.f, q = 0.f;
  for (int g = threadIdx.x; g < GG; g += 256) {
    float v = z[g * 64 + j];
    s += v;
    q += v * v;
  }
  __shared__ float ps[256], pq[256];
  ps[threadIdx.x] = s;
  pq[threadIdx.x] = q;
  __syncthreads();
  for (int st = 128; st > 0; st >>= 1) {
    if (threadIdx.x < st) {
      ps[threadIdx.x] += ps[threadIdx.x + st];
      pq[threadIdx.x] += pq[threadIdx.x + st];
    }
    __syncthreads();
  }
  if (threadIdx.x == 0) {
    float m = ps[0] / (float)GG;
    zm[j] = m;
    zv[j] = pq[0] / (float)GG - m * m;
  }
}

__global__ void final_out(const float* __restrict__ z, const float* __restrict__ zm,
                          const float* __restrict__ zv, const float* __restrict__ hg,
                          const float* __restrict__ hb, const float* __restrict__ W2,
                          const float* __restrict__ b2, float* __restrict__ out)
{
  int g = blockIdx.x;
  int j = threadIdx.x; // 64 = one wave
  float v = (z[g * 64 + j] - zm[j]) * rsqrtf(zv[j] + 1e-5f) * hg[j] + hb[j];
  float t = v * W2[j];
#pragma unroll
  for (int off = 32; off > 0; off >>= 1) t += __shfl_down(t, off);
  if (j == 0) out[g] = t + b2[0];
}

// ---------------------------------------------------------------------------
extern "C" void kernel_launch(void* const* d_in, const int* in_sizes, int n_in,
                              void* d_out, int out_size, void* d_ws, size_t ws_size,
                              hipStream_t stream)
{
  (void)in_sizes; (void)n_in; (void)out_size;
  const float* x = (const float*)d_in[0];
  const float* eat = (const float*)d_in[1];
  const int* ei = (const int*)d_in[2];
  const int* batch = (const int*)d_in[3];
  const float* Wa = (const float*)d_in[4];
  const float* ba = (const float*)d_in[5];
  const float* We = (const float*)d_in[6];
  const float* be = (const float*)d_in[7];
  const float* We_conv = (const float*)d_in[8];
  const float* be_conv = (const float*)d_in[9];
  const float* Wpre = (const float*)d_in[10];
  const float* bpre = (const float*)d_in[11];
  const float* Wpost = (const float*)d_in[12];
  const float* bpost = (const float*)d_in[13];
  const float* Wlin = (const float*)d_in[14];
  const float* blin = (const float*)d_in[15];
  const float* bng = (const float*)d_in[16];
  const float* bnb = (const float*)d_in[17];
  const float* W1 = (const float*)d_in[18];
  const float* b1 = (const float*)d_in[19];
  const float* hg = (const float*)d_in[20];
  const float* hb = (const float*)d_in[21];
  const float* W2 = (const float*)d_in[22];
  const float* b2 = (const float*)d_in[23];
  float* out = (float*)d_out;

  const int* srcI = ei;
  const int* dstI = ei + EE;

  char* ws = (char*)d_ws;
  size_t off = 0;
  auto alloc = [&](size_t bytes) -> char* {
    char* p = ws + off;
    off += (bytes + 255) & ~(size_t)255;
    return p;
  };

  unsigned short* hbf = (unsigned short*)alloc((size_t)NN * 128 * 2); // fp16 h
  unsigned short* hn = (unsigned short*)alloc((size_t)NN * 128 * 2);  // fp16 hn
  unsigned short* eaf = (unsigned short*)alloc((size_t)EE * 128 * 2); // fp16 ea, CSR order
  unsigned short* AB = (unsigned short*)alloc((size_t)4 * NN * 256 * 2); // fp16 [T][N][256]
  char* Mregion = alloc((size_t)4 * EE * 128 * 2);           // Mb fp16 [4][E][128]; later P fp16
  unsigned short* Mb = (unsigned short*)Mregion;
  unsigned short* P = (unsigned short*)Mregion;               // fp16 [N][384]
  unsigned short* aggt = (unsigned short*)alloc((size_t)4 * NN * 512 * 2); // fp16 [T][N][512]
  float* s_arr = (float*)alloc((size_t)NN * 4);
  float* invs = (float*)alloc((size_t)NN * 4);
  int* degi = (int*)alloc((size_t)NN * 4);
  int* cursor = (int*)alloc((size_t)NN * 4);
  int* row_off = (int*)alloc((size_t)(NN + 1) * 4);
  int* slot_of = (int*)alloc((size_t)EE * 4);
  int* esrc = (int*)alloc((size_t)EE * 4);
  float* WfoldF = (float*)alloc((size_t)3 * 128 * 512 * 4);
  float* bfold = (float*)alloc((size_t)3 * 512 * 4);
  unsigned short* preABT = (unsigned short*)alloc((size_t)12 * 256 * 128 * 2);
  unsigned short* foldT = (unsigned short*)alloc((size_t)12 * 128 * 128 * 2);
  unsigned short* post3T = (unsigned short*)alloc((size_t)12 * 128 * 512 * 2);
  unsigned short* linT2 = (unsigned short*)alloc((size_t)3 * 128 * 256 * 2); // [Wlin^T | Wx@Wlin]
  unsigned short* w1T = (unsigned short*)alloc((size_t)64 * 128 * 2);
  float* colstats = (float*)alloc(3 * 256 * 4); // one 256-buffer per layer
  float* pooled = (float*)alloc((size_t)GG * 128 * 4);
  float* cntf = (float*)alloc((size_t)GG * 4);
  float* zbuf = (float*)alloc((size_t)GG * 64 * 4);
  float* zm = (float*)alloc(64 * 4);
  float* zv = (float*)alloc(64 * 4);

  if (off > ws_size) return; // bail rather than corrupt

  // ---- graph structure ----
  hipMemsetAsync(degi, 0, (size_t)NN * 4, stream);
  hipMemsetAsync(colstats, 0, 3 * 256 * 4, stream);
  count_deg<<<EE / 256, 256, 0, stream>>>(dstI, degi);
  scan_k<<<1, 1024, 0, stream>>>(degi, row_off, cursor, s_arr, invs);
  scatter_k<<<EE / 256, 256, 0, stream>>>(srcI, dstI, cursor, slot_of, esrc);

  // ---- encoders + weight folds/packing ----
  edge_enc<<<EE / 2, 256, 0, stream>>>(eat, We, be, slot_of, eaf); // after scatter_k
  fold_w<<<384, 512, 0, stream>>>(We_conv, Wpre, WfoldF);
  fold_b<<<3, 512, 0, stream>>>(be_conv, Wpre, bpre, bfold);
  pack_all<<<6976 + NN, 128, 0, stream>>>(Wpre, WfoldF, Wpost, Wlin, W1, x, Wa, ba,
                                          preABT, foldT, post3T, linT2, w1T, hbf);

  for (int l = 0; l < 3; ++l) {
    float* cs_l = colstats + l * 256;
    // merged AB (z=4, both col-halves) + C (z=4) gemms, one dispatch
    abc_gemm<<<3072, 256, 0, stream>>>(
        hbf, preABT + (size_t)l * 4 * 256 * 128, AB,
        eaf, foldT + (size_t)l * 4 * 128 * 128, bfold + l * 512, Mb);
    // stats over m = (A + B[src]) + C ; 4 nodes x 4 towers per block
    aggregate_ct<<<dim3(NN / 4, 1, 1), 256, 0, stream>>>(AB, Mb, row_off, esrc, aggt);
    // P all towers: fp16 [N,512] @ [512,96] (z=4, exact 96-col tile) -> fp16 P
    mgemm<1, 6, false, false, true><<<dim3(NN / 128, 1, 4), 256, 0, stream>>>(
        aggt, post3T + (size_t)l * 4 * 128 * 512, nullptr, (float*)P, AuxP{},
        96, 512, 512, 384, (long long)NN * 512, (long long)128 * 512, 96, 0);
    // lin (K=256 two-phase: P-combine | hbf x-through vs folded Wx@Wlin),
    // + blin; epilogue fuses BN column stats into cs_l; output fp16 hn
    mgemm<3, 8, true, false, true><<<dim3(NN / 128, 1, 1), 256, 0, stream>>>(
        hbf, linT2 + (size_t)l * 128 * 256, blin + l * 128, (float*)hn,
        AuxP{(const float*)P, cs_l, s_arr, invs, bpost + l * 128},
        128, 256, 128, 128, 0, 0, 0, 0);
    if (l < 2)
      bn_apply<<<NN * 128 / 256, 256, 0, stream>>>(hn, cs_l, bng + l * 128,
                                                   bnb + l * 128, hbf);
  }

  // ---- pooling (BN+ReLU fused) + head ----
  hipMemsetAsync(pooled, 0, (size_t)GG * 128 * 4, stream);
  hipMemsetAsync(cntf, 0, (size_t)GG * 4, stream);
  pool_add<<<NN, 128, 0, stream>>>(hn, colstats + 2 * 256,
                                   bng + 2 * 128, bnb + 2 * 128, batch, pooled, cntf);
  mgemm<4, 4, true, true, false><<<dim3(GG / 128, 1, 1), 256, 0, stream>>>(
      pooled, w1T, b1, zbuf, AuxP{cntf, nullptr, nullptr, nullptr, nullptr},
      64, 128, 128, 64, 0, 0, 0, 0);
  zstats<<<64, 256, 0, stream>>>(zbuf, zm, zv);
  final_out<<<GG, 64, 0, stream>>>(zbuf, zm, zv, hg, hb, W2, b2, out);
}